// Round 1
// baseline (14857.147 us; speedup 1.0000x reference)
//
#include <hip/hip_runtime.h>
#include <math.h>
#include <float.h>

#define T_SEQ  2048
#define DMODEL 512
#define NHEAD  8
#define DHEAD  64
#define FDIM   2048
#define NLAYER 4
#define NB     2
#define MROWS  (NB*T_SEQ)   // 4096

// ---------------------------------------------------------------------------
// GEMM: C = A[M,K] @ W[N,K]^T + bias[N], fp32 vector-FMA, BM=128, BK=32.
// EPI: 0 = none, 1 = +pos_emb[m%T][n] (embedding), 2 = spike (x>0.5 ? 1 : 0)
// LAYOUT: 0 = plain row-major [M,N], 1 = head layout [B,H,T,dh]
// ---------------------------------------------------------------------------
template<int BN, int EPI, int LAYOUT>
__global__ __launch_bounds__(256) void gemm_k(
    const float* __restrict__ A, const float* __restrict__ W,
    const float* __restrict__ bias, const float* __restrict__ pos,
    float* __restrict__ C, int M, int N, int K)
{
    constexpr int BM = 128;
    constexpr int BK = 32;
    constexpr int MN = BN / 16;          // 4 (BN=64) or 8 (BN=128)
    __shared__ float As[BK][BM + 4];     // [k][m], pad 4 keeps 16B align
    __shared__ float Ws[BK][BN + 4];     // [k][n]
    const int tid = threadIdx.x;
    const int n0 = blockIdx.x * BN;
    const int m0 = blockIdx.y * BM;
    const int tx = tid & 15;             // n direction: cols tx*4 (+64)
    const int ty = tid >> 4;             // m direction: rows ty*8..+7

    float acc[8][MN];
    #pragma unroll
    for (int i = 0; i < 8; ++i)
        #pragma unroll
        for (int j = 0; j < MN; ++j) acc[i][j] = 0.f;

    for (int k0 = 0; k0 < K; k0 += BK) {
        // stage A tile 128x32 (transposed into LDS): 4 float4 per thread
        #pragma unroll
        for (int it = 0; it < 4; ++it) {
            int qq = tid + 256 * it;
            int m = qq >> 3, kq = qq & 7;
            float4 v4 = *(const float4*)(A + (size_t)(m0 + m) * K + k0 + kq * 4);
            As[kq*4+0][m] = v4.x; As[kq*4+1][m] = v4.y;
            As[kq*4+2][m] = v4.z; As[kq*4+3][m] = v4.w;
        }
        // stage W tile BNx32
        #pragma unroll
        for (int it = 0; it < BN/32; ++it) {
            int qq = tid + 256 * it;
            int n = qq >> 3, kq = qq & 7;
            float4 v4 = *(const float4*)(W + (size_t)(n0 + n) * K + k0 + kq * 4);
            Ws[kq*4+0][n] = v4.x; Ws[kq*4+1][n] = v4.y;
            Ws[kq*4+2][n] = v4.z; Ws[kq*4+3][n] = v4.w;
        }
        __syncthreads();
        for (int kk = 0; kk < BK; ++kk) {
            float a[8], b[MN];
            float4 a0 = *(const float4*)&As[kk][ty*8];
            float4 a1 = *(const float4*)&As[kk][ty*8+4];
            a[0]=a0.x; a[1]=a0.y; a[2]=a0.z; a[3]=a0.w;
            a[4]=a1.x; a[5]=a1.y; a[6]=a1.z; a[7]=a1.w;
            float4 b0 = *(const float4*)&Ws[kk][tx*4];
            b[0]=b0.x; b[1]=b0.y; b[2]=b0.z; b[3]=b0.w;
            if constexpr (MN == 8) {
                float4 b1 = *(const float4*)&Ws[kk][64 + tx*4];
                b[4]=b1.x; b[5]=b1.y; b[6]=b1.z; b[7]=b1.w;
            }
            #pragma unroll
            for (int i = 0; i < 8; ++i)
                #pragma unroll
                for (int j = 0; j < MN; ++j)
                    acc[i][j] = fmaf(a[i], b[j], acc[i][j]);
        }
        __syncthreads();
    }

    // epilogue
    #pragma unroll
    for (int i = 0; i < 8; ++i) {
        int m = m0 + ty*8 + i;
        #pragma unroll
        for (int jb = 0; jb < MN/4; ++jb) {
            int nn = n0 + jb*64 + tx*4;
            float4 r;
            r.x = acc[i][jb*4+0] + bias[nn+0];
            r.y = acc[i][jb*4+1] + bias[nn+1];
            r.z = acc[i][jb*4+2] + bias[nn+2];
            r.w = acc[i][jb*4+3] + bias[nn+3];
            if constexpr (EPI == 1) {
                const float* pp = pos + (size_t)(m & (T_SEQ-1)) * DMODEL + nn;
                r.x += pp[0]; r.y += pp[1]; r.z += pp[2]; r.w += pp[3];
            }
            if constexpr (EPI == 2) {
                r.x = r.x > 0.5f ? 1.f : 0.f;
                r.y = r.y > 0.5f ? 1.f : 0.f;
                r.z = r.z > 0.5f ? 1.f : 0.f;
                r.w = r.w > 0.5f ? 1.f : 0.f;
            }
            if constexpr (LAYOUT == 0) {
                *(float4*)(C + (size_t)m * N + nn) = r;
            } else {
                int b_ = m >> 11, t_ = m & (T_SEQ-1);
                int h_ = nn >> 6, d_ = nn & 63;
                *(float4*)(C + (((size_t)(b_*NHEAD + h_)*T_SEQ + t_) << 6) + d_) = r;
            }
        }
    }
}

// ---------------------------------------------------------------------------
// Transpose: k_plain [B*T, D] -> kT [B, H, dh, T]  (i.e. [B*D, T])
// ---------------------------------------------------------------------------
__global__ __launch_bounds__(256) void transpose_k(
    const float* __restrict__ in, float* __restrict__ out)
{
    __shared__ float tile[32][33];
    const int t0 = blockIdx.x * 32;   // row block (b*T + t)
    const int c0 = blockIdx.y * 32;   // model-dim block
    const int tid = threadIdx.x;
    const int r = tid >> 5;           // 0..7
    const int c = tid & 31;
    #pragma unroll
    for (int i = 0; i < 4; ++i)
        tile[r + 8*i][c] = in[(size_t)(t0 + r + 8*i) * DMODEL + c0 + c];
    __syncthreads();
    #pragma unroll
    for (int i = 0; i < 4; ++i) {
        int n = c0 + r + 8*i;               // model-dim index
        int m = t0 + c;                     // global row
        int b = m >> 11, t = m & (T_SEQ-1);
        out[((size_t)(b * DMODEL + n)) * T_SEQ + t] = tile[c][r + 8*i];
    }
}

// ---------------------------------------------------------------------------
// Fused sparse attention: scores -> online top-32 -> softmax -> AV
// block = 256 thr = one (b,h) x 32 query rows; grid (T/32, B*H)
// q: [B,H,T,dh]  kT: [B,H,dh,T]  v: [B,H,T,dh]  out: [B,T,D] merged heads
// ---------------------------------------------------------------------------
__global__ __launch_bounds__(256) void attn_k(
    const float* __restrict__ q, const float* __restrict__ kT,
    const float* __restrict__ v, float* __restrict__ out)
{
    __shared__ float qsT[64][36];        // q tile transposed [d][row]
    __shared__ float ksbuf[64*128];      // k tile [d][j]; re-used as scores [row][j]
    __shared__ float tv[32][33];         // running top-32 values (sorted desc)
    __shared__ int   ti[32][33];         // matching indices

    const int tid = threadIdx.x;
    const int bh  = blockIdx.y;
    const int t0  = blockIdx.x * 32;
    const float* qb = q  + ((size_t)bh * T_SEQ + t0) * DHEAD;
    const float* kb = kT + (size_t)bh * DHEAD * T_SEQ;
    const float* vb = v  + (size_t)bh * T_SEQ * DHEAD;

    #pragma unroll
    for (int it = 0; it < 8; ++it) {
        int e = tid + 256*it;
        qsT[e & 63][e >> 6] = qb[e];     // e = row*64 + d
    }
    #pragma unroll
    for (int it = 0; it < 4; ++it) {
        int e = tid + 256*it;
        tv[e >> 5][e & 31] = -FLT_MAX;
        ti[e >> 5][e & 31] = 0;
    }

    const int ry = tid >> 5;             // 0..7 -> rows ry*4..+3
    const int tx = tid & 31;             // cols tx*4..+3
    float (*ks)[128] = (float(*)[128])ksbuf;
    float (*ss)[128] = (float(*)[128])ksbuf;

    for (int jt = 0; jt < 16; ++jt) {
        const int j0 = jt * 128;
        // stage k tile [64 d][128 j]
        #pragma unroll
        for (int it = 0; it < 8; ++it) {
            int e = tid + 256*it;
            int d = e >> 5, tq = e & 31;
            *(float4*)&ks[d][tq*4] = *(const float4*)(kb + (size_t)d*T_SEQ + j0 + tq*4);
        }
        __syncthreads();                 // A: qsT + ks ready
        float acc[4][4];
        #pragma unroll
        for (int i = 0; i < 4; ++i)
            #pragma unroll
            for (int j = 0; j < 4; ++j) acc[i][j] = 0.f;
        #pragma unroll 8
        for (int d = 0; d < 64; ++d) {
            float4 qa4 = *(const float4*)&qsT[d][ry*4];
            float4 kb4 = *(const float4*)&ks[d][tx*4];
            float qa[4] = {qa4.x, qa4.y, qa4.z, qa4.w};
            float kv[4] = {kb4.x, kb4.y, kb4.z, kb4.w};
            #pragma unroll
            for (int i = 0; i < 4; ++i)
                #pragma unroll
                for (int j = 0; j < 4; ++j)
                    acc[i][j] = fmaf(qa[i], kv[j], acc[i][j]);
        }
        __syncthreads();                 // B: all ks reads done before overwrite
        #pragma unroll
        for (int i = 0; i < 4; ++i) {
            float4 r4;
            r4.x = acc[i][0]*0.125f; r4.y = acc[i][1]*0.125f;
            r4.z = acc[i][2]*0.125f; r4.w = acc[i][3]*0.125f;
            *(float4*)&ss[ry*4+i][tx*4] = r4;   // scaled by 1/sqrt(64)
        }
        __syncthreads();                 // C: scores visible
        if (tid < 32) {
            const int row = tid;
            float cut = tv[row][31];
            for (int jj = 0; jj < 128; ++jj) {
                int j = (jj + row) & 127;        // bank-conflict-free rotation
                float val = ss[row][j];
                if (val > cut) {                  // strict > : ties keep earlier idx
                    int p = 31;
                    while (p > 0 && tv[row][p-1] < val) {
                        tv[row][p] = tv[row][p-1];
                        ti[row][p] = ti[row][p-1];
                        --p;
                    }
                    tv[row][p] = val;
                    ti[row][p] = j0 + j;
                    cut = tv[row][31];
                }
            }
        }
        __syncthreads();                 // D: merge done before next stage clobbers
    }

    // softmax over the kept 32 (equals full-row softmax: exp(-1e9-m) == 0 in fp32)
    if (tid < 32) {
        const int row = tid;
        float m = tv[row][0];            // sorted desc -> max
        float w[32];
        float s = 0.f;
        #pragma unroll
        for (int i = 0; i < 32; ++i) { w[i] = expf(tv[row][i] - m); s += w[i]; }
        float inv = 1.f / s;
        #pragma unroll
        for (int i = 0; i < 32; ++i) tv[row][i] = w[i] * inv;
    }
    __syncthreads();

    // AV: wave per row-group, lane = head dim
    const int wid = tid >> 6, lane = tid & 63;
    const int b = bh >> 3, h = bh & 7;
    for (int rr = wid; rr < 32; rr += 4) {
        float accv = 0.f;
        #pragma unroll
        for (int i = 0; i < 32; ++i) {
            float wgt = tv[rr][i];
            int   idx = ti[rr][i];
            accv = fmaf(wgt, vb[(size_t)idx * DHEAD + lane], accv);
        }
        out[((size_t)(b * T_SEQ + t0 + rr)) * DMODEL + h * DHEAD + lane] = accv;
    }
}

// ---------------------------------------------------------------------------
// Rowwise LayerNorm with optional fused residual: out = LN(x [+ res]) * g + b
// block = 256 threads per row of 512
// ---------------------------------------------------------------------------
__global__ __launch_bounds__(256) void ln_k(
    const float* __restrict__ x, const float* __restrict__ res,
    const float* __restrict__ g, const float* __restrict__ bb,
    float* __restrict__ out)
{
    __shared__ float red[8];
    const int row = blockIdx.x;
    const int tid = threadIdx.x;
    const float* xr = x + (size_t)row * DMODEL;
    float v0 = xr[tid], v1 = xr[tid + 256];
    if (res) {
        const float* rr = res + (size_t)row * DMODEL;
        v0 += rr[tid]; v1 += rr[tid + 256];
    }
    float s = v0 + v1;
    #pragma unroll
    for (int o = 1; o < 64; o <<= 1) s += __shfl_xor(s, o);
    const int wid = tid >> 6, lane = tid & 63;
    if (lane == 0) red[wid] = s;
    __syncthreads();
    float mean = (red[0] + red[1] + red[2] + red[3]) * (1.f / DMODEL);
    float d0 = v0 - mean, d1 = v1 - mean;
    float qs = d0*d0 + d1*d1;
    #pragma unroll
    for (int o = 1; o < 64; o <<= 1) qs += __shfl_xor(qs, o);
    if (lane == 0) red[4 + wid] = qs;
    __syncthreads();
    float var = (red[4] + red[5] + red[6] + red[7]) * (1.f / DMODEL);
    float rs = rsqrtf(var + 1e-5f);
    out[(size_t)row * DMODEL + tid]       = d0 * rs * g[tid]       + bb[tid];
    out[(size_t)row * DMODEL + tid + 256] = d1 * rs * g[tid + 256] + bb[tid + 256];
}

// ---------------------------------------------------------------------------
// Mean pool over T:  pooled[b,d] = mean_t h[b,t,d]
// ---------------------------------------------------------------------------
__global__ __launch_bounds__(256) void pool_k(
    const float* __restrict__ h, float* __restrict__ pooled)
{
    int idx = blockIdx.x * 256 + threadIdx.x;    // 0..1023
    int b = idx >> 9, d = idx & 511;
    const float* p = h + (size_t)b * T_SEQ * DMODEL + d;
    float s = 0.f;
    for (int t = 0; t < T_SEQ; ++t) s += p[(size_t)t * DMODEL];
    pooled[idx] = s * (1.f / T_SEQ);
}

// ---------------------------------------------------------------------------
// Classifier: out[b,o] = pooled[b,:] . cls_w[o,:] + cls_b[o]; wave per output
// ---------------------------------------------------------------------------
__global__ __launch_bounds__(256) void cls_k(
    const float* __restrict__ pooled, const float* __restrict__ w,
    const float* __restrict__ bias, float* __restrict__ out)
{
    const int wid = threadIdx.x >> 6, lane = threadIdx.x & 63;
    const int oi = blockIdx.x * 4 + wid;     // 0..511
    const int b = oi >> 8, o = oi & 255;
    const float* pr = pooled + b * DMODEL;
    const float* wr = w + (size_t)o * DMODEL;
    float s = 0.f;
    for (int d = lane; d < DMODEL; d += 64) s = fmaf(pr[d], wr[d], s);
    #pragma unroll
    for (int off = 1; off < 64; off <<= 1) s += __shfl_xor(s, off);
    if (lane == 0) out[oi] = s + bias[o];
}

// ---------------------------------------------------------------------------
extern "C" void kernel_launch(void* const* d_in, const int* in_sizes, int n_in,
                              void* d_out, int out_size, void* d_ws, size_t ws_size,
                              hipStream_t stream)
{
    const float* x     = (const float*)d_in[0];
    const float* emb_w = (const float*)d_in[1];
    const float* emb_b = (const float*)d_in[2];
    const float* pos   = (const float*)d_in[3];
    const float* wq    = (const float*)d_in[4];
    const float* bq    = (const float*)d_in[5];
    const float* wk    = (const float*)d_in[6];
    const float* bk    = (const float*)d_in[7];
    const float* wv    = (const float*)d_in[8];
    const float* bv    = (const float*)d_in[9];
    const float* wo    = (const float*)d_in[10];
    const float* bo    = (const float*)d_in[11];
    const float* ln1g  = (const float*)d_in[12];
    const float* ln1b  = (const float*)d_in[13];
    const float* fc1w  = (const float*)d_in[14];
    const float* fc1b  = (const float*)d_in[15];
    const float* fc2w  = (const float*)d_in[16];
    const float* fc2b  = (const float*)d_in[17];
    const float* ln2g  = (const float*)d_in[18];
    const float* ln2b  = (const float*)d_in[19];
    const float* fng   = (const float*)d_in[20];
    const float* fnb   = (const float*)d_in[21];
    const float* clsw  = (const float*)d_in[22];
    const float* clsb  = (const float*)d_in[23];

    float* ws = (float*)d_ws;
    const size_t SZ = (size_t)MROWS * DMODEL;        // 2M floats
    float* h    = ws;                                // [4096,512]
    float* qb   = ws + 1*SZ;                         // q heads
    float* kTb  = ws + 2*SZ;                         // kT
    float* vbuf = ws + 3*SZ;                         // v heads
    float* t1   = ws + 4*SZ;                         // a / f
    float* h1   = ws + 5*SZ;                         // [4096,2048]: kp / attn_out / ffn hidden
    float* pooled = ws + 5*SZ + (size_t)MROWS * FDIM;
    const size_t needed = (5*SZ + (size_t)MROWS*FDIM + (size_t)NB*DMODEL) * sizeof(float);
    if (ws_size < needed) return;   // workspace too small -> visible failure

    dim3 blk(256);

    // embedding: h = x @ emb_w^T + emb_b + pos
    gemm_k<64,1,0><<<dim3(DMODEL/64, MROWS/128), blk, 0, stream>>>(
        x, emb_w, emb_b, pos, h, MROWS, DMODEL, 128);

    for (int l = 0; l < NLAYER; ++l) {
        const float* wq_l = wq + (size_t)l*DMODEL*DMODEL;
        const float* bq_l = bq + (size_t)l*DMODEL;
        const float* wk_l = wk + (size_t)l*DMODEL*DMODEL;
        const float* bk_l = bk + (size_t)l*DMODEL;
        const float* wv_l = wv + (size_t)l*DMODEL*DMODEL;
        const float* bv_l = bv + (size_t)l*DMODEL;
        const float* wo_l = wo + (size_t)l*DMODEL*DMODEL;
        const float* bo_l = bo + (size_t)l*DMODEL;
        const float* f1w_l = fc1w + (size_t)l*FDIM*DMODEL;
        const float* f1b_l = fc1b + (size_t)l*FDIM;
        const float* f2w_l = fc2w + (size_t)l*DMODEL*FDIM;
        const float* f2b_l = fc2b + (size_t)l*DMODEL;

        // q, k, v projections
        gemm_k<64,0,1><<<dim3(8,32), blk, 0, stream>>>(h, wq_l, bq_l, nullptr, qb,  MROWS, DMODEL, DMODEL);
        gemm_k<64,0,0><<<dim3(8,32), blk, 0, stream>>>(h, wk_l, bk_l, nullptr, h1,  MROWS, DMODEL, DMODEL);
        transpose_k<<<dim3(MROWS/32, DMODEL/32), blk, 0, stream>>>(h1, kTb);
        gemm_k<64,0,1><<<dim3(8,32), blk, 0, stream>>>(h, wv_l, bv_l, nullptr, vbuf, MROWS, DMODEL, DMODEL);

        // fused top-k attention -> h1 (merged heads [B,T,D])
        attn_k<<<dim3(T_SEQ/32, NB*NHEAD), blk, 0, stream>>>(qb, kTb, vbuf, h1);

        // output projection + spike -> t1
        gemm_k<64,2,0><<<dim3(8,32), blk, 0, stream>>>(h1, wo_l, bo_l, nullptr, t1, MROWS, DMODEL, DMODEL);
        // h = LN(h + a)
        ln_k<<<dim3(MROWS), blk, 0, stream>>>(h, t1, ln1g + (size_t)l*DMODEL, ln1b + (size_t)l*DMODEL, h);

        // FFN
        gemm_k<128,2,0><<<dim3(FDIM/128, 32), blk, 0, stream>>>(h,  f1w_l, f1b_l, nullptr, h1, MROWS, FDIM,   DMODEL);
        gemm_k<64,2,0> <<<dim3(8,32),        blk, 0, stream>>>(h1, f2w_l, f2b_l, nullptr, t1, MROWS, DMODEL, FDIM);
        // h = LN(h + f)
        ln_k<<<dim3(MROWS), blk, 0, stream>>>(h, t1, ln2g + (size_t)l*DMODEL, ln2b + (size_t)l*DMODEL, h);
    }

    // final norm, pool, classify
    ln_k<<<dim3(MROWS), blk, 0, stream>>>(h, nullptr, fng, fnb, h);
    pool_k<<<dim3(4), blk, 0, stream>>>(h, pooled);
    cls_k<<<dim3(128), blk, 0, stream>>>(pooled, clsw, clsb, (float*)d_out);
}

// Round 2
// 6478.679 us; speedup vs baseline: 2.2932x; 2.2932x over previous
//
#include <hip/hip_runtime.h>
#include <math.h>
#include <float.h>

#define T_SEQ  2048
#define DMODEL 512
#define NHEAD  8
#define DHEAD  64
#define FDIM   2048
#define NLAYER 4
#define NB     2
#define MROWS  (NB*T_SEQ)   // 4096

// ---------------------------------------------------------------------------
// GEMM: C = A[M,K] @ W[N,K]^T + bias[N], fp32 vector-FMA, BM=128, BK=32.
// EPI: 0 = none, 1 = +pos_emb[m%T][n] (embedding), 2 = spike (x>0.5 ? 1 : 0)
// LAYOUT: 0 = plain row-major [M,N], 1 = head layout [B,H,T,dh]
// ---------------------------------------------------------------------------
template<int BN, int EPI, int LAYOUT>
__global__ __launch_bounds__(256) void gemm_k(
    const float* __restrict__ A, const float* __restrict__ W,
    const float* __restrict__ bias, const float* __restrict__ pos,
    float* __restrict__ C, int M, int N, int K)
{
    constexpr int BM = 128;
    constexpr int BK = 32;
    constexpr int MN = BN / 16;          // 4 (BN=64) or 8 (BN=128)
    __shared__ float As[BK][BM + 4];     // [k][m], pad 4 keeps 16B align
    __shared__ float Ws[BK][BN + 4];     // [k][n]
    const int tid = threadIdx.x;
    const int n0 = blockIdx.x * BN;
    const int m0 = blockIdx.y * BM;
    const int tx = tid & 15;             // n direction: cols tx*4 (+64)
    const int ty = tid >> 4;             // m direction: rows ty*8..+7

    float acc[8][MN];
    #pragma unroll
    for (int i = 0; i < 8; ++i)
        #pragma unroll
        for (int j = 0; j < MN; ++j) acc[i][j] = 0.f;

    for (int k0 = 0; k0 < K; k0 += BK) {
        // stage A tile 128x32 (transposed into LDS): 4 float4 per thread
        #pragma unroll
        for (int it = 0; it < 4; ++it) {
            int qq = tid + 256 * it;
            int m = qq >> 3, kq = qq & 7;
            float4 v4 = *(const float4*)(A + (size_t)(m0 + m) * K + k0 + kq * 4);
            As[kq*4+0][m] = v4.x; As[kq*4+1][m] = v4.y;
            As[kq*4+2][m] = v4.z; As[kq*4+3][m] = v4.w;
        }
        // stage W tile BNx32
        #pragma unroll
        for (int it = 0; it < BN/32; ++it) {
            int qq = tid + 256 * it;
            int n = qq >> 3, kq = qq & 7;
            float4 v4 = *(const float4*)(W + (size_t)(n0 + n) * K + k0 + kq * 4);
            Ws[kq*4+0][n] = v4.x; Ws[kq*4+1][n] = v4.y;
            Ws[kq*4+2][n] = v4.z; Ws[kq*4+3][n] = v4.w;
        }
        __syncthreads();
        for (int kk = 0; kk < BK; ++kk) {
            float a[8], b[MN];
            float4 a0 = *(const float4*)&As[kk][ty*8];
            float4 a1 = *(const float4*)&As[kk][ty*8+4];
            a[0]=a0.x; a[1]=a0.y; a[2]=a0.z; a[3]=a0.w;
            a[4]=a1.x; a[5]=a1.y; a[6]=a1.z; a[7]=a1.w;
            float4 b0 = *(const float4*)&Ws[kk][tx*4];
            b[0]=b0.x; b[1]=b0.y; b[2]=b0.z; b[3]=b0.w;
            if constexpr (MN == 8) {
                float4 b1 = *(const float4*)&Ws[kk][64 + tx*4];
                b[4]=b1.x; b[5]=b1.y; b[6]=b1.z; b[7]=b1.w;
            }
            #pragma unroll
            for (int i = 0; i < 8; ++i)
                #pragma unroll
                for (int j = 0; j < MN; ++j)
                    acc[i][j] = fmaf(a[i], b[j], acc[i][j]);
        }
        __syncthreads();
    }

    // epilogue
    #pragma unroll
    for (int i = 0; i < 8; ++i) {
        int m = m0 + ty*8 + i;
        #pragma unroll
        for (int jb = 0; jb < MN/4; ++jb) {
            int nn = n0 + jb*64 + tx*4;
            float4 r;
            r.x = acc[i][jb*4+0] + bias[nn+0];
            r.y = acc[i][jb*4+1] + bias[nn+1];
            r.z = acc[i][jb*4+2] + bias[nn+2];
            r.w = acc[i][jb*4+3] + bias[nn+3];
            if constexpr (EPI == 1) {
                const float* pp = pos + (size_t)(m & (T_SEQ-1)) * DMODEL + nn;
                r.x += pp[0]; r.y += pp[1]; r.z += pp[2]; r.w += pp[3];
            }
            if constexpr (EPI == 2) {
                r.x = r.x > 0.5f ? 1.f : 0.f;
                r.y = r.y > 0.5f ? 1.f : 0.f;
                r.z = r.z > 0.5f ? 1.f : 0.f;
                r.w = r.w > 0.5f ? 1.f : 0.f;
            }
            if constexpr (LAYOUT == 0) {
                *(float4*)(C + (size_t)m * N + nn) = r;
            } else {
                int b_ = m >> 11, t_ = m & (T_SEQ-1);
                int h_ = nn >> 6, d_ = nn & 63;
                *(float4*)(C + (((size_t)(b_*NHEAD + h_)*T_SEQ + t_) << 6) + d_) = r;
            }
        }
    }
}

// ---------------------------------------------------------------------------
// Transpose: k_plain [B*T, D] -> kT [B, H, dh, T]  (i.e. [B*D, T])
// ---------------------------------------------------------------------------
__global__ __launch_bounds__(256) void transpose_k(
    const float* __restrict__ in, float* __restrict__ out)
{
    __shared__ float tile[32][33];
    const int t0 = blockIdx.x * 32;   // row block (b*T + t)
    const int c0 = blockIdx.y * 32;   // model-dim block
    const int tid = threadIdx.x;
    const int r = tid >> 5;           // 0..7
    const int c = tid & 31;
    #pragma unroll
    for (int i = 0; i < 4; ++i)
        tile[r + 8*i][c] = in[(size_t)(t0 + r + 8*i) * DMODEL + c0 + c];
    __syncthreads();
    #pragma unroll
    for (int i = 0; i < 4; ++i) {
        int n = c0 + r + 8*i;               // model-dim index
        int m = t0 + c;                     // global row
        int b = m >> 11, t = m & (T_SEQ-1);
        out[((size_t)(b * DMODEL + n)) * T_SEQ + t] = tile[c][r + 8*i];
    }
}

// ---------------------------------------------------------------------------
// 64-bit shuffle helper (wave64; partner = lane ^ mask stays in-wave)
// ---------------------------------------------------------------------------
__device__ __forceinline__ unsigned long long shfl_xor_u64(unsigned long long x, int mask) {
    int lo = __shfl_xor((int)(unsigned)(x & 0xffffffffull), mask, 64);
    int hi = __shfl_xor((int)(unsigned)(x >> 32), mask, 64);
    return ((unsigned long long)(unsigned)hi << 32) | (unsigned)(unsigned)lo;
}

// ---------------------------------------------------------------------------
// Fused sparse attention: scores -> exact top-32 (register lists) -> softmax -> AV
// block = 256 thr = one (b,h) x 32 query rows; grid (T/32, B*H)
// q: [B,H,T,dh]  kT: [B,H,dh,T]  v: [B,H,T,dh]  out: [B,T,D] merged heads
//
// Selection: key = (mono(f32 score) << 32) | (2047 - j)  -- exact jax top_k
// tie-break (bigger val first, then smaller index). Each of 8 sub-threads per
// row keeps a sorted top-32 of its 256-element share in VGPRs (straight-line
// insert, no LDS latency). Final: 3 shfl-merge rounds using the bitonic
// identity top32(A,B)[i] = max(a[i], b[31-i]) + 5-stage bitonic clean.
// ---------------------------------------------------------------------------
__global__ __launch_bounds__(256) void attn_k(
    const float* __restrict__ q, const float* __restrict__ kT,
    const float* __restrict__ v, float* __restrict__ out)
{
    __shared__ float qsT[64][36];        // q tile transposed [d][row]
    __shared__ float ksbuf[64*128];      // aliased: ks[64][128] | ss[32][132] | weights

    const int tid = threadIdx.x;
    const int bh  = blockIdx.y;
    const int t0  = blockIdx.x * 32;
    const float* qb = q  + ((size_t)bh * T_SEQ + t0) * DHEAD;
    const float* kb = kT + (size_t)bh * DHEAD * T_SEQ;
    const float* vb = v  + (size_t)bh * T_SEQ * DHEAD;

    #pragma unroll
    for (int it = 0; it < 8; ++it) {
        int e = tid + 256*it;
        qsT[e & 63][e >> 6] = qb[e];     // e = row*64 + d
    }

    unsigned long long kreg[32];         // sorted desc, [31] = current cutoff
    #pragma unroll
    for (int i = 0; i < 32; ++i) kreg[i] = 0ull;

    const int ry = tid >> 5;             // compute: rows ry*4..+3
    const int tx = tid & 31;             // compute: cols tx*4..+3
    const int srow = tid >> 3;           // scan: row 0..31
    const int ssub = tid & 7;            // scan: sub 0..7 (adjacent lanes!)
    float (*ks)[128] = (float(*)[128])ksbuf;
    float (*ss)[132] = (float(*)[132])ksbuf;   // padded stride: scan ~2-way banks

    for (int jt = 0; jt < 16; ++jt) {
        const int j0 = jt * 128;
        // stage k tile [64 d][128 j]
        #pragma unroll
        for (int it = 0; it < 8; ++it) {
            int e = tid + 256*it;
            int d = e >> 5, tq = e & 31;
            *(float4*)&ks[d][tq*4] = *(const float4*)(kb + (size_t)d*T_SEQ + j0 + tq*4);
        }
        __syncthreads();                 // A: qsT + ks ready
        float acc[4][4];
        #pragma unroll
        for (int i = 0; i < 4; ++i)
            #pragma unroll
            for (int j = 0; j < 4; ++j) acc[i][j] = 0.f;
        #pragma unroll 8
        for (int d = 0; d < 64; ++d) {
            float4 qa4 = *(const float4*)&qsT[d][ry*4];
            float4 kb4 = *(const float4*)&ks[d][tx*4];
            float qa[4] = {qa4.x, qa4.y, qa4.z, qa4.w};
            float kv[4] = {kb4.x, kb4.y, kb4.z, kb4.w};
            #pragma unroll
            for (int i = 0; i < 4; ++i)
                #pragma unroll
                for (int j = 0; j < 4; ++j)
                    acc[i][j] = fmaf(qa[i], kv[j], acc[i][j]);
        }
        __syncthreads();                 // B: all ks reads done before overwrite
        #pragma unroll
        for (int i = 0; i < 4; ++i) {
            float4 r4;
            r4.x = acc[i][0]*0.125f; r4.y = acc[i][1]*0.125f;
            r4.z = acc[i][2]*0.125f; r4.w = acc[i][3]*0.125f;
            *(float4*)&ss[ry*4+i][tx*4] = r4;   // scaled by 1/sqrt(64)
        }
        __syncthreads();                 // C: scores visible

        // register top-32 insert: 16 elems/thread, stride-8 (bank-friendly)
        #pragma unroll
        for (int e = 0; e < 16; ++e) {
            int c = ssub + 8*e;
            float val = ss[srow][c];
            unsigned u = __float_as_uint(val);
            u ^= (unsigned)((int)u >> 31) | 0x80000000u;   // monotonic fp32->u32
            unsigned long long key =
                ((unsigned long long)u << 32) | (unsigned)(2047 - (j0 + c));
            if (key > kreg[31]) {
                #pragma unroll
                for (int i = 31; i >= 1; --i) {
                    bool sh   = key > kreg[i-1];
                    bool here = key > kreg[i];
                    kreg[i] = sh ? kreg[i-1] : (here ? key : kreg[i]);
                }
                if (key > kreg[0]) kreg[0] = key;
            }
        }
        __syncthreads();                 // D: scan done before next stage clobbers
    }

    // merge 8 per-sub lists (adjacent lanes) -> every lane ends with global top-32
    #pragma unroll
    for (int s = 1; s <= 4; s <<= 1) {
        #pragma unroll
        for (int i = 0; i < 16; ++i) {
            unsigned long long pa = shfl_xor_u64(kreg[31-i], s); // partner [31-i]
            unsigned long long pb = shfl_xor_u64(kreg[i],    s); // partner [i]
            if (pa > kreg[i])    kreg[i]    = pa;
            if (pb > kreg[31-i]) kreg[31-i] = pb;
        }
        // clean bitonic sequence -> sorted desc (stages 16,8,4,2,1)
        #pragma unroll
        for (int st = 16; st >= 1; st >>= 1) {
            #pragma unroll
            for (int i2 = 0; i2 < 32; ++i2) {
                if ((i2 & st) == 0) {
                    unsigned long long lo = kreg[i2], hi = kreg[i2 | st];
                    kreg[i2]      = lo < hi ? hi : lo;
                    kreg[i2 | st] = lo < hi ? lo : hi;
                }
            }
        }
    }

    // softmax over the kept 32 (equals full-row softmax: exp(-1e9-m)==0 in fp32)
    float* wrow = ksbuf + 4352;                  // 32x32 weights
    int*   irow = (int*)(ksbuf + 4352 + 1024);   // 32x32 indices
    if (ssub == 0) {
        float w[32];
        #pragma unroll
        for (int i = 0; i < 32; ++i) {
            unsigned um = (unsigned)(kreg[i] >> 32);
            unsigned ub = (um & 0x80000000u) ? (um ^ 0x80000000u) : ~um;
            w[i] = __uint_as_float(ub);
        }
        float m = w[0];                  // sorted desc -> max
        float s = 0.f;
        #pragma unroll
        for (int i = 0; i < 32; ++i) { w[i] = expf(w[i] - m); s += w[i]; }
        float inv = 1.f / s;
        #pragma unroll
        for (int i = 0; i < 32; ++i) {
            wrow[srow*32 + i] = w[i] * inv;
            irow[srow*32 + i] = 2047 - (int)(unsigned)(kreg[i] & 0xffffffffull);
        }
    }
    __syncthreads();

    // AV: wave per row-group, lane = head dim
    const int wid = tid >> 6, lane = tid & 63;
    const int b = bh >> 3, h = bh & 7;
    for (int rr = wid; rr < 32; rr += 4) {
        float accv = 0.f;
        #pragma unroll
        for (int i = 0; i < 32; ++i) {
            float wgt = wrow[rr*32 + i];
            int   idx = irow[rr*32 + i];
            accv = fmaf(wgt, vb[(size_t)idx * DHEAD + lane], accv);
        }
        out[((size_t)(b * T_SEQ + t0 + rr)) * DMODEL + h * DHEAD + lane] = accv;
    }
}

// ---------------------------------------------------------------------------
// Rowwise LayerNorm with optional fused residual: out = LN(x [+ res]) * g + b
// block = 256 threads per row of 512
// ---------------------------------------------------------------------------
__global__ __launch_bounds__(256) void ln_k(
    const float* __restrict__ x, const float* __restrict__ res,
    const float* __restrict__ g, const float* __restrict__ bb,
    float* __restrict__ out)
{
    __shared__ float red[8];
    const int row = blockIdx.x;
    const int tid = threadIdx.x;
    const float* xr = x + (size_t)row * DMODEL;
    float v0 = xr[tid], v1 = xr[tid + 256];
    if (res) {
        const float* rr = res + (size_t)row * DMODEL;
        v0 += rr[tid]; v1 += rr[tid + 256];
    }
    float s = v0 + v1;
    #pragma unroll
    for (int o = 1; o < 64; o <<= 1) s += __shfl_xor(s, o);
    const int wid = tid >> 6, lane = tid & 63;
    if (lane == 0) red[wid] = s;
    __syncthreads();
    float mean = (red[0] + red[1] + red[2] + red[3]) * (1.f / DMODEL);
    float d0 = v0 - mean, d1 = v1 - mean;
    float qs = d0*d0 + d1*d1;
    #pragma unroll
    for (int o = 1; o < 64; o <<= 1) qs += __shfl_xor(qs, o);
    if (lane == 0) red[4 + wid] = qs;
    __syncthreads();
    float var = (red[4] + red[5] + red[6] + red[7]) * (1.f / DMODEL);
    float rs = rsqrtf(var + 1e-5f);
    out[(size_t)row * DMODEL + tid]       = d0 * rs * g[tid]       + bb[tid];
    out[(size_t)row * DMODEL + tid + 256] = d1 * rs * g[tid + 256] + bb[tid + 256];
}

// ---------------------------------------------------------------------------
// Mean pool over T:  pooled[b,d] = mean_t h[b,t,d]
// ---------------------------------------------------------------------------
__global__ __launch_bounds__(256) void pool_k(
    const float* __restrict__ h, float* __restrict__ pooled)
{
    int idx = blockIdx.x * 256 + threadIdx.x;    // 0..1023
    int b = idx >> 9, d = idx & 511;
    const float* p = h + (size_t)b * T_SEQ * DMODEL + d;
    float s = 0.f;
    for (int t = 0; t < T_SEQ; ++t) s += p[(size_t)t * DMODEL];
    pooled[idx] = s * (1.f / T_SEQ);
}

// ---------------------------------------------------------------------------
// Classifier: out[b,o] = pooled[b,:] . cls_w[o,:] + cls_b[o]; wave per output
// ---------------------------------------------------------------------------
__global__ __launch_bounds__(256) void cls_k(
    const float* __restrict__ pooled, const float* __restrict__ w,
    const float* __restrict__ bias, float* __restrict__ out)
{
    const int wid = threadIdx.x >> 6, lane = threadIdx.x & 63;
    const int oi = blockIdx.x * 4 + wid;     // 0..511
    const int b = oi >> 8, o = oi & 255;
    const float* pr = pooled + b * DMODEL;
    const float* wr = w + (size_t)o * DMODEL;
    float s = 0.f;
    for (int d = lane; d < DMODEL; d += 64) s = fmaf(pr[d], wr[d], s);
    #pragma unroll
    for (int off = 1; off < 64; off <<= 1) s += __shfl_xor(s, off);
    if (lane == 0) out[oi] = s + bias[o];
}

// ---------------------------------------------------------------------------
extern "C" void kernel_launch(void* const* d_in, const int* in_sizes, int n_in,
                              void* d_out, int out_size, void* d_ws, size_t ws_size,
                              hipStream_t stream)
{
    const float* x     = (const float*)d_in[0];
    const float* emb_w = (const float*)d_in[1];
    const float* emb_b = (const float*)d_in[2];
    const float* pos   = (const float*)d_in[3];
    const float* wq    = (const float*)d_in[4];
    const float* bq    = (const float*)d_in[5];
    const float* wk    = (const float*)d_in[6];
    const float* bk    = (const float*)d_in[7];
    const float* wv    = (const float*)d_in[8];
    const float* bv    = (const float*)d_in[9];
    const float* wo    = (const float*)d_in[10];
    const float* bo    = (const float*)d_in[11];
    const float* ln1g  = (const float*)d_in[12];
    const float* ln1b  = (const float*)d_in[13];
    const float* fc1w  = (const float*)d_in[14];
    const float* fc1b  = (const float*)d_in[15];
    const float* fc2w  = (const float*)d_in[16];
    const float* fc2b  = (const float*)d_in[17];
    const float* ln2g  = (const float*)d_in[18];
    const float* ln2b  = (const float*)d_in[19];
    const float* fng   = (const float*)d_in[20];
    const float* fnb   = (const float*)d_in[21];
    const float* clsw  = (const float*)d_in[22];
    const float* clsb  = (const float*)d_in[23];

    float* ws = (float*)d_ws;
    const size_t SZ = (size_t)MROWS * DMODEL;        // 2M floats
    float* h    = ws;                                // [4096,512]
    float* qb   = ws + 1*SZ;                         // q heads
    float* kTb  = ws + 2*SZ;                         // kT
    float* vbuf = ws + 3*SZ;                         // v heads
    float* t1   = ws + 4*SZ;                         // a / f
    float* h1   = ws + 5*SZ;                         // [4096,2048]: kp / attn_out / ffn hidden
    float* pooled = ws + 5*SZ + (size_t)MROWS * FDIM;
    const size_t needed = (5*SZ + (size_t)MROWS*FDIM + (size_t)NB*DMODEL) * sizeof(float);
    if (ws_size < needed) return;   // workspace too small -> visible failure

    dim3 blk(256);

    // embedding: h = x @ emb_w^T + emb_b + pos
    gemm_k<64,1,0><<<dim3(DMODEL/64, MROWS/128), blk, 0, stream>>>(
        x, emb_w, emb_b, pos, h, MROWS, DMODEL, 128);

    for (int l = 0; l < NLAYER; ++l) {
        const float* wq_l = wq + (size_t)l*DMODEL*DMODEL;
        const float* bq_l = bq + (size_t)l*DMODEL;
        const float* wk_l = wk + (size_t)l*DMODEL*DMODEL;
        const float* bk_l = bk + (size_t)l*DMODEL;
        const float* wv_l = wv + (size_t)l*DMODEL*DMODEL;
        const float* bv_l = bv + (size_t)l*DMODEL;
        const float* wo_l = wo + (size_t)l*DMODEL*DMODEL;
        const float* bo_l = bo + (size_t)l*DMODEL;
        const float* f1w_l = fc1w + (size_t)l*FDIM*DMODEL;
        const float* f1b_l = fc1b + (size_t)l*FDIM;
        const float* f2w_l = fc2w + (size_t)l*DMODEL*FDIM;
        const float* f2b_l = fc2b + (size_t)l*DMODEL;

        // q, k, v projections
        gemm_k<64,0,1><<<dim3(8,32), blk, 0, stream>>>(h, wq_l, bq_l, nullptr, qb,  MROWS, DMODEL, DMODEL);
        gemm_k<64,0,0><<<dim3(8,32), blk, 0, stream>>>(h, wk_l, bk_l, nullptr, h1,  MROWS, DMODEL, DMODEL);
        transpose_k<<<dim3(MROWS/32, DMODEL/32), blk, 0, stream>>>(h1, kTb);
        gemm_k<64,0,1><<<dim3(8,32), blk, 0, stream>>>(h, wv_l, bv_l, nullptr, vbuf, MROWS, DMODEL, DMODEL);

        // fused top-k attention -> h1 (merged heads [B,T,D])
        attn_k<<<dim3(T_SEQ/32, NB*NHEAD), blk, 0, stream>>>(qb, kTb, vbuf, h1);

        // output projection + spike -> t1
        gemm_k<64,2,0><<<dim3(8,32), blk, 0, stream>>>(h1, wo_l, bo_l, nullptr, t1, MROWS, DMODEL, DMODEL);
        // h = LN(h + a)
        ln_k<<<dim3(MROWS), blk, 0, stream>>>(h, t1, ln1g + (size_t)l*DMODEL, ln1b + (size_t)l*DMODEL, h);

        // FFN
        gemm_k<128,2,0><<<dim3(FDIM/128, 32), blk, 0, stream>>>(h,  f1w_l, f1b_l, nullptr, h1, MROWS, FDIM,   DMODEL);
        gemm_k<64,2,0> <<<dim3(8,32),        blk, 0, stream>>>(h1, f2w_l, f2b_l, nullptr, t1, MROWS, DMODEL, FDIM);
        // h = LN(h + f)
        ln_k<<<dim3(MROWS), blk, 0, stream>>>(h, t1, ln2g + (size_t)l*DMODEL, ln2b + (size_t)l*DMODEL, h);
    }

    // final norm, pool, classify
    ln_k<<<dim3(MROWS), blk, 0, stream>>>(h, nullptr, fng, fnb, h);
    pool_k<<<dim3(4), blk, 0, stream>>>(h, pooled);
    cls_k<<<dim3(128), blk, 0, stream>>>(pooled, clsw, clsb, (float*)d_out);
}

// Round 3
// 3889.458 us; speedup vs baseline: 3.8199x; 1.6657x over previous
//
#include <hip/hip_runtime.h>
#include <math.h>
#include <float.h>

#define T_SEQ  2048
#define DMODEL 512
#define NHEAD  8
#define DHEAD  64
#define FDIM   2048
#define NLAYER 4
#define NB     2
#define MROWS  (NB*T_SEQ)   // 4096

// ---------------------------------------------------------------------------
// GEMM: C = A[M,K] @ W[N,K]^T + bias[N], fp32 vector-FMA, BM=128, BK=32.
// EPI: 0 = none, 1 = +pos_emb[m%T][n] (embedding), 2 = spike (x>0.5 ? 1 : 0)
// LAYOUT: 0 = plain row-major [M,N], 1 = head layout [B,H,T,dh]
// ---------------------------------------------------------------------------
template<int BN, int EPI, int LAYOUT>
__global__ __launch_bounds__(256) void gemm_k(
    const float* __restrict__ A, const float* __restrict__ W,
    const float* __restrict__ bias, const float* __restrict__ pos,
    float* __restrict__ C, int M, int N, int K)
{
    constexpr int BM = 128;
    constexpr int BK = 32;
    constexpr int MN = BN / 16;          // 4 (BN=64) or 8 (BN=128)
    __shared__ float As[BK][BM + 4];     // [k][m], pad 4 keeps 16B align
    __shared__ float Ws[BK][BN + 4];     // [k][n]
    const int tid = threadIdx.x;
    const int n0 = blockIdx.x * BN;
    const int m0 = blockIdx.y * BM;
    const int tx = tid & 15;             // n direction: cols tx*4 (+64)
    const int ty = tid >> 4;             // m direction: rows ty*8..+7

    float acc[8][MN];
    #pragma unroll
    for (int i = 0; i < 8; ++i)
        #pragma unroll
        for (int j = 0; j < MN; ++j) acc[i][j] = 0.f;

    for (int k0 = 0; k0 < K; k0 += BK) {
        // stage A tile 128x32 (transposed into LDS): 4 float4 per thread
        #pragma unroll
        for (int it = 0; it < 4; ++it) {
            int qq = tid + 256 * it;
            int m = qq >> 3, kq = qq & 7;
            float4 v4 = *(const float4*)(A + (size_t)(m0 + m) * K + k0 + kq * 4);
            As[kq*4+0][m] = v4.x; As[kq*4+1][m] = v4.y;
            As[kq*4+2][m] = v4.z; As[kq*4+3][m] = v4.w;
        }
        // stage W tile BNx32
        #pragma unroll
        for (int it = 0; it < BN/32; ++it) {
            int qq = tid + 256 * it;
            int n = qq >> 3, kq = qq & 7;
            float4 v4 = *(const float4*)(W + (size_t)(n0 + n) * K + k0 + kq * 4);
            Ws[kq*4+0][n] = v4.x; Ws[kq*4+1][n] = v4.y;
            Ws[kq*4+2][n] = v4.z; Ws[kq*4+3][n] = v4.w;
        }
        __syncthreads();
        for (int kk = 0; kk < BK; ++kk) {
            float a[8], b[MN];
            float4 a0 = *(const float4*)&As[kk][ty*8];
            float4 a1 = *(const float4*)&As[kk][ty*8+4];
            a[0]=a0.x; a[1]=a0.y; a[2]=a0.z; a[3]=a0.w;
            a[4]=a1.x; a[5]=a1.y; a[6]=a1.z; a[7]=a1.w;
            float4 b0 = *(const float4*)&Ws[kk][tx*4];
            b[0]=b0.x; b[1]=b0.y; b[2]=b0.z; b[3]=b0.w;
            if constexpr (MN == 8) {
                float4 b1 = *(const float4*)&Ws[kk][64 + tx*4];
                b[4]=b1.x; b[5]=b1.y; b[6]=b1.z; b[7]=b1.w;
            }
            #pragma unroll
            for (int i = 0; i < 8; ++i)
                #pragma unroll
                for (int j = 0; j < MN; ++j)
                    acc[i][j] = fmaf(a[i], b[j], acc[i][j]);
        }
        __syncthreads();
    }

    // epilogue
    #pragma unroll
    for (int i = 0; i < 8; ++i) {
        int m = m0 + ty*8 + i;
        #pragma unroll
        for (int jb = 0; jb < MN/4; ++jb) {
            int nn = n0 + jb*64 + tx*4;
            float4 r;
            r.x = acc[i][jb*4+0] + bias[nn+0];
            r.y = acc[i][jb*4+1] + bias[nn+1];
            r.z = acc[i][jb*4+2] + bias[nn+2];
            r.w = acc[i][jb*4+3] + bias[nn+3];
            if constexpr (EPI == 1) {
                const float* pp = pos + (size_t)(m & (T_SEQ-1)) * DMODEL + nn;
                r.x += pp[0]; r.y += pp[1]; r.z += pp[2]; r.w += pp[3];
            }
            if constexpr (EPI == 2) {
                r.x = r.x > 0.5f ? 1.f : 0.f;
                r.y = r.y > 0.5f ? 1.f : 0.f;
                r.z = r.z > 0.5f ? 1.f : 0.f;
                r.w = r.w > 0.5f ? 1.f : 0.f;
            }
            if constexpr (LAYOUT == 0) {
                *(float4*)(C + (size_t)m * N + nn) = r;
            } else {
                int b_ = m >> 11, t_ = m & (T_SEQ-1);
                int h_ = nn >> 6, d_ = nn & 63;
                *(float4*)(C + (((size_t)(b_*NHEAD + h_)*T_SEQ + t_) << 6) + d_) = r;
            }
        }
    }
}

// ---------------------------------------------------------------------------
// Transpose: k_plain [B*T, D] -> kT [B, H, dh, T]  (i.e. [B*D, T])
// ---------------------------------------------------------------------------
__global__ __launch_bounds__(256) void transpose_k(
    const float* __restrict__ in, float* __restrict__ out)
{
    __shared__ float tile[32][33];
    const int t0 = blockIdx.x * 32;   // row block (b*T + t)
    const int c0 = blockIdx.y * 32;   // model-dim block
    const int tid = threadIdx.x;
    const int r = tid >> 5;           // 0..7
    const int c = tid & 31;
    #pragma unroll
    for (int i = 0; i < 4; ++i)
        tile[r + 8*i][c] = in[(size_t)(t0 + r + 8*i) * DMODEL + c0 + c];
    __syncthreads();
    #pragma unroll
    for (int i = 0; i < 4; ++i) {
        int n = c0 + r + 8*i;               // model-dim index
        int m = t0 + c;                     // global row
        int b = m >> 11, t = m & (T_SEQ-1);
        out[((size_t)(b * DMODEL + n)) * T_SEQ + t] = tile[c][r + 8*i];
    }
}

// ---------------------------------------------------------------------------
// 64-bit shuffle helper (wave64; partner = lane ^ mask stays in-wave)
// ---------------------------------------------------------------------------
__device__ __forceinline__ unsigned long long shfl_xor_u64(unsigned long long x, int mask) {
    int lo = __shfl_xor((int)(unsigned)(x & 0xffffffffull), mask, 64);
    int hi = __shfl_xor((int)(unsigned)(x >> 32), mask, 64);
    return ((unsigned long long)(unsigned)hi << 32) | (unsigned)(unsigned)lo;
}

// ---------------------------------------------------------------------------
// Fused sparse attention: scores -> exact top-32 -> softmax -> AV
// block = 256 thr = one (b,h) x 32 query rows; grid (T/32, B*H)
// q: [B,H,T,dh]  kT: [B,H,dh,T]  v: [B,H,T,dh]  out: [B,T,D] merged heads
//
// key = (mono(f32 score) << 32) | (2047 - j)  -- exact jax top_k tie-break.
// Per tile: each of 8 lanes/row reads 16 candidates (4x b128), bitonic-SORTS
// them (branch-free, 80 comparators), merges into its running sorted top-32
// via the bitonic top-k identity kreg[16+j] = max(kreg[16+j], cand[15-j])
// (exact: multiset == top-32 of union) then a 5-stage bitonic clean. No
// divergence, no dependent-LDS chains. Next K tile register-prefetched so
// global latency hides behind the sort.
// ---------------------------------------------------------------------------
__global__ __launch_bounds__(256) void attn_k(
    const float* __restrict__ q, const float* __restrict__ kT,
    const float* __restrict__ v, float* __restrict__ out)
{
    __shared__ float qsT[64][36];        // q tile transposed [d][row]
    __shared__ float ksbuf[64*128];      // aliased: ks[64][128] | ss[32][132] | w/idx

    const int tid = threadIdx.x;
    const int bh  = blockIdx.y;
    const int t0  = blockIdx.x * 32;
    const float* qb = q  + ((size_t)bh * T_SEQ + t0) * DHEAD;
    const float* kb = kT + (size_t)bh * DHEAD * T_SEQ;
    const float* vb = v  + (size_t)bh * T_SEQ * DHEAD;

    // prefetch K tile 0 into registers
    float4 pf[8];
    {
        const int d = tid >> 5, tq = tid & 31;
        #pragma unroll
        for (int it = 0; it < 8; ++it)
            pf[it] = *(const float4*)(kb + (size_t)(d + 8*it)*T_SEQ + tq*4);
    }
    #pragma unroll
    for (int it = 0; it < 8; ++it) {
        int e = tid + 256*it;
        qsT[e & 63][e >> 6] = qb[e];     // e = row*64 + d
    }

    unsigned long long kreg[32];         // running top-32, sorted desc
    #pragma unroll
    for (int i = 0; i < 32; ++i) kreg[i] = 0ull;   // < any real score key

    const int ry = tid >> 5;             // compute: rows ry*4..+3
    const int tx = tid & 31;             // compute: cols tx*4..+3
    const int srow = tid >> 3;           // scan: row 0..31
    const int ssub = tid & 7;            // scan: sub 0..7
    float (*ks)[128] = (float(*)[128])ksbuf;
    float (*ss)[132] = (float(*)[132])ksbuf;   // stride 132 words (16B-aligned)

    for (int jt = 0; jt < 16; ++jt) {
        const int j0 = jt * 128;
        // write prefetched K tile to LDS [64 d][128 j]
        {
            const int d = tid >> 5, tq = tid & 31;
            #pragma unroll
            for (int it = 0; it < 8; ++it)
                *(float4*)&ks[d + 8*it][tq*4] = pf[it];
        }
        __syncthreads();                 // A: qsT + ks ready
        float acc[4][4];
        #pragma unroll
        for (int i = 0; i < 4; ++i)
            #pragma unroll
            for (int j = 0; j < 4; ++j) acc[i][j] = 0.f;
        #pragma unroll 8
        for (int d = 0; d < 64; ++d) {
            float4 qa4 = *(const float4*)&qsT[d][ry*4];
            float4 kb4 = *(const float4*)&ks[d][tx*4];
            float qa[4] = {qa4.x, qa4.y, qa4.z, qa4.w};
            float kv[4] = {kb4.x, kb4.y, kb4.z, kb4.w};
            #pragma unroll
            for (int i = 0; i < 4; ++i)
                #pragma unroll
                for (int j = 0; j < 4; ++j)
                    acc[i][j] = fmaf(qa[i], kv[j], acc[i][j]);
        }
        // issue next tile's global loads (consumed at next iter's LDS write)
        if (jt < 15) {
            const int d = tid >> 5, tq = tid & 31;
            const float* kbn = kb + (j0 + 128) + tq*4;
            #pragma unroll
            for (int it = 0; it < 8; ++it)
                pf[it] = *(const float4*)(kbn + (size_t)(d + 8*it)*T_SEQ);
        }
        __syncthreads();                 // B: all ks reads done before overwrite
        #pragma unroll
        for (int i = 0; i < 4; ++i) {
            float4 r4;
            r4.x = acc[i][0]*0.125f; r4.y = acc[i][1]*0.125f;
            r4.z = acc[i][2]*0.125f; r4.w = acc[i][3]*0.125f;
            *(float4*)&ss[ry*4+i][tx*4] = r4;   // scaled by 1/sqrt(64)
        }
        __syncthreads();                 // C: scores visible

        // ---- branch-free selection: 16 candidates, cols ssub*4 + g*32 + r
        float4 c4[4];
        {
            const float* ssr = &ss[srow][0] + ssub*4;
            #pragma unroll
            for (int g = 0; g < 4; ++g) c4[g] = *(const float4*)(ssr + g*32);
        }
        unsigned long long cand[16];
        #pragma unroll
        for (int g = 0; g < 4; ++g) {
            float vg[4] = {c4[g].x, c4[g].y, c4[g].z, c4[g].w};
            #pragma unroll
            for (int r = 0; r < 4; ++r) {
                unsigned u = __float_as_uint(vg[r]);
                u ^= (unsigned)((int)u >> 31) | 0x80000000u;   // monotonic map
                int col = ssub*4 + g*32 + r;
                cand[g*4+r] = ((unsigned long long)u << 32) | (unsigned)(2047 - (j0 + col));
            }
        }
        // bitonic sort-16 descending (fully unrolled, compile-time indices)
        #pragma unroll
        for (int k2 = 2; k2 <= 16; k2 <<= 1) {
            #pragma unroll
            for (int j2 = k2 >> 1; j2 > 0; j2 >>= 1) {
                #pragma unroll
                for (int i2 = 0; i2 < 16; ++i2) {
                    int l2 = i2 ^ j2;
                    if (l2 > i2) {
                        unsigned long long a = cand[i2], b = cand[l2];
                        bool sw = ((i2 & k2) == 0) ? (a < b) : (a > b);
                        cand[i2] = sw ? b : a;
                        cand[l2] = sw ? a : b;
                    }
                }
            }
        }
        // merge: top-32(kreg ∪ cand) — bitonic top-k identity
        #pragma unroll
        for (int j2 = 0; j2 < 16; ++j2) {
            unsigned long long b = cand[15 - j2];
            if (kreg[16 + j2] < b) kreg[16 + j2] = b;
        }
        // clean bitonic-32 -> sorted desc
        #pragma unroll
        for (int st = 16; st >= 1; st >>= 1) {
            #pragma unroll
            for (int i2 = 0; i2 < 32; ++i2) {
                if ((i2 & st) == 0) {
                    unsigned long long lo = kreg[i2], hi = kreg[i2 | st];
                    kreg[i2]      = lo < hi ? hi : lo;
                    kreg[i2 | st] = lo < hi ? lo : hi;
                }
            }
        }
        __syncthreads();                 // D: scan done before next ks write
    }

    // merge 8 per-sub lists (lane^1,2,4) -> every lane has global top-32
    #pragma unroll
    for (int s = 1; s <= 4; s <<= 1) {
        #pragma unroll
        for (int i = 0; i < 16; ++i) {
            unsigned long long pa = shfl_xor_u64(kreg[31-i], s);
            unsigned long long pb = shfl_xor_u64(kreg[i],    s);
            if (pa > kreg[i])    kreg[i]    = pa;
            if (pb > kreg[31-i]) kreg[31-i] = pb;
        }
        #pragma unroll
        for (int st = 16; st >= 1; st >>= 1) {
            #pragma unroll
            for (int i2 = 0; i2 < 32; ++i2) {
                if ((i2 & st) == 0) {
                    unsigned long long lo = kreg[i2], hi = kreg[i2 | st];
                    kreg[i2]      = lo < hi ? hi : lo;
                    kreg[i2 | st] = lo < hi ? lo : hi;
                }
            }
        }
    }

    // softmax over kept 32 (== full-row softmax: exp(-1e9-m) == 0 in fp32)
    float* wrow = ksbuf + 4352;                  // 32 x stride-33 weights
    int*   irow = (int*)(ksbuf + 4352 + 1088);   // 32 x stride-33 indices
    if (ssub == 0) {
        float w[32];
        #pragma unroll
        for (int i = 0; i < 32; ++i) {
            unsigned um = (unsigned)(kreg[i] >> 32);
            unsigned ub = (um & 0x80000000u) ? (um ^ 0x80000000u) : ~um;
            w[i] = __uint_as_float(ub);
        }
        float m = w[0];                  // sorted desc -> max
        float s = 0.f;
        #pragma unroll
        for (int i = 0; i < 32; ++i) { w[i] = expf(w[i] - m); s += w[i]; }
        float inv = 1.f / s;
        #pragma unroll
        for (int i = 0; i < 32; ++i) {
            wrow[srow*33 + i] = w[i] * inv;
            irow[srow*33 + i] = 2047 - (int)(unsigned)(kreg[i] & 0xffffffffull);
        }
    }
    __syncthreads();

    // AV: wave per row-group, lane = head dim
    const int wid = tid >> 6, lane = tid & 63;
    const int b = bh >> 3, h = bh & 7;
    for (int rr = wid; rr < 32; rr += 4) {
        float accv = 0.f;
        #pragma unroll
        for (int i = 0; i < 32; ++i) {
            float wgt = wrow[rr*33 + i];
            int   idx = irow[rr*33 + i];
            accv = fmaf(wgt, vb[(size_t)idx * DHEAD + lane], accv);
        }
        out[((size_t)(b * T_SEQ + t0 + rr)) * DMODEL + h * DHEAD + lane] = accv;
    }
}

// ---------------------------------------------------------------------------
// Rowwise LayerNorm with optional fused residual: out = LN(x [+ res]) * g + b
// ---------------------------------------------------------------------------
__global__ __launch_bounds__(256) void ln_k(
    const float* __restrict__ x, const float* __restrict__ res,
    const float* __restrict__ g, const float* __restrict__ bb,
    float* __restrict__ out)
{
    __shared__ float red[8];
    const int row = blockIdx.x;
    const int tid = threadIdx.x;
    const float* xr = x + (size_t)row * DMODEL;
    float v0 = xr[tid], v1 = xr[tid + 256];
    if (res) {
        const float* rr = res + (size_t)row * DMODEL;
        v0 += rr[tid]; v1 += rr[tid + 256];
    }
    float s = v0 + v1;
    #pragma unroll
    for (int o = 1; o < 64; o <<= 1) s += __shfl_xor(s, o);
    const int wid = tid >> 6, lane = tid & 63;
    if (lane == 0) red[wid] = s;
    __syncthreads();
    float mean = (red[0] + red[1] + red[2] + red[3]) * (1.f / DMODEL);
    float d0 = v0 - mean, d1 = v1 - mean;
    float qs = d0*d0 + d1*d1;
    #pragma unroll
    for (int o = 1; o < 64; o <<= 1) qs += __shfl_xor(qs, o);
    if (lane == 0) red[4 + wid] = qs;
    __syncthreads();
    float var = (red[4] + red[5] + red[6] + red[7]) * (1.f / DMODEL);
    float rs = rsqrtf(var + 1e-5f);
    out[(size_t)row * DMODEL + tid]       = d0 * rs * g[tid]       + bb[tid];
    out[(size_t)row * DMODEL + tid + 256] = d1 * rs * g[tid + 256] + bb[tid + 256];
}

// ---------------------------------------------------------------------------
// Mean pool over T:  pooled[b,d] = mean_t h[b,t,d]
// ---------------------------------------------------------------------------
__global__ __launch_bounds__(256) void pool_k(
    const float* __restrict__ h, float* __restrict__ pooled)
{
    int idx = blockIdx.x * 256 + threadIdx.x;    // 0..1023
    int b = idx >> 9, d = idx & 511;
    const float* p = h + (size_t)b * T_SEQ * DMODEL + d;
    float s = 0.f;
    for (int t = 0; t < T_SEQ; ++t) s += p[(size_t)t * DMODEL];
    pooled[idx] = s * (1.f / T_SEQ);
}

// ---------------------------------------------------------------------------
// Classifier: out[b,o] = pooled[b,:] . cls_w[o,:] + cls_b[o]; wave per output
// ---------------------------------------------------------------------------
__global__ __launch_bounds__(256) void cls_k(
    const float* __restrict__ pooled, const float* __restrict__ w,
    const float* __restrict__ bias, float* __restrict__ out)
{
    const int wid = threadIdx.x >> 6, lane = threadIdx.x & 63;
    const int oi = blockIdx.x * 4 + wid;     // 0..511
    const int b = oi >> 8, o = oi & 255;
    const float* pr = pooled + b * DMODEL;
    const float* wr = w + (size_t)o * DMODEL;
    float s = 0.f;
    for (int d = lane; d < DMODEL; d += 64) s = fmaf(pr[d], wr[d], s);
    #pragma unroll
    for (int off = 1; off < 64; off <<= 1) s += __shfl_xor(s, off);
    if (lane == 0) out[oi] = s + bias[o];
}

// ---------------------------------------------------------------------------
extern "C" void kernel_launch(void* const* d_in, const int* in_sizes, int n_in,
                              void* d_out, int out_size, void* d_ws, size_t ws_size,
                              hipStream_t stream)
{
    const float* x     = (const float*)d_in[0];
    const float* emb_w = (const float*)d_in[1];
    const float* emb_b = (const float*)d_in[2];
    const float* pos   = (const float*)d_in[3];
    const float* wq    = (const float*)d_in[4];
    const float* bq    = (const float*)d_in[5];
    const float* wk    = (const float*)d_in[6];
    const float* bk    = (const float*)d_in[7];
    const float* wv    = (const float*)d_in[8];
    const float* bv    = (const float*)d_in[9];
    const float* wo    = (const float*)d_in[10];
    const float* bo    = (const float*)d_in[11];
    const float* ln1g  = (const float*)d_in[12];
    const float* ln1b  = (const float*)d_in[13];
    const float* fc1w  = (const float*)d_in[14];
    const float* fc1b  = (const float*)d_in[15];
    const float* fc2w  = (const float*)d_in[16];
    const float* fc2b  = (const float*)d_in[17];
    const float* ln2g  = (const float*)d_in[18];
    const float* ln2b  = (const float*)d_in[19];
    const float* fng   = (const float*)d_in[20];
    const float* fnb   = (const float*)d_in[21];
    const float* clsw  = (const float*)d_in[22];
    const float* clsb  = (const float*)d_in[23];

    float* ws = (float*)d_ws;
    const size_t SZ = (size_t)MROWS * DMODEL;        // 2M floats
    float* h    = ws;                                // [4096,512]
    float* qb   = ws + 1*SZ;                         // q heads
    float* kTb  = ws + 2*SZ;                         // kT
    float* vbuf = ws + 3*SZ;                         // v heads
    float* t1   = ws + 4*SZ;                         // a / f
    float* h1   = ws + 5*SZ;                         // [4096,2048]
    float* pooled = ws + 5*SZ + (size_t)MROWS * FDIM;
    const size_t needed = (5*SZ + (size_t)MROWS*FDIM + (size_t)NB*DMODEL) * sizeof(float);
    if (ws_size < needed) return;

    dim3 blk(256);

    // embedding: h = x @ emb_w^T + emb_b + pos
    gemm_k<64,1,0><<<dim3(DMODEL/64, MROWS/128), blk, 0, stream>>>(
        x, emb_w, emb_b, pos, h, MROWS, DMODEL, 128);

    for (int l = 0; l < NLAYER; ++l) {
        const float* wq_l = wq + (size_t)l*DMODEL*DMODEL;
        const float* bq_l = bq + (size_t)l*DMODEL;
        const float* wk_l = wk + (size_t)l*DMODEL*DMODEL;
        const float* bk_l = bk + (size_t)l*DMODEL;
        const float* wv_l = wv + (size_t)l*DMODEL*DMODEL;
        const float* bv_l = bv + (size_t)l*DMODEL;
        const float* wo_l = wo + (size_t)l*DMODEL*DMODEL;
        const float* bo_l = bo + (size_t)l*DMODEL;
        const float* f1w_l = fc1w + (size_t)l*FDIM*DMODEL;
        const float* f1b_l = fc1b + (size_t)l*FDIM;
        const float* f2w_l = fc2w + (size_t)l*DMODEL*FDIM;
        const float* f2b_l = fc2b + (size_t)l*DMODEL;

        // q, k, v projections
        gemm_k<64,0,1><<<dim3(8,32), blk, 0, stream>>>(h, wq_l, bq_l, nullptr, qb,  MROWS, DMODEL, DMODEL);
        gemm_k<64,0,0><<<dim3(8,32), blk, 0, stream>>>(h, wk_l, bk_l, nullptr, h1,  MROWS, DMODEL, DMODEL);
        transpose_k<<<dim3(MROWS/32, DMODEL/32), blk, 0, stream>>>(h1, kTb);
        gemm_k<64,0,1><<<dim3(8,32), blk, 0, stream>>>(h, wv_l, bv_l, nullptr, vbuf, MROWS, DMODEL, DMODEL);

        // fused top-k attention -> h1 (merged heads [B,T,D])
        attn_k<<<dim3(T_SEQ/32, NB*NHEAD), blk, 0, stream>>>(qb, kTb, vbuf, h1);

        // output projection + spike -> t1
        gemm_k<64,2,0><<<dim3(8,32), blk, 0, stream>>>(h1, wo_l, bo_l, nullptr, t1, MROWS, DMODEL, DMODEL);
        // h = LN(h + a)
        ln_k<<<dim3(MROWS), blk, 0, stream>>>(h, t1, ln1g + (size_t)l*DMODEL, ln1b + (size_t)l*DMODEL, h);

        // FFN
        gemm_k<128,2,0><<<dim3(FDIM/128, 32), blk, 0, stream>>>(h,  f1w_l, f1b_l, nullptr, h1, MROWS, FDIM,   DMODEL);
        gemm_k<64,2,0> <<<dim3(8,32),        blk, 0, stream>>>(h1, f2w_l, f2b_l, nullptr, t1, MROWS, DMODEL, FDIM);
        // h = LN(h + f)
        ln_k<<<dim3(MROWS), blk, 0, stream>>>(h, t1, ln2g + (size_t)l*DMODEL, ln2b + (size_t)l*DMODEL, h);
    }

    // final norm, pool, classify
    ln_k<<<dim3(MROWS), blk, 0, stream>>>(h, nullptr, fng, fnb, h);
    pool_k<<<dim3(4), blk, 0, stream>>>(h, pooled);
    cls_k<<<dim3(128), blk, 0, stream>>>(pooled, clsw, clsb, (float*)d_out);
}

// Round 4
// 2677.790 us; speedup vs baseline: 5.5483x; 1.4525x over previous
//
#include <hip/hip_runtime.h>
#include <math.h>
#include <float.h>

#define T_SEQ  2048
#define DMODEL 512
#define NHEAD  8
#define DHEAD  64
#define FDIM   2048
#define NLAYER 4
#define NB     2
#define MROWS  (NB*T_SEQ)   // 4096

typedef _Float16 f16x8 __attribute__((ext_vector_type(8)));
typedef float    f32x4 __attribute__((ext_vector_type(4)));

// ---------------------------------------------------------------------------
// fp32 vector GEMM — kept only for the embedding (K=128, 0.5 GF)
// ---------------------------------------------------------------------------
template<int BN, int EPI, int LAYOUT>
__global__ __launch_bounds__(256) void gemm_k(
    const float* __restrict__ A, const float* __restrict__ W,
    const float* __restrict__ bias, const float* __restrict__ pos,
    float* __restrict__ C, int M, int N, int K)
{
    constexpr int BM = 128;
    constexpr int BK = 32;
    constexpr int MN = BN / 16;
    __shared__ float As[BK][BM + 4];
    __shared__ float Ws[BK][BN + 4];
    const int tid = threadIdx.x;
    const int n0 = blockIdx.x * BN;
    const int m0 = blockIdx.y * BM;
    const int tx = tid & 15;
    const int ty = tid >> 4;

    float acc[8][MN];
    #pragma unroll
    for (int i = 0; i < 8; ++i)
        #pragma unroll
        for (int j = 0; j < MN; ++j) acc[i][j] = 0.f;

    for (int k0 = 0; k0 < K; k0 += BK) {
        #pragma unroll
        for (int it = 0; it < 4; ++it) {
            int qq = tid + 256 * it;
            int m = qq >> 3, kq = qq & 7;
            float4 v4 = *(const float4*)(A + (size_t)(m0 + m) * K + k0 + kq * 4);
            As[kq*4+0][m] = v4.x; As[kq*4+1][m] = v4.y;
            As[kq*4+2][m] = v4.z; As[kq*4+3][m] = v4.w;
        }
        #pragma unroll
        for (int it = 0; it < BN/32; ++it) {
            int qq = tid + 256 * it;
            int n = qq >> 3, kq = qq & 7;
            float4 v4 = *(const float4*)(W + (size_t)(n0 + n) * K + k0 + kq * 4);
            Ws[kq*4+0][n] = v4.x; Ws[kq*4+1][n] = v4.y;
            Ws[kq*4+2][n] = v4.z; Ws[kq*4+3][n] = v4.w;
        }
        __syncthreads();
        for (int kk = 0; kk < BK; ++kk) {
            float a[8], b[MN];
            float4 a0 = *(const float4*)&As[kk][ty*8];
            float4 a1 = *(const float4*)&As[kk][ty*8+4];
            a[0]=a0.x; a[1]=a0.y; a[2]=a0.z; a[3]=a0.w;
            a[4]=a1.x; a[5]=a1.y; a[6]=a1.z; a[7]=a1.w;
            float4 b0 = *(const float4*)&Ws[kk][tx*4];
            b[0]=b0.x; b[1]=b0.y; b[2]=b0.z; b[3]=b0.w;
            if constexpr (MN == 8) {
                float4 b1 = *(const float4*)&Ws[kk][64 + tx*4];
                b[4]=b1.x; b[5]=b1.y; b[6]=b1.z; b[7]=b1.w;
            }
            #pragma unroll
            for (int i = 0; i < 8; ++i)
                #pragma unroll
                for (int j = 0; j < MN; ++j)
                    acc[i][j] = fmaf(a[i], b[j], acc[i][j]);
        }
        __syncthreads();
    }

    #pragma unroll
    for (int i = 0; i < 8; ++i) {
        int m = m0 + ty*8 + i;
        #pragma unroll
        for (int jb = 0; jb < MN/4; ++jb) {
            int nn = n0 + jb*64 + tx*4;
            float4 r;
            r.x = acc[i][jb*4+0] + bias[nn+0];
            r.y = acc[i][jb*4+1] + bias[nn+1];
            r.z = acc[i][jb*4+2] + bias[nn+2];
            r.w = acc[i][jb*4+3] + bias[nn+3];
            if constexpr (EPI == 1) {
                const float* pp = pos + (size_t)(m & (T_SEQ-1)) * DMODEL + nn;
                r.x += pp[0]; r.y += pp[1]; r.z += pp[2]; r.w += pp[3];
            }
            if constexpr (EPI == 2) {
                r.x = r.x > 0.5f ? 1.f : 0.f;
                r.y = r.y > 0.5f ? 1.f : 0.f;
                r.z = r.z > 0.5f ? 1.f : 0.f;
                r.w = r.w > 0.5f ? 1.f : 0.f;
            }
            if constexpr (LAYOUT == 0) {
                *(float4*)(C + (size_t)m * N + nn) = r;
            } else {
                int b_ = m >> 11, t_ = m & (T_SEQ-1);
                int h_ = nn >> 6, d_ = nn & 63;
                *(float4*)(C + (((size_t)(b_*NHEAD + h_)*T_SEQ + t_) << 6) + d_) = r;
            }
        }
    }
}

// ---------------------------------------------------------------------------
// f16-split MFMA GEMM: C = (1/1024)·A'[M,K]·W'[N,K]^T + bias
// A' = 16·A as (hi,lo) f16 planes; W' = 64·W as (hi,lo) planes (pre-split).
// 3 products hihi + hilo + lohi into ONE fp32 accumulator (rel err ~2^-22).
// ASRC: 0 = dual-plane A, 1 = single-plane A (exact spikes, lo==0 -> 2 MFMAs)
// EPI:  0 = fp32 store; 2 = spike -> fp32; 3 = spike -> f16 plane (x16)
// LAYOUT: 0 = [M,N]; 1 = fused QKV: n<512 q-head->O0, <1024 k-plain->O1, else v-head->O2
// ---------------------------------------------------------------------------
template<int ASRC, int EPI, int LAYOUT>
__global__ __launch_bounds__(256, 2) void mgemm_k(
    const _Float16* __restrict__ AH, const _Float16* __restrict__ AL,
    const _Float16* __restrict__ WH, const _Float16* __restrict__ WL,
    const float* __restrict__ bias,
    float* __restrict__ O0, float* __restrict__ O1, float* __restrict__ O2,
    int M, int N, int K)
{
    __shared__ _Float16 AsH[4][128][8];
    __shared__ _Float16 AsL[4][128][8];
    __shared__ _Float16 WsH[4][128][8];
    __shared__ _Float16 WsL[4][128][8];

    const int tid = threadIdx.x;
    const int n0 = blockIdx.x * 128;
    const int m0 = blockIdx.y * 128;
    const int wv = tid >> 6, lane = tid & 63;
    const int mw = (wv >> 1) * 64, nw = (wv & 1) * 64;
    const int fr = lane & 15;      // fragment row (m or n within 16)
    const int kb = lane >> 4;      // fragment k-block (8 halfs each)

    const int srow = tid >> 1;            // staging row 0..127
    const int skoff = (tid & 1) * 16;     // k-offset 0/16
    const int skb = skoff >> 3;           // kblock 0 or 2

    f32x4 acc[4][4];
    #pragma unroll
    for (int i = 0; i < 4; ++i)
        #pragma unroll
        for (int j = 0; j < 4; ++j) acc[i][j] = (f32x4)(0.f);

    for (int k0 = 0; k0 < K; k0 += 32) {
        // stage A planes (16 halfs per thread per plane)
        {
            const _Float16* ap = AH + (size_t)(m0 + srow) * K + k0 + skoff;
            *(f16x8*)&AsH[skb  ][srow][0] = *(const f16x8*)ap;
            *(f16x8*)&AsH[skb+1][srow][0] = *(const f16x8*)(ap + 8);
            if constexpr (ASRC == 0) {
                const _Float16* alp = AL + (size_t)(m0 + srow) * K + k0 + skoff;
                *(f16x8*)&AsL[skb  ][srow][0] = *(const f16x8*)alp;
                *(f16x8*)&AsL[skb+1][srow][0] = *(const f16x8*)(alp + 8);
            }
        }
        // stage W planes
        {
            const _Float16* wp = WH + (size_t)(n0 + srow) * K + k0 + skoff;
            *(f16x8*)&WsH[skb  ][srow][0] = *(const f16x8*)wp;
            *(f16x8*)&WsH[skb+1][srow][0] = *(const f16x8*)(wp + 8);
            const _Float16* wlp = WL + (size_t)(n0 + srow) * K + k0 + skoff;
            *(f16x8*)&WsL[skb  ][srow][0] = *(const f16x8*)wlp;
            *(f16x8*)&WsL[skb+1][srow][0] = *(const f16x8*)(wlp + 8);
        }
        __syncthreads();

        f16x8 aH[4], aL[4], bH[4], bL[4];
        #pragma unroll
        for (int i = 0; i < 4; ++i) {
            aH[i] = *(const f16x8*)&AsH[kb][mw + i*16 + fr][0];
            if constexpr (ASRC == 0) aL[i] = *(const f16x8*)&AsL[kb][mw + i*16 + fr][0];
            bH[i] = *(const f16x8*)&WsH[kb][nw + i*16 + fr][0];
            bL[i] = *(const f16x8*)&WsL[kb][nw + i*16 + fr][0];
        }
        #pragma unroll
        for (int i = 0; i < 4; ++i)
            #pragma unroll
            for (int j = 0; j < 4; ++j) {
                acc[i][j] = __builtin_amdgcn_mfma_f32_16x16x32_f16(aH[i], bH[j], acc[i][j], 0, 0, 0);
                acc[i][j] = __builtin_amdgcn_mfma_f32_16x16x32_f16(aH[i], bL[j], acc[i][j], 0, 0, 0);
                if constexpr (ASRC == 0)
                    acc[i][j] = __builtin_amdgcn_mfma_f32_16x16x32_f16(aL[i], bH[j], acc[i][j], 0, 0, 0);
            }
        __syncthreads();
    }

    // epilogue: C/D layout col = lane&15, row = (lane>>4)*4 + reg
    const int q = lane >> 4;
    #pragma unroll
    for (int j = 0; j < 4; ++j) {
        int n = n0 + nw + j*16 + fr;
        float bv = bias[n];
        #pragma unroll
        for (int i = 0; i < 4; ++i) {
            #pragma unroll
            for (int r = 0; r < 4; ++r) {
                int m = m0 + mw + i*16 + q*4 + r;
                float val = acc[i][j][r] * (1.f/1024.f) + bv;
                if constexpr (EPI == 2) val = val > 0.5f ? 1.f : 0.f;
                if constexpr (EPI == 3) {
                    ((_Float16*)O0)[(size_t)m * N + n] = (val > 0.5f) ? (_Float16)16.f : (_Float16)0.f;
                } else if constexpr (LAYOUT == 0) {
                    O0[(size_t)m * N + n] = val;
                } else {
                    int b_ = m >> 11, t_ = m & (T_SEQ-1);
                    if (n < 512) {
                        O0[(((size_t)(b_*NHEAD + (n>>6))*T_SEQ + t_) << 6) + (n & 63)] = val;
                    } else if (n < 1024) {
                        O1[(size_t)m * 512 + (n - 512)] = val;
                    } else {
                        int nn = n - 1024;
                        O2[(((size_t)(b_*NHEAD + (nn>>6))*T_SEQ + t_) << 6) + (nn & 63)] = val;
                    }
                }
            }
        }
    }
}

// ---------------------------------------------------------------------------
// Weight split: dst = 64*w as f16 hi/lo planes
// ---------------------------------------------------------------------------
__global__ __launch_bounds__(256) void cvtw_k(
    const float* __restrict__ w, _Float16* __restrict__ H, _Float16* __restrict__ L,
    int n, float scale)
{
    int i = blockIdx.x * 256 + threadIdx.x;
    if (i < n) {
        float s = scale * w[i];
        _Float16 h = (_Float16)s;
        H[i] = h;
        L[i] = (_Float16)(s - (float)h);
    }
}

// qkv weight concat + split (x64), bias concat (fp32)
__global__ __launch_bounds__(256) void cat_k(
    const float* __restrict__ wq, const float* __restrict__ wk, const float* __restrict__ wv,
    const float* __restrict__ bq, const float* __restrict__ bk, const float* __restrict__ bv,
    _Float16* __restrict__ WH, _Float16* __restrict__ WL, float* __restrict__ bcat)
{
    int i = blockIdx.x * 256 + threadIdx.x;
    if (i < 786432) {
        int src = i >> 18, off = i & 262143;
        float w = (src == 0 ? wq : (src == 1 ? wk : wv))[off];
        float s = 64.f * w;
        _Float16 h = (_Float16)s;
        WH[i] = h;
        WL[i] = (_Float16)(s - (float)h);
    } else if (i < 786432 + 1536) {
        int j = i - 786432;
        int src = j >> 9, off = j & 511;
        bcat[j] = (src == 0 ? bq : (src == 1 ? bk : bv))[off];
    }
}

// ---------------------------------------------------------------------------
// Transpose: k_plain [B*T, D] -> kT [B, H, dh, T]
// ---------------------------------------------------------------------------
__global__ __launch_bounds__(256) void transpose_k(
    const float* __restrict__ in, float* __restrict__ out)
{
    __shared__ float tile[32][33];
    const int t0 = blockIdx.x * 32;
    const int c0 = blockIdx.y * 32;
    const int tid = threadIdx.x;
    const int r = tid >> 5;
    const int c = tid & 31;
    #pragma unroll
    for (int i = 0; i < 4; ++i)
        tile[r + 8*i][c] = in[(size_t)(t0 + r + 8*i) * DMODEL + c0 + c];
    __syncthreads();
    #pragma unroll
    for (int i = 0; i < 4; ++i) {
        int n = c0 + r + 8*i;
        int m = t0 + c;
        int b = m >> 11, t = m & (T_SEQ-1);
        out[((size_t)(b * DMODEL + n)) * T_SEQ + t] = tile[c][r + 8*i];
    }
}

// ---------------------------------------------------------------------------
__device__ __forceinline__ unsigned long long shfl_xor_u64(unsigned long long x, int mask) {
    int lo = __shfl_xor((int)(unsigned)(x & 0xffffffffull), mask, 64);
    int hi = __shfl_xor((int)(unsigned)(x >> 32), mask, 64);
    return ((unsigned long long)(unsigned)hi << 32) | (unsigned)(unsigned)lo;
}

// ---------------------------------------------------------------------------
// Fused sparse attention (as round 3) — now emits x16 f16 hi/lo planes
// ---------------------------------------------------------------------------
__global__ __launch_bounds__(256) void attn_k(
    const float* __restrict__ q, const float* __restrict__ kT,
    const float* __restrict__ v, _Float16* __restrict__ outH, _Float16* __restrict__ outL)
{
    __shared__ float qsT[64][36];
    __shared__ float ksbuf[64*128];

    const int tid = threadIdx.x;
    const int bh  = blockIdx.y;
    const int t0  = blockIdx.x * 32;
    const float* qb = q  + ((size_t)bh * T_SEQ + t0) * DHEAD;
    const float* kb = kT + (size_t)bh * DHEAD * T_SEQ;
    const float* vb = v  + (size_t)bh * T_SEQ * DHEAD;

    float4 pf[8];
    {
        const int d = tid >> 5, tq = tid & 31;
        #pragma unroll
        for (int it = 0; it < 8; ++it)
            pf[it] = *(const float4*)(kb + (size_t)(d + 8*it)*T_SEQ + tq*4);
    }
    #pragma unroll
    for (int it = 0; it < 8; ++it) {
        int e = tid + 256*it;
        qsT[e & 63][e >> 6] = qb[e];
    }

    unsigned long long kreg[32];
    #pragma unroll
    for (int i = 0; i < 32; ++i) kreg[i] = 0ull;

    const int ry = tid >> 5;
    const int tx = tid & 31;
    const int srow = tid >> 3;
    const int ssub = tid & 7;
    float (*ks)[128] = (float(*)[128])ksbuf;
    float (*ss)[132] = (float(*)[132])ksbuf;

    for (int jt = 0; jt < 16; ++jt) {
        const int j0 = jt * 128;
        {
            const int d = tid >> 5, tq = tid & 31;
            #pragma unroll
            for (int it = 0; it < 8; ++it)
                *(float4*)&ks[d + 8*it][tq*4] = pf[it];
        }
        __syncthreads();
        float acc[4][4];
        #pragma unroll
        for (int i = 0; i < 4; ++i)
            #pragma unroll
            for (int j = 0; j < 4; ++j) acc[i][j] = 0.f;
        #pragma unroll 8
        for (int d = 0; d < 64; ++d) {
            float4 qa4 = *(const float4*)&qsT[d][ry*4];
            float4 kb4 = *(const float4*)&ks[d][tx*4];
            float qa[4] = {qa4.x, qa4.y, qa4.z, qa4.w};
            float kv[4] = {kb4.x, kb4.y, kb4.z, kb4.w};
            #pragma unroll
            for (int i = 0; i < 4; ++i)
                #pragma unroll
                for (int j = 0; j < 4; ++j)
                    acc[i][j] = fmaf(qa[i], kv[j], acc[i][j]);
        }
        if (jt < 15) {
            const int d = tid >> 5, tq = tid & 31;
            const float* kbn = kb + (j0 + 128) + tq*4;
            #pragma unroll
            for (int it = 0; it < 8; ++it)
                pf[it] = *(const float4*)(kbn + (size_t)(d + 8*it)*T_SEQ);
        }
        __syncthreads();
        #pragma unroll
        for (int i = 0; i < 4; ++i) {
            float4 r4;
            r4.x = acc[i][0]*0.125f; r4.y = acc[i][1]*0.125f;
            r4.z = acc[i][2]*0.125f; r4.w = acc[i][3]*0.125f;
            *(float4*)&ss[ry*4+i][tx*4] = r4;
        }
        __syncthreads();

        float4 c4[4];
        {
            const float* ssr = &ss[srow][0] + ssub*4;
            #pragma unroll
            for (int g = 0; g < 4; ++g) c4[g] = *(const float4*)(ssr + g*32);
        }
        unsigned long long cand[16];
        #pragma unroll
        for (int g = 0; g < 4; ++g) {
            float vg[4] = {c4[g].x, c4[g].y, c4[g].z, c4[g].w};
            #pragma unroll
            for (int r = 0; r < 4; ++r) {
                unsigned u = __float_as_uint(vg[r]);
                u ^= (unsigned)((int)u >> 31) | 0x80000000u;
                int col = ssub*4 + g*32 + r;
                cand[g*4+r] = ((unsigned long long)u << 32) | (unsigned)(2047 - (j0 + col));
            }
        }
        #pragma unroll
        for (int k2 = 2; k2 <= 16; k2 <<= 1) {
            #pragma unroll
            for (int j2 = k2 >> 1; j2 > 0; j2 >>= 1) {
                #pragma unroll
                for (int i2 = 0; i2 < 16; ++i2) {
                    int l2 = i2 ^ j2;
                    if (l2 > i2) {
                        unsigned long long a = cand[i2], b = cand[l2];
                        bool sw = ((i2 & k2) == 0) ? (a < b) : (a > b);
                        cand[i2] = sw ? b : a;
                        cand[l2] = sw ? a : b;
                    }
                }
            }
        }
        #pragma unroll
        for (int j2 = 0; j2 < 16; ++j2) {
            unsigned long long b = cand[15 - j2];
            if (kreg[16 + j2] < b) kreg[16 + j2] = b;
        }
        #pragma unroll
        for (int st = 16; st >= 1; st >>= 1) {
            #pragma unroll
            for (int i2 = 0; i2 < 32; ++i2) {
                if ((i2 & st) == 0) {
                    unsigned long long lo = kreg[i2], hi = kreg[i2 | st];
                    kreg[i2]      = lo < hi ? hi : lo;
                    kreg[i2 | st] = lo < hi ? lo : hi;
                }
            }
        }
        __syncthreads();
    }

    #pragma unroll
    for (int s = 1; s <= 4; s <<= 1) {
        #pragma unroll
        for (int i = 0; i < 16; ++i) {
            unsigned long long pa = shfl_xor_u64(kreg[31-i], s);
            unsigned long long pb = shfl_xor_u64(kreg[i],    s);
            if (pa > kreg[i])    kreg[i]    = pa;
            if (pb > kreg[31-i]) kreg[31-i] = pb;
        }
        #pragma unroll
        for (int st = 16; st >= 1; st >>= 1) {
            #pragma unroll
            for (int i2 = 0; i2 < 32; ++i2) {
                if ((i2 & st) == 0) {
                    unsigned long long lo = kreg[i2], hi = kreg[i2 | st];
                    kreg[i2]      = lo < hi ? hi : lo;
                    kreg[i2 | st] = lo < hi ? lo : hi;
                }
            }
        }
    }

    float* wrow = ksbuf + 4352;
    int*   irow = (int*)(ksbuf + 4352 + 1088);
    if (ssub == 0) {
        float w[32];
        #pragma unroll
        for (int i = 0; i < 32; ++i) {
            unsigned um = (unsigned)(kreg[i] >> 32);
            unsigned ub = (um & 0x80000000u) ? (um ^ 0x80000000u) : ~um;
            w[i] = __uint_as_float(ub);
        }
        float m = w[0];
        float s = 0.f;
        #pragma unroll
        for (int i = 0; i < 32; ++i) { w[i] = expf(w[i] - m); s += w[i]; }
        float inv = 1.f / s;
        #pragma unroll
        for (int i = 0; i < 32; ++i) {
            wrow[srow*33 + i] = w[i] * inv;
            irow[srow*33 + i] = 2047 - (int)(unsigned)(kreg[i] & 0xffffffffull);
        }
    }
    __syncthreads();

    const int wid = tid >> 6, lane = tid & 63;
    const int b = bh >> 3, h = bh & 7;
    for (int rr = wid; rr < 32; rr += 4) {
        float accv = 0.f;
        #pragma unroll
        for (int i = 0; i < 32; ++i) {
            float wgt = wrow[rr*33 + i];
            int   idx = irow[rr*33 + i];
            accv = fmaf(wgt, vb[(size_t)idx * DHEAD + lane], accv);
        }
        size_t oi = ((size_t)(b * T_SEQ + t0 + rr)) * DMODEL + h * DHEAD + lane;
        float s16 = 16.f * accv;
        _Float16 hh = (_Float16)s16;
        outH[oi] = hh;
        outL[oi] = (_Float16)(s16 - (float)hh);
    }
}

// ---------------------------------------------------------------------------
// LayerNorm (+residual); also emits x16 f16 hi/lo planes of the output
// ---------------------------------------------------------------------------
__global__ __launch_bounds__(256) void ln_k(
    const float* __restrict__ x, const float* __restrict__ res,
    const float* __restrict__ g, const float* __restrict__ bb,
    float* __restrict__ out, _Float16* __restrict__ oH, _Float16* __restrict__ oL)
{
    __shared__ float red[8];
    const int row = blockIdx.x;
    const int tid = threadIdx.x;
    const float* xr = x + (size_t)row * DMODEL;
    float v0 = xr[tid], v1 = xr[tid + 256];
    if (res) {
        const float* rr = res + (size_t)row * DMODEL;
        v0 += rr[tid]; v1 += rr[tid + 256];
    }
    float s = v0 + v1;
    #pragma unroll
    for (int o = 1; o < 64; o <<= 1) s += __shfl_xor(s, o);
    const int wid = tid >> 6, lane = tid & 63;
    if (lane == 0) red[wid] = s;
    __syncthreads();
    float mean = (red[0] + red[1] + red[2] + red[3]) * (1.f / DMODEL);
    float d0 = v0 - mean, d1 = v1 - mean;
    float qs = d0*d0 + d1*d1;
    #pragma unroll
    for (int o = 1; o < 64; o <<= 1) qs += __shfl_xor(qs, o);
    if (lane == 0) red[4 + wid] = qs;
    __syncthreads();
    float var = (red[4] + red[5] + red[6] + red[7]) * (1.f / DMODEL);
    float rs = rsqrtf(var + 1e-5f);
    float o0 = d0 * rs * g[tid]       + bb[tid];
    float o1 = d1 * rs * g[tid + 256] + bb[tid + 256];
    size_t base = (size_t)row * DMODEL;
    out[base + tid]       = o0;
    out[base + tid + 256] = o1;
    float s0 = 16.f * o0, s1 = 16.f * o1;
    _Float16 h0 = (_Float16)s0, h1 = (_Float16)s1;
    oH[base + tid]       = h0;
    oH[base + tid + 256] = h1;
    oL[base + tid]       = (_Float16)(s0 - (float)h0);
    oL[base + tid + 256] = (_Float16)(s1 - (float)h1);
}

// ---------------------------------------------------------------------------
__global__ __launch_bounds__(256) void pool_k(
    const float* __restrict__ h, float* __restrict__ pooled)
{
    int idx = blockIdx.x * 256 + threadIdx.x;
    int b = idx >> 9, d = idx & 511;
    const float* p = h + (size_t)b * T_SEQ * DMODEL + d;
    float s = 0.f;
    for (int t = 0; t < T_SEQ; ++t) s += p[(size_t)t * DMODEL];
    pooled[idx] = s * (1.f / T_SEQ);
}

__global__ __launch_bounds__(256) void cls_k(
    const float* __restrict__ pooled, const float* __restrict__ w,
    const float* __restrict__ bias, float* __restrict__ out)
{
    const int wid = threadIdx.x >> 6, lane = threadIdx.x & 63;
    const int oi = blockIdx.x * 4 + wid;
    const int b = oi >> 8, o = oi & 255;
    const float* pr = pooled + b * DMODEL;
    const float* wr = w + (size_t)o * DMODEL;
    float s = 0.f;
    for (int d = lane; d < DMODEL; d += 64) s = fmaf(pr[d], wr[d], s);
    #pragma unroll
    for (int off = 1; off < 64; off <<= 1) s += __shfl_xor(s, off);
    if (lane == 0) out[oi] = s + bias[o];
}

// ---------------------------------------------------------------------------
extern "C" void kernel_launch(void* const* d_in, const int* in_sizes, int n_in,
                              void* d_out, int out_size, void* d_ws, size_t ws_size,
                              hipStream_t stream)
{
    const float* x     = (const float*)d_in[0];
    const float* emb_w = (const float*)d_in[1];
    const float* emb_b = (const float*)d_in[2];
    const float* pos   = (const float*)d_in[3];
    const float* wq    = (const float*)d_in[4];
    const float* bq    = (const float*)d_in[5];
    const float* wk    = (const float*)d_in[6];
    const float* bk    = (const float*)d_in[7];
    const float* wv    = (const float*)d_in[8];
    const float* bv    = (const float*)d_in[9];
    const float* wo    = (const float*)d_in[10];
    const float* bo    = (const float*)d_in[11];
    const float* ln1g  = (const float*)d_in[12];
    const float* ln1b  = (const float*)d_in[13];
    const float* fc1w  = (const float*)d_in[14];
    const float* fc1b  = (const float*)d_in[15];
    const float* fc2w  = (const float*)d_in[16];
    const float* fc2b  = (const float*)d_in[17];
    const float* ln2g  = (const float*)d_in[18];
    const float* ln2b  = (const float*)d_in[19];
    const float* fng   = (const float*)d_in[20];
    const float* fnb   = (const float*)d_in[21];
    const float* clsw  = (const float*)d_in[22];
    const float* clsb  = (const float*)d_in[23];

    float* ws = (float*)d_ws;
    const size_t SZ  = (size_t)MROWS * DMODEL;       // 2,097,152 floats
    const size_t HP  = SZ / 2;                       // one half-plane in floats
    float*     h     = ws;                           // fp32 residual stream
    float*     qb    = ws + 1*SZ;
    float*     kTb   = ws + 2*SZ;
    float*     vbuf  = ws + 3*SZ;
    float*     t1    = ws + 4*SZ;                    // spike fp32 / k-plain temp
    _Float16*  hH    = (_Float16*)(ws + 5*SZ);       // x16 planes of h
    _Float16*  hL    = (_Float16*)(ws + 5*SZ + HP);
    _Float16*  aoH   = (_Float16*)(ws + 6*SZ);       // x16 planes of attn out
    _Float16*  aoL   = (_Float16*)(ws + 6*SZ + HP);
    _Float16*  WcatH = (_Float16*)(ws + 7*SZ);                 // 786432 halfs
    _Float16*  WcatL = (_Float16*)(ws + 7*SZ + 393216);
    _Float16*  WoH   = (_Float16*)(ws + 7*SZ + 786432);        // 262144 halfs
    _Float16*  WoL   = (_Float16*)(ws + 7*SZ + 917504);
    _Float16*  W1H   = (_Float16*)(ws + 7*SZ + 1048576);       // 1048576 halfs
    _Float16*  W1L   = (_Float16*)(ws + 7*SZ + 1572864);
    _Float16*  W2H   = (_Float16*)(ws + 7*SZ + 2097152);
    _Float16*  W2L   = (_Float16*)(ws + 7*SZ + 2621440);
    float*     bcat  = ws + 7*SZ + 3145728;                    // 1536 floats
    float*     pooled= ws + 7*SZ + 3145728 + 1536;
    _Float16*  hid   = (_Float16*)qb;   // [M,FDIM] halfs aliases qb+kTb (dead then)
    const size_t needed = (7*SZ + 3145728 + 1536 + 1024) * sizeof(float);
    if (ws_size < needed) return;

    dim3 blk(256);

    // embedding: h = x @ emb_w^T + emb_b + pos ; then split planes
    gemm_k<64,1,0><<<dim3(DMODEL/64, MROWS/128), blk, 0, stream>>>(
        x, emb_w, emb_b, pos, h, MROWS, DMODEL, 128);
    cvtw_k<<<dim3((int)(SZ/256)), blk, 0, stream>>>(h, hH, hL, (int)SZ, 16.f);

    for (int l = 0; l < NLAYER; ++l) {
        const float* wq_l = wq + (size_t)l*DMODEL*DMODEL;
        const float* bq_l = bq + (size_t)l*DMODEL;
        const float* wk_l = wk + (size_t)l*DMODEL*DMODEL;
        const float* bk_l = bk + (size_t)l*DMODEL;
        const float* wv_l = wv + (size_t)l*DMODEL*DMODEL;
        const float* bv_l = bv + (size_t)l*DMODEL;
        const float* wo_l = wo + (size_t)l*DMODEL*DMODEL;
        const float* bo_l = bo + (size_t)l*DMODEL;
        const float* f1w_l = fc1w + (size_t)l*FDIM*DMODEL;
        const float* f1b_l = fc1b + (size_t)l*FDIM;
        const float* f2w_l = fc2w + (size_t)l*DMODEL*FDIM;
        const float* f2b_l = fc2b + (size_t)l*DMODEL;

        // weight conversions (x64 split)
        cat_k<<<dim3(3079), blk, 0, stream>>>(wq_l, wk_l, wv_l, bq_l, bk_l, bv_l,
                                              WcatH, WcatL, bcat);
        cvtw_k<<<dim3(1024), blk, 0, stream>>>(wo_l, WoH, WoL, 262144, 64.f);
        cvtw_k<<<dim3(4096), blk, 0, stream>>>(f1w_l, W1H, W1L, 1048576, 64.f);
        cvtw_k<<<dim3(4096), blk, 0, stream>>>(f2w_l, W2H, W2L, 1048576, 64.f);

        // fused QKV GEMM: q->qb(head), k->t1(plain), v->vbuf(head)
        mgemm_k<0,0,1><<<dim3(12, 32), blk, 0, stream>>>(
            hH, hL, WcatH, WcatL, bcat, qb, t1, vbuf, MROWS, 1536, DMODEL);
        transpose_k<<<dim3(MROWS/32, DMODEL/32), blk, 0, stream>>>(t1, kTb);

        // fused top-k attention -> x16 planes
        attn_k<<<dim3(T_SEQ/32, NB*NHEAD), blk, 0, stream>>>(qb, kTb, vbuf, aoH, aoL);

        // o-proj + spike -> t1 (fp32 0/1)
        mgemm_k<0,2,0><<<dim3(4, 32), blk, 0, stream>>>(
            aoH, aoL, WoH, WoL, bo_l, t1, nullptr, nullptr, MROWS, DMODEL, DMODEL);
        ln_k<<<dim3(MROWS), blk, 0, stream>>>(h, t1, ln1g + (size_t)l*DMODEL,
                                              ln1b + (size_t)l*DMODEL, h, hH, hL);

        // FFN: fc1 spike -> f16 plane (x16, exact); fc2 spike -> fp32
        mgemm_k<0,3,0><<<dim3(16, 32), blk, 0, stream>>>(
            hH, hL, W1H, W1L, f1b_l, (float*)hid, nullptr, nullptr, MROWS, FDIM, DMODEL);
        mgemm_k<1,2,0><<<dim3(4, 32), blk, 0, stream>>>(
            hid, nullptr, W2H, W2L, f2b_l, t1, nullptr, nullptr, MROWS, DMODEL, FDIM);
        ln_k<<<dim3(MROWS), blk, 0, stream>>>(h, t1, ln2g + (size_t)l*DMODEL,
                                              ln2b + (size_t)l*DMODEL, h, hH, hL);
    }

    // final norm, pool, classify
    ln_k<<<dim3(MROWS), blk, 0, stream>>>(h, nullptr, fng, fnb, h, hH, hL);
    pool_k<<<dim3(4), blk, 0, stream>>>(h, pooled);
    cls_k<<<dim3(128), blk, 0, stream>>>(pooled, clsw, clsb, (float*)d_out);
}

// Round 5
// 2606.019 us; speedup vs baseline: 5.7011x; 1.0275x over previous
//
#include <hip/hip_runtime.h>
#include <math.h>
#include <float.h>

#define T_SEQ  2048
#define DMODEL 512
#define NHEAD  8
#define DHEAD  64
#define FDIM   2048
#define NLAYER 4
#define NB     2
#define MROWS  (NB*T_SEQ)   // 4096

typedef _Float16 f16x8 __attribute__((ext_vector_type(8)));
typedef float    f32x4 __attribute__((ext_vector_type(4)));

// ---------------------------------------------------------------------------
// fp32 vector GEMM — kept only for the embedding (K=128, 0.5 GF)
// ---------------------------------------------------------------------------
template<int BN, int EPI, int LAYOUT>
__global__ __launch_bounds__(256) void gemm_k(
    const float* __restrict__ A, const float* __restrict__ W,
    const float* __restrict__ bias, const float* __restrict__ pos,
    float* __restrict__ C, int M, int N, int K)
{
    constexpr int BM = 128;
    constexpr int BK = 32;
    constexpr int MN = BN / 16;
    __shared__ float As[BK][BM + 4];
    __shared__ float Ws[BK][BN + 4];
    const int tid = threadIdx.x;
    const int n0 = blockIdx.x * BN;
    const int m0 = blockIdx.y * BM;
    const int tx = tid & 15;
    const int ty = tid >> 4;

    float acc[8][MN];
    #pragma unroll
    for (int i = 0; i < 8; ++i)
        #pragma unroll
        for (int j = 0; j < MN; ++j) acc[i][j] = 0.f;

    for (int k0 = 0; k0 < K; k0 += BK) {
        #pragma unroll
        for (int it = 0; it < 4; ++it) {
            int qq = tid + 256 * it;
            int m = qq >> 3, kq = qq & 7;
            float4 v4 = *(const float4*)(A + (size_t)(m0 + m) * K + k0 + kq * 4);
            As[kq*4+0][m] = v4.x; As[kq*4+1][m] = v4.y;
            As[kq*4+2][m] = v4.z; As[kq*4+3][m] = v4.w;
        }
        #pragma unroll
        for (int it = 0; it < BN/32; ++it) {
            int qq = tid + 256 * it;
            int n = qq >> 3, kq = qq & 7;
            float4 v4 = *(const float4*)(W + (size_t)(n0 + n) * K + k0 + kq * 4);
            Ws[kq*4+0][n] = v4.x; Ws[kq*4+1][n] = v4.y;
            Ws[kq*4+2][n] = v4.z; Ws[kq*4+3][n] = v4.w;
        }
        __syncthreads();
        for (int kk = 0; kk < BK; ++kk) {
            float a[8], b[MN];
            float4 a0 = *(const float4*)&As[kk][ty*8];
            float4 a1 = *(const float4*)&As[kk][ty*8+4];
            a[0]=a0.x; a[1]=a0.y; a[2]=a0.z; a[3]=a0.w;
            a[4]=a1.x; a[5]=a1.y; a[6]=a1.z; a[7]=a1.w;
            float4 b0 = *(const float4*)&Ws[kk][tx*4];
            b[0]=b0.x; b[1]=b0.y; b[2]=b0.z; b[3]=b0.w;
            if constexpr (MN == 8) {
                float4 b1 = *(const float4*)&Ws[kk][64 + tx*4];
                b[4]=b1.x; b[5]=b1.y; b[6]=b1.z; b[7]=b1.w;
            }
            #pragma unroll
            for (int i = 0; i < 8; ++i)
                #pragma unroll
                for (int j = 0; j < MN; ++j)
                    acc[i][j] = fmaf(a[i], b[j], acc[i][j]);
        }
        __syncthreads();
    }

    #pragma unroll
    for (int i = 0; i < 8; ++i) {
        int m = m0 + ty*8 + i;
        #pragma unroll
        for (int jb = 0; jb < MN/4; ++jb) {
            int nn = n0 + jb*64 + tx*4;
            float4 r;
            r.x = acc[i][jb*4+0] + bias[nn+0];
            r.y = acc[i][jb*4+1] + bias[nn+1];
            r.z = acc[i][jb*4+2] + bias[nn+2];
            r.w = acc[i][jb*4+3] + bias[nn+3];
            if constexpr (EPI == 1) {
                const float* pp = pos + (size_t)(m & (T_SEQ-1)) * DMODEL + nn;
                r.x += pp[0]; r.y += pp[1]; r.z += pp[2]; r.w += pp[3];
            }
            if constexpr (EPI == 2) {
                r.x = r.x > 0.5f ? 1.f : 0.f;
                r.y = r.y > 0.5f ? 1.f : 0.f;
                r.z = r.z > 0.5f ? 1.f : 0.f;
                r.w = r.w > 0.5f ? 1.f : 0.f;
            }
            if constexpr (LAYOUT == 0) {
                *(float4*)(C + (size_t)m * N + nn) = r;
            } else {
                int b_ = m >> 11, t_ = m & (T_SEQ-1);
                int h_ = nn >> 6, d_ = nn & 63;
                *(float4*)(C + (((size_t)(b_*NHEAD + h_)*T_SEQ + t_) << 6) + d_) = r;
            }
        }
    }
}

// ---------------------------------------------------------------------------
// f16-split MFMA GEMM: C = (1/1024)·A'[M,K]·W'[N,K]^T + bias
// A' = 16·A as (hi,lo) f16 planes; W' = 64·W as (hi,lo) planes (pre-split).
// 3 products hihi + hilo + lohi into ONE fp32 accumulator (rel err ~2^-22).
// ASRC: 0 = dual-plane A, 1 = single-plane A (exact spikes, lo==0 -> 2 MFMAs)
// EPI:  0 = fp32 store; 2 = spike -> fp32; 3 = spike -> f16 plane (x16)
// LAYOUT: 0 = [M,N]; 1 = fused QKV: n<512 q-head->O0, <1024 k-plain->O1, else v-head->O2
// ---------------------------------------------------------------------------
template<int ASRC, int EPI, int LAYOUT>
__global__ __launch_bounds__(256, 2) void mgemm_k(
    const _Float16* __restrict__ AH, const _Float16* __restrict__ AL,
    const _Float16* __restrict__ WH, const _Float16* __restrict__ WL,
    const float* __restrict__ bias,
    float* __restrict__ O0, float* __restrict__ O1, float* __restrict__ O2,
    int M, int N, int K)
{
    __shared__ _Float16 AsH[4][128][8];
    __shared__ _Float16 AsL[4][128][8];
    __shared__ _Float16 WsH[4][128][8];
    __shared__ _Float16 WsL[4][128][8];

    const int tid = threadIdx.x;
    const int n0 = blockIdx.x * 128;
    const int m0 = blockIdx.y * 128;
    const int wv = tid >> 6, lane = tid & 63;
    const int mw = (wv >> 1) * 64, nw = (wv & 1) * 64;
    const int fr = lane & 15;
    const int kb = lane >> 4;

    const int srow = tid >> 1;
    const int skoff = (tid & 1) * 16;
    const int skb = skoff >> 3;

    f32x4 acc[4][4];
    #pragma unroll
    for (int i = 0; i < 4; ++i)
        #pragma unroll
        for (int j = 0; j < 4; ++j) acc[i][j] = (f32x4)(0.f);

    for (int k0 = 0; k0 < K; k0 += 32) {
        {
            const _Float16* ap = AH + (size_t)(m0 + srow) * K + k0 + skoff;
            *(f16x8*)&AsH[skb  ][srow][0] = *(const f16x8*)ap;
            *(f16x8*)&AsH[skb+1][srow][0] = *(const f16x8*)(ap + 8);
            if constexpr (ASRC == 0) {
                const _Float16* alp = AL + (size_t)(m0 + srow) * K + k0 + skoff;
                *(f16x8*)&AsL[skb  ][srow][0] = *(const f16x8*)alp;
                *(f16x8*)&AsL[skb+1][srow][0] = *(const f16x8*)(alp + 8);
            }
        }
        {
            const _Float16* wp = WH + (size_t)(n0 + srow) * K + k0 + skoff;
            *(f16x8*)&WsH[skb  ][srow][0] = *(const f16x8*)wp;
            *(f16x8*)&WsH[skb+1][srow][0] = *(const f16x8*)(wp + 8);
            const _Float16* wlp = WL + (size_t)(n0 + srow) * K + k0 + skoff;
            *(f16x8*)&WsL[skb  ][srow][0] = *(const f16x8*)wlp;
            *(f16x8*)&WsL[skb+1][srow][0] = *(const f16x8*)(wlp + 8);
        }
        __syncthreads();

        f16x8 aH[4], aL[4], bH[4], bL[4];
        #pragma unroll
        for (int i = 0; i < 4; ++i) {
            aH[i] = *(const f16x8*)&AsH[kb][mw + i*16 + fr][0];
            if constexpr (ASRC == 0) aL[i] = *(const f16x8*)&AsL[kb][mw + i*16 + fr][0];
            bH[i] = *(const f16x8*)&WsH[kb][nw + i*16 + fr][0];
            bL[i] = *(const f16x8*)&WsL[kb][nw + i*16 + fr][0];
        }
        #pragma unroll
        for (int i = 0; i < 4; ++i)
            #pragma unroll
            for (int j = 0; j < 4; ++j) {
                acc[i][j] = __builtin_amdgcn_mfma_f32_16x16x32_f16(aH[i], bH[j], acc[i][j], 0, 0, 0);
                acc[i][j] = __builtin_amdgcn_mfma_f32_16x16x32_f16(aH[i], bL[j], acc[i][j], 0, 0, 0);
                if constexpr (ASRC == 0)
                    acc[i][j] = __builtin_amdgcn_mfma_f32_16x16x32_f16(aL[i], bH[j], acc[i][j], 0, 0, 0);
            }
        __syncthreads();
    }

    const int q = lane >> 4;
    #pragma unroll
    for (int j = 0; j < 4; ++j) {
        int n = n0 + nw + j*16 + fr;
        float bv = bias[n];
        #pragma unroll
        for (int i = 0; i < 4; ++i) {
            #pragma unroll
            for (int r = 0; r < 4; ++r) {
                int m = m0 + mw + i*16 + q*4 + r;
                float val = acc[i][j][r] * (1.f/1024.f) + bv;
                if constexpr (EPI == 2) val = val > 0.5f ? 1.f : 0.f;
                if constexpr (EPI == 3) {
                    ((_Float16*)O0)[(size_t)m * N + n] = (val > 0.5f) ? (_Float16)16.f : (_Float16)0.f;
                } else if constexpr (LAYOUT == 0) {
                    O0[(size_t)m * N + n] = val;
                } else {
                    int b_ = m >> 11, t_ = m & (T_SEQ-1);
                    if (n < 512) {
                        O0[(((size_t)(b_*NHEAD + (n>>6))*T_SEQ + t_) << 6) + (n & 63)] = val;
                    } else if (n < 1024) {
                        O1[(size_t)m * 512 + (n - 512)] = val;
                    } else {
                        int nn = n - 1024;
                        O2[(((size_t)(b_*NHEAD + (nn>>6))*T_SEQ + t_) << 6) + (nn & 63)] = val;
                    }
                }
            }
        }
    }
}

// ---------------------------------------------------------------------------
__global__ __launch_bounds__(256) void cvtw_k(
    const float* __restrict__ w, _Float16* __restrict__ H, _Float16* __restrict__ L,
    int n, float scale)
{
    int i = blockIdx.x * 256 + threadIdx.x;
    if (i < n) {
        float s = scale * w[i];
        _Float16 h = (_Float16)s;
        H[i] = h;
        L[i] = (_Float16)(s - (float)h);
    }
}

__global__ __launch_bounds__(256) void cat_k(
    const float* __restrict__ wq, const float* __restrict__ wk, const float* __restrict__ wv,
    const float* __restrict__ bq, const float* __restrict__ bk, const float* __restrict__ bv,
    _Float16* __restrict__ WH, _Float16* __restrict__ WL, float* __restrict__ bcat)
{
    int i = blockIdx.x * 256 + threadIdx.x;
    if (i < 786432) {
        int src = i >> 18, off = i & 262143;
        float w = (src == 0 ? wq : (src == 1 ? wk : wv))[off];
        float s = 64.f * w;
        _Float16 h = (_Float16)s;
        WH[i] = h;
        WL[i] = (_Float16)(s - (float)h);
    } else if (i < 786432 + 1536) {
        int j = i - 786432;
        int src = j >> 9, off = j & 511;
        bcat[j] = (src == 0 ? bq : (src == 1 ? bk : bv))[off];
    }
}

// ---------------------------------------------------------------------------
__global__ __launch_bounds__(256) void transpose_k(
    const float* __restrict__ in, float* __restrict__ out)
{
    __shared__ float tile[32][33];
    const int t0 = blockIdx.x * 32;
    const int c0 = blockIdx.y * 32;
    const int tid = threadIdx.x;
    const int r = tid >> 5;
    const int c = tid & 31;
    #pragma unroll
    for (int i = 0; i < 4; ++i)
        tile[r + 8*i][c] = in[(size_t)(t0 + r + 8*i) * DMODEL + c0 + c];
    __syncthreads();
    #pragma unroll
    for (int i = 0; i < 4; ++i) {
        int n = c0 + r + 8*i;
        int m = t0 + c;
        int b = m >> 11, t = m & (T_SEQ-1);
        out[((size_t)(b * DMODEL + n)) * T_SEQ + t] = tile[c][r + 8*i];
    }
}

// ---------------------------------------------------------------------------
__device__ __forceinline__ unsigned long long shfl_xor_u64(unsigned long long x, int mask) {
    int lo = __shfl_xor((int)(unsigned)(x & 0xffffffffull), mask, 64);
    int hi = __shfl_xor((int)(unsigned)(x >> 32), mask, 64);
    return ((unsigned long long)(unsigned)hi << 32) | (unsigned)(unsigned)lo;
}

// ---------------------------------------------------------------------------
// Fused sparse attention — round-4 structure, but __launch_bounds__(256,2):
// VGPR budget 256 so kreg/cand/pf stay register-resident (round 4 spilled
// ~330 MB of scratch per dispatch at the compiler-chosen 96 VGPRs).
// ---------------------------------------------------------------------------
__global__ __launch_bounds__(256, 2) void attn_k(
    const float* __restrict__ q, const float* __restrict__ kT,
    const float* __restrict__ v, _Float16* __restrict__ outH, _Float16* __restrict__ outL)
{
    __shared__ float qsT[64][36];
    __shared__ float ksbuf[64*128];

    const int tid = threadIdx.x;
    const int bh  = blockIdx.y;
    const int t0  = blockIdx.x * 32;
    const float* qb = q  + ((size_t)bh * T_SEQ + t0) * DHEAD;
    const float* kb = kT + (size_t)bh * DHEAD * T_SEQ;
    const float* vb = v  + (size_t)bh * T_SEQ * DHEAD;

    float4 pf[8];
    {
        const int d = tid >> 5, tq = tid & 31;
        #pragma unroll
        for (int it = 0; it < 8; ++it)
            pf[it] = *(const float4*)(kb + (size_t)(d + 8*it)*T_SEQ + tq*4);
    }
    #pragma unroll
    for (int it = 0; it < 8; ++it) {
        int e = tid + 256*it;
        qsT[e & 63][e >> 6] = qb[e];
    }

    unsigned long long kreg[32];
    #pragma unroll
    for (int i = 0; i < 32; ++i) kreg[i] = 0ull;

    const int ry = tid >> 5;
    const int tx = tid & 31;
    const int srow = tid >> 3;
    const int ssub = tid & 7;
    float (*ks)[128] = (float(*)[128])ksbuf;
    float (*ss)[132] = (float(*)[132])ksbuf;

    for (int jt = 0; jt < 16; ++jt) {
        const int j0 = jt * 128;
        {
            const int d = tid >> 5, tq = tid & 31;
            #pragma unroll
            for (int it = 0; it < 8; ++it)
                *(float4*)&ks[d + 8*it][tq*4] = pf[it];
        }
        __syncthreads();
        float acc[4][4];
        #pragma unroll
        for (int i = 0; i < 4; ++i)
            #pragma unroll
            for (int j = 0; j < 4; ++j) acc[i][j] = 0.f;
        #pragma unroll 8
        for (int d = 0; d < 64; ++d) {
            float4 qa4 = *(const float4*)&qsT[d][ry*4];
            float4 kb4 = *(const float4*)&ks[d][tx*4];
            float qa[4] = {qa4.x, qa4.y, qa4.z, qa4.w};
            float kv[4] = {kb4.x, kb4.y, kb4.z, kb4.w};
            #pragma unroll
            for (int i = 0; i < 4; ++i)
                #pragma unroll
                for (int j = 0; j < 4; ++j)
                    acc[i][j] = fmaf(qa[i], kv[j], acc[i][j]);
        }
        if (jt < 15) {
            const int d = tid >> 5, tq = tid & 31;
            const float* kbn = kb + (j0 + 128) + tq*4;
            #pragma unroll
            for (int it = 0; it < 8; ++it)
                pf[it] = *(const float4*)(kbn + (size_t)(d + 8*it)*T_SEQ);
        }
        __syncthreads();
        #pragma unroll
        for (int i = 0; i < 4; ++i) {
            float4 r4;
            r4.x = acc[i][0]*0.125f; r4.y = acc[i][1]*0.125f;
            r4.z = acc[i][2]*0.125f; r4.w = acc[i][3]*0.125f;
            *(float4*)&ss[ry*4+i][tx*4] = r4;
        }
        __syncthreads();

        float4 c4[4];
        {
            const float* ssr = &ss[srow][0] + ssub*4;
            #pragma unroll
            for (int g = 0; g < 4; ++g) c4[g] = *(const float4*)(ssr + g*32);
        }
        unsigned long long cand[16];
        #pragma unroll
        for (int g = 0; g < 4; ++g) {
            float vg[4] = {c4[g].x, c4[g].y, c4[g].z, c4[g].w};
            #pragma unroll
            for (int r = 0; r < 4; ++r) {
                unsigned u = __float_as_uint(vg[r]);
                u ^= (unsigned)((int)u >> 31) | 0x80000000u;
                int col = ssub*4 + g*32 + r;
                cand[g*4+r] = ((unsigned long long)u << 32) | (unsigned)(2047 - (j0 + col));
            }
        }
        #pragma unroll
        for (int k2 = 2; k2 <= 16; k2 <<= 1) {
            #pragma unroll
            for (int j2 = k2 >> 1; j2 > 0; j2 >>= 1) {
                #pragma unroll
                for (int i2 = 0; i2 < 16; ++i2) {
                    int l2 = i2 ^ j2;
                    if (l2 > i2) {
                        unsigned long long a = cand[i2], b = cand[l2];
                        bool sw = ((i2 & k2) == 0) ? (a < b) : (a > b);
                        cand[i2] = sw ? b : a;
                        cand[l2] = sw ? a : b;
                    }
                }
            }
        }
        #pragma unroll
        for (int j2 = 0; j2 < 16; ++j2) {
            unsigned long long b = cand[15 - j2];
            if (kreg[16 + j2] < b) kreg[16 + j2] = b;
        }
        #pragma unroll
        for (int st = 16; st >= 1; st >>= 1) {
            #pragma unroll
            for (int i2 = 0; i2 < 32; ++i2) {
                if ((i2 & st) == 0) {
                    unsigned long long lo = kreg[i2], hi = kreg[i2 | st];
                    kreg[i2]      = lo < hi ? hi : lo;
                    kreg[i2 | st] = lo < hi ? lo : hi;
                }
            }
        }
        __syncthreads();
    }

    #pragma unroll
    for (int s = 1; s <= 4; s <<= 1) {
        #pragma unroll
        for (int i = 0; i < 16; ++i) {
            unsigned long long pa = shfl_xor_u64(kreg[31-i], s);
            unsigned long long pb = shfl_xor_u64(kreg[i],    s);
            if (pa > kreg[i])    kreg[i]    = pa;
            if (pb > kreg[31-i]) kreg[31-i] = pb;
        }
        #pragma unroll
        for (int st = 16; st >= 1; st >>= 1) {
            #pragma unroll
            for (int i2 = 0; i2 < 32; ++i2) {
                if ((i2 & st) == 0) {
                    unsigned long long lo = kreg[i2], hi = kreg[i2 | st];
                    kreg[i2]      = lo < hi ? hi : lo;
                    kreg[i2 | st] = lo < hi ? lo : hi;
                }
            }
        }
    }

    float* wrow = ksbuf + 4352;
    int*   irow = (int*)(ksbuf + 4352 + 1088);
    if (ssub == 0) {
        float w[32];
        #pragma unroll
        for (int i = 0; i < 32; ++i) {
            unsigned um = (unsigned)(kreg[i] >> 32);
            unsigned ub = (um & 0x80000000u) ? (um ^ 0x80000000u) : ~um;
            w[i] = __uint_as_float(ub);
        }
        float m = w[0];
        float s = 0.f;
        #pragma unroll
        for (int i = 0; i < 32; ++i) { w[i] = expf(w[i] - m); s += w[i]; }
        float inv = 1.f / s;
        #pragma unroll
        for (int i = 0; i < 32; ++i) {
            wrow[srow*33 + i] = w[i] * inv;
            irow[srow*33 + i] = 2047 - (int)(unsigned)(kreg[i] & 0xffffffffull);
        }
    }
    __syncthreads();

    const int wid = tid >> 6, lane = tid & 63;
    const int b = bh >> 3, h = bh & 7;
    for (int rr = wid; rr < 32; rr += 4) {
        float accv = 0.f;
        #pragma unroll
        for (int i = 0; i < 32; ++i) {
            float wgt = wrow[rr*33 + i];
            int   idx = irow[rr*33 + i];
            accv = fmaf(wgt, vb[(size_t)idx * DHEAD + lane], accv);
        }
        size_t oi = ((size_t)(b * T_SEQ + t0 + rr)) * DMODEL + h * DHEAD + lane;
        float s16 = 16.f * accv;
        _Float16 hh = (_Float16)s16;
        outH[oi] = hh;
        outL[oi] = (_Float16)(s16 - (float)hh);
    }
}

// ---------------------------------------------------------------------------
// LayerNorm (+residual); also emits x16 f16 hi/lo planes of the output
// ---------------------------------------------------------------------------
__global__ __launch_bounds__(256) void ln_k(
    const float* __restrict__ x, const float* __restrict__ res,
    const float* __restrict__ g, const float* __restrict__ bb,
    float* __restrict__ out, _Float16* __restrict__ oH, _Float16* __restrict__ oL)
{
    __shared__ float red[8];
    const int row = blockIdx.x;
    const int tid = threadIdx.x;
    const float* xr = x + (size_t)row * DMODEL;
    float v0 = xr[tid], v1 = xr[tid + 256];
    if (res) {
        const float* rr = res + (size_t)row * DMODEL;
        v0 += rr[tid]; v1 += rr[tid + 256];
    }
    float s = v0 + v1;
    #pragma unroll
    for (int o = 1; o < 64; o <<= 1) s += __shfl_xor(s, o);
    const int wid = tid >> 6, lane = tid & 63;
    if (lane == 0) red[wid] = s;
    __syncthreads();
    float mean = (red[0] + red[1] + red[2] + red[3]) * (1.f / DMODEL);
    float d0 = v0 - mean, d1 = v1 - mean;
    float qs = d0*d0 + d1*d1;
    #pragma unroll
    for (int o = 1; o < 64; o <<= 1) qs += __shfl_xor(qs, o);
    if (lane == 0) red[4 + wid] = qs;
    __syncthreads();
    float var = (red[4] + red[5] + red[6] + red[7]) * (1.f / DMODEL);
    float rs = rsqrtf(var + 1e-5f);
    float o0 = d0 * rs * g[tid]       + bb[tid];
    float o1 = d1 * rs * g[tid + 256] + bb[tid + 256];
    size_t base = (size_t)row * DMODEL;
    out[base + tid]       = o0;
    out[base + tid + 256] = o1;
    float s0 = 16.f * o0, s1 = 16.f * o1;
    _Float16 h0 = (_Float16)s0, h1 = (_Float16)s1;
    oH[base + tid]       = h0;
    oH[base + tid + 256] = h1;
    oL[base + tid]       = (_Float16)(s0 - (float)h0);
    oL[base + tid + 256] = (_Float16)(s1 - (float)h1);
}

// ---------------------------------------------------------------------------
// Mean pool, two-stage: 64-block partial sums over T/16 chunks, then reduce
// ---------------------------------------------------------------------------
__global__ __launch_bounds__(256) void pool_k(
    const float* __restrict__ h, float* __restrict__ part)
{
    const int chunk = blockIdx.x & 15;                 // T chunk
    const int idx = (blockIdx.x >> 4) * 256 + threadIdx.x;  // 0..1023 (b,d)
    const int b = idx >> 9, d = idx & 511;
    const float* p = h + ((size_t)b * T_SEQ + chunk * 128) * DMODEL + d;
    float s = 0.f;
    for (int t = 0; t < 128; ++t) s += p[(size_t)t * DMODEL];
    part[chunk * 1024 + idx] = s;
}

__global__ __launch_bounds__(256) void poolsum_k(
    const float* __restrict__ part, float* __restrict__ pooled)
{
    int idx = blockIdx.x * 256 + threadIdx.x;          // 0..1023
    float s = 0.f;
    #pragma unroll
    for (int c = 0; c < 16; ++c) s += part[c * 1024 + idx];
    pooled[idx] = s * (1.f / T_SEQ);
}

__global__ __launch_bounds__(256) void cls_k(
    const float* __restrict__ pooled, const float* __restrict__ w,
    const float* __restrict__ bias, float* __restrict__ out)
{
    const int wid = threadIdx.x >> 6, lane = threadIdx.x & 63;
    const int oi = blockIdx.x * 4 + wid;
    const int b = oi >> 8, o = oi & 255;
    const float* pr = pooled + b * DMODEL;
    const float* wr = w + (size_t)o * DMODEL;
    float s = 0.f;
    for (int d = lane; d < DMODEL; d += 64) s = fmaf(pr[d], wr[d], s);
    #pragma unroll
    for (int off = 1; off < 64; off <<= 1) s += __shfl_xor(s, off);
    if (lane == 0) out[oi] = s + bias[o];
}

// ---------------------------------------------------------------------------
extern "C" void kernel_launch(void* const* d_in, const int* in_sizes, int n_in,
                              void* d_out, int out_size, void* d_ws, size_t ws_size,
                              hipStream_t stream)
{
    const float* x     = (const float*)d_in[0];
    const float* emb_w = (const float*)d_in[1];
    const float* emb_b = (const float*)d_in[2];
    const float* pos   = (const float*)d_in[3];
    const float* wq    = (const float*)d_in[4];
    const float* bq    = (const float*)d_in[5];
    const float* wk    = (const float*)d_in[6];
    const float* bk    = (const float*)d_in[7];
    const float* wv    = (const float*)d_in[8];
    const float* bv    = (const float*)d_in[9];
    const float* wo    = (const float*)d_in[10];
    const float* bo    = (const float*)d_in[11];
    const float* ln1g  = (const float*)d_in[12];
    const float* ln1b  = (const float*)d_in[13];
    const float* fc1w  = (const float*)d_in[14];
    const float* fc1b  = (const float*)d_in[15];
    const float* fc2w  = (const float*)d_in[16];
    const float* fc2b  = (const float*)d_in[17];
    const float* ln2g  = (const float*)d_in[18];
    const float* ln2b  = (const float*)d_in[19];
    const float* fng   = (const float*)d_in[20];
    const float* fnb   = (const float*)d_in[21];
    const float* clsw  = (const float*)d_in[22];
    const float* clsb  = (const float*)d_in[23];

    float* ws = (float*)d_ws;
    const size_t SZ  = (size_t)MROWS * DMODEL;       // 2,097,152 floats
    const size_t HP  = SZ / 2;
    float*     h     = ws;
    float*     qb    = ws + 1*SZ;
    float*     kTb   = ws + 2*SZ;
    float*     vbuf  = ws + 3*SZ;
    float*     t1    = ws + 4*SZ;
    _Float16*  hH    = (_Float16*)(ws + 5*SZ);
    _Float16*  hL    = (_Float16*)(ws + 5*SZ + HP);
    _Float16*  aoH   = (_Float16*)(ws + 6*SZ);
    _Float16*  aoL   = (_Float16*)(ws + 6*SZ + HP);
    _Float16*  WcatH = (_Float16*)(ws + 7*SZ);
    _Float16*  WcatL = (_Float16*)(ws + 7*SZ + 393216);
    _Float16*  WoH   = (_Float16*)(ws + 7*SZ + 786432);
    _Float16*  WoL   = (_Float16*)(ws + 7*SZ + 917504);
    _Float16*  W1H   = (_Float16*)(ws + 7*SZ + 1048576);
    _Float16*  W1L   = (_Float16*)(ws + 7*SZ + 1572864);
    _Float16*  W2H   = (_Float16*)(ws + 7*SZ + 2097152);
    _Float16*  W2L   = (_Float16*)(ws + 7*SZ + 2621440);
    float*     bcat  = ws + 7*SZ + 3145728;
    float*     pooled= ws + 7*SZ + 3145728 + 1536;
    float*     part  = ws + 7*SZ + 3145728 + 1536 + 1024;   // 16x1024 partials
    _Float16*  hid   = (_Float16*)qb;
    const size_t needed = (7*SZ + 3145728 + 1536 + 1024 + 16384) * sizeof(float);
    if (ws_size < needed) return;

    dim3 blk(256);

    gemm_k<64,1,0><<<dim3(DMODEL/64, MROWS/128), blk, 0, stream>>>(
        x, emb_w, emb_b, pos, h, MROWS, DMODEL, 128);
    cvtw_k<<<dim3((int)(SZ/256)), blk, 0, stream>>>(h, hH, hL, (int)SZ, 16.f);

    for (int l = 0; l < NLAYER; ++l) {
        const float* wq_l = wq + (size_t)l*DMODEL*DMODEL;
        const float* bq_l = bq + (size_t)l*DMODEL;
        const float* wk_l = wk + (size_t)l*DMODEL*DMODEL;
        const float* bk_l = bk + (size_t)l*DMODEL;
        const float* wv_l = wv + (size_t)l*DMODEL*DMODEL;
        const float* bv_l = bv + (size_t)l*DMODEL;
        const float* wo_l = wo + (size_t)l*DMODEL*DMODEL;
        const float* bo_l = bo + (size_t)l*DMODEL;
        const float* f1w_l = fc1w + (size_t)l*FDIM*DMODEL;
        const float* f1b_l = fc1b + (size_t)l*FDIM;
        const float* f2w_l = fc2w + (size_t)l*DMODEL*FDIM;
        const float* f2b_l = fc2b + (size_t)l*DMODEL;

        cat_k<<<dim3(3079), blk, 0, stream>>>(wq_l, wk_l, wv_l, bq_l, bk_l, bv_l,
                                              WcatH, WcatL, bcat);
        cvtw_k<<<dim3(1024), blk, 0, stream>>>(wo_l, WoH, WoL, 262144, 64.f);
        cvtw_k<<<dim3(4096), blk, 0, stream>>>(f1w_l, W1H, W1L, 1048576, 64.f);
        cvtw_k<<<dim3(4096), blk, 0, stream>>>(f2w_l, W2H, W2L, 1048576, 64.f);

        mgemm_k<0,0,1><<<dim3(12, 32), blk, 0, stream>>>(
            hH, hL, WcatH, WcatL, bcat, qb, t1, vbuf, MROWS, 1536, DMODEL);
        transpose_k<<<dim3(MROWS/32, DMODEL/32), blk, 0, stream>>>(t1, kTb);

        attn_k<<<dim3(T_SEQ/32, NB*NHEAD), blk, 0, stream>>>(qb, kTb, vbuf, aoH, aoL);

        mgemm_k<0,2,0><<<dim3(4, 32), blk, 0, stream>>>(
            aoH, aoL, WoH, WoL, bo_l, t1, nullptr, nullptr, MROWS, DMODEL, DMODEL);
        ln_k<<<dim3(MROWS), blk, 0, stream>>>(h, t1, ln1g + (size_t)l*DMODEL,
                                              ln1b + (size_t)l*DMODEL, h, hH, hL);

        mgemm_k<0,3,0><<<dim3(16, 32), blk, 0, stream>>>(
            hH, hL, W1H, W1L, f1b_l, (float*)hid, nullptr, nullptr, MROWS, FDIM, DMODEL);
        mgemm_k<1,2,0><<<dim3(4, 32), blk, 0, stream>>>(
            hid, nullptr, W2H, W2L, f2b_l, t1, nullptr, nullptr, MROWS, DMODEL, FDIM);
        ln_k<<<dim3(MROWS), blk, 0, stream>>>(h, t1, ln2g + (size_t)l*DMODEL,
                                              ln2b + (size_t)l*DMODEL, h, hH, hL);
    }

    ln_k<<<dim3(MROWS), blk, 0, stream>>>(h, nullptr, fng, fnb, h, hH, hL);
    pool_k<<<dim3(64), blk, 0, stream>>>(h, part);
    poolsum_k<<<dim3(4), blk, 0, stream>>>(part, pooled);
    cls_k<<<dim3(128), blk, 0, stream>>>(pooled, clsw, clsb, (float*)d_out);
}

// Round 6
// 1653.635 us; speedup vs baseline: 8.9845x; 1.5759x over previous
//
#include <hip/hip_runtime.h>
#include <math.h>
#include <float.h>

#define T_SEQ  2048
#define DMODEL 512
#define NHEAD  8
#define DHEAD  64
#define FDIM   2048
#define NLAYER 4
#define NB     2
#define MROWS  (NB*T_SEQ)   // 4096

typedef _Float16 f16x8 __attribute__((ext_vector_type(8)));
typedef float    f32x4 __attribute__((ext_vector_type(4)));

// ---------------------------------------------------------------------------
// fp32 vector GEMM — kept only for the embedding (K=128, 0.5 GF)
// ---------------------------------------------------------------------------
template<int BN, int EPI, int LAYOUT>
__global__ __launch_bounds__(256) void gemm_k(
    const float* __restrict__ A, const float* __restrict__ W,
    const float* __restrict__ bias, const float* __restrict__ pos,
    float* __restrict__ C, int M, int N, int K)
{
    constexpr int BM = 128;
    constexpr int BK = 32;
    constexpr int MN = BN / 16;
    __shared__ float As[BK][BM + 4];
    __shared__ float Ws[BK][BN + 4];
    const int tid = threadIdx.x;
    const int n0 = blockIdx.x * BN;
    const int m0 = blockIdx.y * BM;
    const int tx = tid & 15;
    const int ty = tid >> 4;

    float acc[8][MN];
    #pragma unroll
    for (int i = 0; i < 8; ++i)
        #pragma unroll
        for (int j = 0; j < MN; ++j) acc[i][j] = 0.f;

    for (int k0 = 0; k0 < K; k0 += BK) {
        #pragma unroll
        for (int it = 0; it < 4; ++it) {
            int qq = tid + 256 * it;
            int m = qq >> 3, kq = qq & 7;
            float4 v4 = *(const float4*)(A + (size_t)(m0 + m) * K + k0 + kq * 4);
            As[kq*4+0][m] = v4.x; As[kq*4+1][m] = v4.y;
            As[kq*4+2][m] = v4.z; As[kq*4+3][m] = v4.w;
        }
        #pragma unroll
        for (int it = 0; it < BN/32; ++it) {
            int qq = tid + 256 * it;
            int n = qq >> 3, kq = qq & 7;
            float4 v4 = *(const float4*)(W + (size_t)(n0 + n) * K + k0 + kq * 4);
            Ws[kq*4+0][n] = v4.x; Ws[kq*4+1][n] = v4.y;
            Ws[kq*4+2][n] = v4.z; Ws[kq*4+3][n] = v4.w;
        }
        __syncthreads();
        for (int kk = 0; kk < BK; ++kk) {
            float a[8], b[MN];
            float4 a0 = *(const float4*)&As[kk][ty*8];
            float4 a1 = *(const float4*)&As[kk][ty*8+4];
            a[0]=a0.x; a[1]=a0.y; a[2]=a0.z; a[3]=a0.w;
            a[4]=a1.x; a[5]=a1.y; a[6]=a1.z; a[7]=a1.w;
            float4 b0 = *(const float4*)&Ws[kk][tx*4];
            b[0]=b0.x; b[1]=b0.y; b[2]=b0.z; b[3]=b0.w;
            if constexpr (MN == 8) {
                float4 b1 = *(const float4*)&Ws[kk][64 + tx*4];
                b[4]=b1.x; b[5]=b1.y; b[6]=b1.z; b[7]=b1.w;
            }
            #pragma unroll
            for (int i = 0; i < 8; ++i)
                #pragma unroll
                for (int j = 0; j < MN; ++j)
                    acc[i][j] = fmaf(a[i], b[j], acc[i][j]);
        }
        __syncthreads();
    }

    #pragma unroll
    for (int i = 0; i < 8; ++i) {
        int m = m0 + ty*8 + i;
        #pragma unroll
        for (int jb = 0; jb < MN/4; ++jb) {
            int nn = n0 + jb*64 + tx*4;
            float4 r;
            r.x = acc[i][jb*4+0] + bias[nn+0];
            r.y = acc[i][jb*4+1] + bias[nn+1];
            r.z = acc[i][jb*4+2] + bias[nn+2];
            r.w = acc[i][jb*4+3] + bias[nn+3];
            if constexpr (EPI == 1) {
                const float* pp = pos + (size_t)(m & (T_SEQ-1)) * DMODEL + nn;
                r.x += pp[0]; r.y += pp[1]; r.z += pp[2]; r.w += pp[3];
            }
            if constexpr (EPI == 2) {
                r.x = r.x > 0.5f ? 1.f : 0.f;
                r.y = r.y > 0.5f ? 1.f : 0.f;
                r.z = r.z > 0.5f ? 1.f : 0.f;
                r.w = r.w > 0.5f ? 1.f : 0.f;
            }
            if constexpr (LAYOUT == 0) {
                *(float4*)(C + (size_t)m * N + nn) = r;
            } else {
                int b_ = m >> 11, t_ = m & (T_SEQ-1);
                int h_ = nn >> 6, d_ = nn & 63;
                *(float4*)(C + (((size_t)(b_*NHEAD + h_)*T_SEQ + t_) << 6) + d_) = r;
            }
        }
    }
}

// ---------------------------------------------------------------------------
// f16-split MFMA GEMM: C = (1/1024)·A'[M,K]·W'[N,K]^T + bias
// ---------------------------------------------------------------------------
template<int ASRC, int EPI, int LAYOUT>
__global__ __launch_bounds__(256, 2) void mgemm_k(
    const _Float16* __restrict__ AH, const _Float16* __restrict__ AL,
    const _Float16* __restrict__ WH, const _Float16* __restrict__ WL,
    const float* __restrict__ bias,
    float* __restrict__ O0, float* __restrict__ O1, float* __restrict__ O2,
    int M, int N, int K)
{
    __shared__ _Float16 AsH[4][128][8];
    __shared__ _Float16 AsL[4][128][8];
    __shared__ _Float16 WsH[4][128][8];
    __shared__ _Float16 WsL[4][128][8];

    const int tid = threadIdx.x;
    const int n0 = blockIdx.x * 128;
    const int m0 = blockIdx.y * 128;
    const int wv = tid >> 6, lane = tid & 63;
    const int mw = (wv >> 1) * 64, nw = (wv & 1) * 64;
    const int fr = lane & 15;
    const int kb = lane >> 4;

    const int srow = tid >> 1;
    const int skoff = (tid & 1) * 16;
    const int skb = skoff >> 3;

    f32x4 acc[4][4];
    #pragma unroll
    for (int i = 0; i < 4; ++i)
        #pragma unroll
        for (int j = 0; j < 4; ++j) acc[i][j] = (f32x4)(0.f);

    for (int k0 = 0; k0 < K; k0 += 32) {
        {
            const _Float16* ap = AH + (size_t)(m0 + srow) * K + k0 + skoff;
            *(f16x8*)&AsH[skb  ][srow][0] = *(const f16x8*)ap;
            *(f16x8*)&AsH[skb+1][srow][0] = *(const f16x8*)(ap + 8);
            if constexpr (ASRC == 0) {
                const _Float16* alp = AL + (size_t)(m0 + srow) * K + k0 + skoff;
                *(f16x8*)&AsL[skb  ][srow][0] = *(const f16x8*)alp;
                *(f16x8*)&AsL[skb+1][srow][0] = *(const f16x8*)(alp + 8);
            }
        }
        {
            const _Float16* wp = WH + (size_t)(n0 + srow) * K + k0 + skoff;
            *(f16x8*)&WsH[skb  ][srow][0] = *(const f16x8*)wp;
            *(f16x8*)&WsH[skb+1][srow][0] = *(const f16x8*)(wp + 8);
            const _Float16* wlp = WL + (size_t)(n0 + srow) * K + k0 + skoff;
            *(f16x8*)&WsL[skb  ][srow][0] = *(const f16x8*)wlp;
            *(f16x8*)&WsL[skb+1][srow][0] = *(const f16x8*)(wlp + 8);
        }
        __syncthreads();

        f16x8 aH[4], aL[4], bH[4], bL[4];
        #pragma unroll
        for (int i = 0; i < 4; ++i) {
            aH[i] = *(const f16x8*)&AsH[kb][mw + i*16 + fr][0];
            if constexpr (ASRC == 0) aL[i] = *(const f16x8*)&AsL[kb][mw + i*16 + fr][0];
            bH[i] = *(const f16x8*)&WsH[kb][nw + i*16 + fr][0];
            bL[i] = *(const f16x8*)&WsL[kb][nw + i*16 + fr][0];
        }
        #pragma unroll
        for (int i = 0; i < 4; ++i)
            #pragma unroll
            for (int j = 0; j < 4; ++j) {
                acc[i][j] = __builtin_amdgcn_mfma_f32_16x16x32_f16(aH[i], bH[j], acc[i][j], 0, 0, 0);
                acc[i][j] = __builtin_amdgcn_mfma_f32_16x16x32_f16(aH[i], bL[j], acc[i][j], 0, 0, 0);
                if constexpr (ASRC == 0)
                    acc[i][j] = __builtin_amdgcn_mfma_f32_16x16x32_f16(aL[i], bH[j], acc[i][j], 0, 0, 0);
            }
        __syncthreads();
    }

    const int q = lane >> 4;
    #pragma unroll
    for (int j = 0; j < 4; ++j) {
        int n = n0 + nw + j*16 + fr;
        float bv = bias[n];
        #pragma unroll
        for (int i = 0; i < 4; ++i) {
            #pragma unroll
            for (int r = 0; r < 4; ++r) {
                int m = m0 + mw + i*16 + q*4 + r;
                float val = acc[i][j][r] * (1.f/1024.f) + bv;
                if constexpr (EPI == 2) val = val > 0.5f ? 1.f : 0.f;
                if constexpr (EPI == 3) {
                    ((_Float16*)O0)[(size_t)m * N + n] = (val > 0.5f) ? (_Float16)16.f : (_Float16)0.f;
                } else if constexpr (LAYOUT == 0) {
                    O0[(size_t)m * N + n] = val;
                } else {
                    int b_ = m >> 11, t_ = m & (T_SEQ-1);
                    if (n < 512) {
                        O0[(((size_t)(b_*NHEAD + (n>>6))*T_SEQ + t_) << 6) + (n & 63)] = val;
                    } else if (n < 1024) {
                        O1[(size_t)m * 512 + (n - 512)] = val;
                    } else {
                        int nn = n - 1024;
                        O2[(((size_t)(b_*NHEAD + (nn>>6))*T_SEQ + t_) << 6) + (nn & 63)] = val;
                    }
                }
            }
        }
    }
}

// ---------------------------------------------------------------------------
__global__ __launch_bounds__(256) void cvtw_k(
    const float* __restrict__ w, _Float16* __restrict__ H, _Float16* __restrict__ L,
    int n, float scale)
{
    int i = blockIdx.x * 256 + threadIdx.x;
    if (i < n) {
        float s = scale * w[i];
        _Float16 h = (_Float16)s;
        H[i] = h;
        L[i] = (_Float16)(s - (float)h);
    }
}

__global__ __launch_bounds__(256) void cat_k(
    const float* __restrict__ wq, const float* __restrict__ wk, const float* __restrict__ wv,
    const float* __restrict__ bq, const float* __restrict__ bk, const float* __restrict__ bv,
    _Float16* __restrict__ WH, _Float16* __restrict__ WL, float* __restrict__ bcat)
{
    int i = blockIdx.x * 256 + threadIdx.x;
    if (i < 786432) {
        int src = i >> 18, off = i & 262143;
        float w = (src == 0 ? wq : (src == 1 ? wk : wv))[off];
        float s = 64.f * w;
        _Float16 h = (_Float16)s;
        WH[i] = h;
        WL[i] = (_Float16)(s - (float)h);
    } else if (i < 786432 + 1536) {
        int j = i - 786432;
        int src = j >> 9, off = j & 511;
        bcat[j] = (src == 0 ? bq : (src == 1 ? bk : bv))[off];
    }
}

// ---------------------------------------------------------------------------
__global__ __launch_bounds__(256) void transpose_k(
    const float* __restrict__ in, float* __restrict__ out)
{
    __shared__ float tile[32][33];
    const int t0 = blockIdx.x * 32;
    const int c0 = blockIdx.y * 32;
    const int tid = threadIdx.x;
    const int r = tid >> 5;
    const int c = tid & 31;
    #pragma unroll
    for (int i = 0; i < 4; ++i)
        tile[r + 8*i][c] = in[(size_t)(t0 + r + 8*i) * DMODEL + c0 + c];
    __syncthreads();
    #pragma unroll
    for (int i = 0; i < 4; ++i) {
        int n = c0 + r + 8*i;
        int m = t0 + c;
        int b = m >> 11, t = m & (T_SEQ-1);
        out[((size_t)(b * DMODEL + n)) * T_SEQ + t] = tile[c][r + 8*i];
    }
}

// ---------------------------------------------------------------------------
// Fused sparse attention v3 — u32 packed keys, no register prefetch.
//
// key = (mono(f32 score) & 0xFFFFF800) | (2047 - j): top 21 bits of the
// monotone-mapped value + 11-bit reversed index. Selection matches jax
// top_k except when two scores agree in their top 21 bits (rel diff <2^-21)
// near the cutoff — output perturbation ~1e-5, threshold is 2.6e-3.
// Per-thread state: kreg u32[32] + cand u32[16] + acc 16 ≈ 80 VGPRs < 96:
// no scratch (rounds 3-5 spilled ~350 MB/dispatch with u64 keys + prefetch).
// ---------------------------------------------------------------------------
__global__ __launch_bounds__(256, 2) void attn_k(
    const float* __restrict__ q, const float* __restrict__ kT,
    const float* __restrict__ v, _Float16* __restrict__ outH, _Float16* __restrict__ outL)
{
    __shared__ float qsT[64][36];
    __shared__ float ksbuf[64*128];   // aliased: ks[64][128] | ss[32][132] | w/idx

    const int tid = threadIdx.x;
    const int bh  = blockIdx.y;
    const int t0  = blockIdx.x * 32;
    const float* qb = q  + ((size_t)bh * T_SEQ + t0) * DHEAD;
    const float* kb = kT + (size_t)bh * DHEAD * T_SEQ;
    const float* vb = v  + (size_t)bh * T_SEQ * DHEAD;

    #pragma unroll
    for (int it = 0; it < 8; ++it) {
        int e = tid + 256*it;
        qsT[e & 63][e >> 6] = qb[e];
    }

    unsigned kreg[32];                 // running top-32 keys, sorted desc
    #pragma unroll
    for (int i = 0; i < 32; ++i) kreg[i] = 0u;

    const int ry = tid >> 5;
    const int tx = tid & 31;
    const int srow = tid >> 3;
    const int ssub = tid & 7;
    const int sd = tid >> 5;           // staging d base (0..7)
    const int sq = tid & 31;           // staging col/4
    float (*ks)[128] = (float(*)[128])ksbuf;
    float (*ss)[132] = (float(*)[132])ksbuf;

    for (int jt = 0; jt < 16; ++jt) {
        const int j0 = jt * 128;
        // stage K tile [64 d][128 j]
        {
            const float* kp = kb + (size_t)sd*T_SEQ + j0 + sq*4;
            float4 t[8];
            #pragma unroll
            for (int it = 0; it < 8; ++it)
                t[it] = *(const float4*)(kp + (size_t)(8*it)*T_SEQ);
            #pragma unroll
            for (int it = 0; it < 8; ++it)
                *(float4*)&ks[sd + 8*it][sq*4] = t[it];
        }
        __syncthreads();                 // A: qsT + ks ready
        float acc[4][4];
        #pragma unroll
        for (int i = 0; i < 4; ++i)
            #pragma unroll
            for (int j = 0; j < 4; ++j) acc[i][j] = 0.f;
        #pragma unroll 8
        for (int d = 0; d < 64; ++d) {
            float4 qa4 = *(const float4*)&qsT[d][ry*4];
            float4 kb4 = *(const float4*)&ks[d][tx*4];
            float qa[4] = {qa4.x, qa4.y, qa4.z, qa4.w};
            float kv[4] = {kb4.x, kb4.y, kb4.z, kb4.w};
            #pragma unroll
            for (int i = 0; i < 4; ++i)
                #pragma unroll
                for (int j = 0; j < 4; ++j)
                    acc[i][j] = fmaf(qa[i], kv[j], acc[i][j]);
        }
        __syncthreads();                 // B: ks reads done before ss overwrite
        #pragma unroll
        for (int i = 0; i < 4; ++i) {
            float4 r4;
            r4.x = acc[i][0]*0.125f; r4.y = acc[i][1]*0.125f;
            r4.z = acc[i][2]*0.125f; r4.w = acc[i][3]*0.125f;
            *(float4*)&ss[ry*4+i][tx*4] = r4;
        }
        __syncthreads();                 // C: scores visible

        // branch-free selection: 16 candidates / thread, u32 packed keys
        float4 c4[4];
        {
            const float* ssr = &ss[srow][0] + ssub*4;
            #pragma unroll
            for (int g = 0; g < 4; ++g) c4[g] = *(const float4*)(ssr + g*32);
        }
        unsigned cand[16];
        #pragma unroll
        for (int g = 0; g < 4; ++g) {
            float vg[4] = {c4[g].x, c4[g].y, c4[g].z, c4[g].w};
            #pragma unroll
            for (int r = 0; r < 4; ++r) {
                unsigned u = __float_as_uint(vg[r]);
                u ^= (unsigned)((int)u >> 31) | 0x80000000u;   // monotone fp32->u32
                int col = ssub*4 + g*32 + r;
                cand[g*4+r] = (u & 0xFFFFF800u) | (unsigned)(2047 - (j0 + col));
            }
        }
        // bitonic sort-16 desc (static indices)
        #pragma unroll
        for (int k2 = 2; k2 <= 16; k2 <<= 1) {
            #pragma unroll
            for (int j2 = k2 >> 1; j2 > 0; j2 >>= 1) {
                #pragma unroll
                for (int i2 = 0; i2 < 16; ++i2) {
                    int l2 = i2 ^ j2;
                    if (l2 > i2) {
                        unsigned a = cand[i2], b = cand[l2];
                        bool sw = ((i2 & k2) == 0) ? (a < b) : (a > b);
                        cand[i2] = sw ? b : a;
                        cand[l2] = sw ? a : b;
                    }
                }
            }
        }
        // merge: top-32(kreg ∪ cand), bitonic identity + clean
        #pragma unroll
        for (int j2 = 0; j2 < 16; ++j2) {
            unsigned b = cand[15 - j2];
            if (kreg[16 + j2] < b) kreg[16 + j2] = b;
        }
        #pragma unroll
        for (int st = 16; st >= 1; st >>= 1) {
            #pragma unroll
            for (int i2 = 0; i2 < 32; ++i2) {
                if ((i2 & st) == 0) {
                    unsigned lo = kreg[i2], hi = kreg[i2 | st];
                    kreg[i2]      = lo < hi ? hi : lo;
                    kreg[i2 | st] = lo < hi ? lo : hi;
                }
            }
        }
        __syncthreads();                 // D: scan done before next ks write
    }

    // merge 8 per-sub lists (lane^1,2,4) -> global top-32 everywhere
    #pragma unroll
    for (int s = 1; s <= 4; s <<= 1) {
        #pragma unroll
        for (int i = 0; i < 16; ++i) {
            unsigned pa = (unsigned)__shfl_xor((int)kreg[31-i], s, 64);
            unsigned pb = (unsigned)__shfl_xor((int)kreg[i],    s, 64);
            if (pa > kreg[i])    kreg[i]    = pa;
            if (pb > kreg[31-i]) kreg[31-i] = pb;
        }
        #pragma unroll
        for (int st = 16; st >= 1; st >>= 1) {
            #pragma unroll
            for (int i2 = 0; i2 < 32; ++i2) {
                if ((i2 & st) == 0) {
                    unsigned lo = kreg[i2], hi = kreg[i2 | st];
                    kreg[i2]      = lo < hi ? hi : lo;
                    kreg[i2 | st] = lo < hi ? lo : hi;
                }
            }
        }
    }

    // softmax over kept 32 (bucket-representative logits, err < 2^-20 rel)
    float* wrow = ksbuf + 4352;                  // 32 x stride-33 weights
    int*   irow = (int*)(ksbuf + 4352 + 1088);   // 32 x stride-33 indices
    if (ssub == 0) {
        float w[32];
        #pragma unroll
        for (int i = 0; i < 32; ++i) {
            unsigned um = kreg[i] & 0xFFFFF800u;
            unsigned ub = (um & 0x80000000u) ? (um ^ 0x80000000u) : ~um;
            w[i] = __uint_as_float(ub);
        }
        float m = w[0];                  // sorted desc -> max
        float s = 0.f;
        #pragma unroll
        for (int i = 0; i < 32; ++i) { w[i] = expf(w[i] - m); s += w[i]; }
        float inv = 1.f / s;
        #pragma unroll
        for (int i = 0; i < 32; ++i) {
            wrow[srow*33 + i] = w[i] * inv;
            irow[srow*33 + i] = 2047 - (int)(kreg[i] & 0x7FFu);
        }
    }
    __syncthreads();

    // AV: wave per row-group, lane = head dim
    const int wid = tid >> 6, lane = tid & 63;
    const int b = bh >> 3, h = bh & 7;
    for (int rr = wid; rr < 32; rr += 4) {
        float accv = 0.f;
        #pragma unroll
        for (int i = 0; i < 32; ++i) {
            float wgt = wrow[rr*33 + i];
            int   idx = irow[rr*33 + i];
            accv = fmaf(wgt, vb[(size_t)idx * DHEAD + lane], accv);
        }
        size_t oi = ((size_t)(b * T_SEQ + t0 + rr)) * DMODEL + h * DHEAD + lane;
        float s16 = 16.f * accv;
        _Float16 hh = (_Float16)s16;
        outH[oi] = hh;
        outL[oi] = (_Float16)(s16 - (float)hh);
    }
}

// ---------------------------------------------------------------------------
// LayerNorm (+residual); also emits x16 f16 hi/lo planes of the output
// ---------------------------------------------------------------------------
__global__ __launch_bounds__(256) void ln_k(
    const float* __restrict__ x, const float* __restrict__ res,
    const float* __restrict__ g, const float* __restrict__ bb,
    float* __restrict__ out, _Float16* __restrict__ oH, _Float16* __restrict__ oL)
{
    __shared__ float red[8];
    const int row = blockIdx.x;
    const int tid = threadIdx.x;
    const float* xr = x + (size_t)row * DMODEL;
    float v0 = xr[tid], v1 = xr[tid + 256];
    if (res) {
        const float* rr = res + (size_t)row * DMODEL;
        v0 += rr[tid]; v1 += rr[tid + 256];
    }
    float s = v0 + v1;
    #pragma unroll
    for (int o = 1; o < 64; o <<= 1) s += __shfl_xor(s, o);
    const int wid = tid >> 6, lane = tid & 63;
    if (lane == 0) red[wid] = s;
    __syncthreads();
    float mean = (red[0] + red[1] + red[2] + red[3]) * (1.f / DMODEL);
    float d0 = v0 - mean, d1 = v1 - mean;
    float qs = d0*d0 + d1*d1;
    #pragma unroll
    for (int o = 1; o < 64; o <<= 1) qs += __shfl_xor(qs, o);
    if (lane == 0) red[4 + wid] = qs;
    __syncthreads();
    float var = (red[4] + red[5] + red[6] + red[7]) * (1.f / DMODEL);
    float rs = rsqrtf(var + 1e-5f);
    float o0 = d0 * rs * g[tid]       + bb[tid];
    float o1 = d1 * rs * g[tid + 256] + bb[tid + 256];
    size_t base = (size_t)row * DMODEL;
    out[base + tid]       = o0;
    out[base + tid + 256] = o1;
    float s0 = 16.f * o0, s1 = 16.f * o1;
    _Float16 h0 = (_Float16)s0, h1 = (_Float16)s1;
    oH[base + tid]       = h0;
    oH[base + tid + 256] = h1;
    oL[base + tid]       = (_Float16)(s0 - (float)h0);
    oL[base + tid + 256] = (_Float16)(s1 - (float)h1);
}

// ---------------------------------------------------------------------------
__global__ __launch_bounds__(256) void pool_k(
    const float* __restrict__ h, float* __restrict__ part)
{
    const int chunk = blockIdx.x & 15;
    const int idx = (blockIdx.x >> 4) * 256 + threadIdx.x;
    const int b = idx >> 9, d = idx & 511;
    const float* p = h + ((size_t)b * T_SEQ + chunk * 128) * DMODEL + d;
    float s = 0.f;
    for (int t = 0; t < 128; ++t) s += p[(size_t)t * DMODEL];
    part[chunk * 1024 + idx] = s;
}

__global__ __launch_bounds__(256) void poolsum_k(
    const float* __restrict__ part, float* __restrict__ pooled)
{
    int idx = blockIdx.x * 256 + threadIdx.x;
    float s = 0.f;
    #pragma unroll
    for (int c = 0; c < 16; ++c) s += part[c * 1024 + idx];
    pooled[idx] = s * (1.f / T_SEQ);
}

__global__ __launch_bounds__(256) void cls_k(
    const float* __restrict__ pooled, const float* __restrict__ w,
    const float* __restrict__ bias, float* __restrict__ out)
{
    const int wid = threadIdx.x >> 6, lane = threadIdx.x & 63;
    const int oi = blockIdx.x * 4 + wid;
    const int b = oi >> 8, o = oi & 255;
    const float* pr = pooled + b * DMODEL;
    const float* wr = w + (size_t)o * DMODEL;
    float s = 0.f;
    for (int d = lane; d < DMODEL; d += 64) s = fmaf(pr[d], wr[d], s);
    #pragma unroll
    for (int off = 1; off < 64; off <<= 1) s += __shfl_xor(s, off);
    if (lane == 0) out[oi] = s + bias[o];
}

// ---------------------------------------------------------------------------
extern "C" void kernel_launch(void* const* d_in, const int* in_sizes, int n_in,
                              void* d_out, int out_size, void* d_ws, size_t ws_size,
                              hipStream_t stream)
{
    const float* x     = (const float*)d_in[0];
    const float* emb_w = (const float*)d_in[1];
    const float* emb_b = (const float*)d_in[2];
    const float* pos   = (const float*)d_in[3];
    const float* wq    = (const float*)d_in[4];
    const float* bq    = (const float*)d_in[5];
    const float* wk    = (const float*)d_in[6];
    const float* bk    = (const float*)d_in[7];
    const float* wv    = (const float*)d_in[8];
    const float* bv    = (const float*)d_in[9];
    const float* wo    = (const float*)d_in[10];
    const float* bo    = (const float*)d_in[11];
    const float* ln1g  = (const float*)d_in[12];
    const float* ln1b  = (const float*)d_in[13];
    const float* fc1w  = (const float*)d_in[14];
    const float* fc1b  = (const float*)d_in[15];
    const float* fc2w  = (const float*)d_in[16];
    const float* fc2b  = (const float*)d_in[17];
    const float* ln2g  = (const float*)d_in[18];
    const float* ln2b  = (const float*)d_in[19];
    const float* fng   = (const float*)d_in[20];
    const float* fnb   = (const float*)d_in[21];
    const float* clsw  = (const float*)d_in[22];
    const float* clsb  = (const float*)d_in[23];

    float* ws = (float*)d_ws;
    const size_t SZ  = (size_t)MROWS * DMODEL;
    const size_t HP  = SZ / 2;
    float*     h     = ws;
    float*     qb    = ws + 1*SZ;
    float*     kTb   = ws + 2*SZ;
    float*     vbuf  = ws + 3*SZ;
    float*     t1    = ws + 4*SZ;
    _Float16*  hH    = (_Float16*)(ws + 5*SZ);
    _Float16*  hL    = (_Float16*)(ws + 5*SZ + HP);
    _Float16*  aoH   = (_Float16*)(ws + 6*SZ);
    _Float16*  aoL   = (_Float16*)(ws + 6*SZ + HP);
    _Float16*  WcatH = (_Float16*)(ws + 7*SZ);
    _Float16*  WcatL = (_Float16*)(ws + 7*SZ + 393216);
    _Float16*  WoH   = (_Float16*)(ws + 7*SZ + 786432);
    _Float16*  WoL   = (_Float16*)(ws + 7*SZ + 917504);
    _Float16*  W1H   = (_Float16*)(ws + 7*SZ + 1048576);
    _Float16*  W1L   = (_Float16*)(ws + 7*SZ + 1572864);
    _Float16*  W2H   = (_Float16*)(ws + 7*SZ + 2097152);
    _Float16*  W2L   = (_Float16*)(ws + 7*SZ + 2621440);
    float*     bcat  = ws + 7*SZ + 3145728;
    float*     pooled= ws + 7*SZ + 3145728 + 1536;
    float*     part  = ws + 7*SZ + 3145728 + 1536 + 1024;
    _Float16*  hid   = (_Float16*)qb;
    const size_t needed = (7*SZ + 3145728 + 1536 + 1024 + 16384) * sizeof(float);
    if (ws_size < needed) return;

    dim3 blk(256);

    gemm_k<64,1,0><<<dim3(DMODEL/64, MROWS/128), blk, 0, stream>>>(
        x, emb_w, emb_b, pos, h, MROWS, DMODEL, 128);
    cvtw_k<<<dim3((int)(SZ/256)), blk, 0, stream>>>(h, hH, hL, (int)SZ, 16.f);

    for (int l = 0; l < NLAYER; ++l) {
        const float* wq_l = wq + (size_t)l*DMODEL*DMODEL;
        const float* bq_l = bq + (size_t)l*DMODEL;
        const float* wk_l = wk + (size_t)l*DMODEL*DMODEL;
        const float* bk_l = bk + (size_t)l*DMODEL;
        const float* wv_l = wv + (size_t)l*DMODEL*DMODEL;
        const float* bv_l = bv + (size_t)l*DMODEL;
        const float* wo_l = wo + (size_t)l*DMODEL*DMODEL;
        const float* bo_l = bo + (size_t)l*DMODEL;
        const float* f1w_l = fc1w + (size_t)l*FDIM*DMODEL;
        const float* f1b_l = fc1b + (size_t)l*FDIM;
        const float* f2w_l = fc2w + (size_t)l*DMODEL*FDIM;
        const float* f2b_l = fc2b + (size_t)l*DMODEL;

        cat_k<<<dim3(3079), blk, 0, stream>>>(wq_l, wk_l, wv_l, bq_l, bk_l, bv_l,
                                              WcatH, WcatL, bcat);
        cvtw_k<<<dim3(1024), blk, 0, stream>>>(wo_l, WoH, WoL, 262144, 64.f);
        cvtw_k<<<dim3(4096), blk, 0, stream>>>(f1w_l, W1H, W1L, 1048576, 64.f);
        cvtw_k<<<dim3(4096), blk, 0, stream>>>(f2w_l, W2H, W2L, 1048576, 64.f);

        mgemm_k<0,0,1><<<dim3(12, 32), blk, 0, stream>>>(
            hH, hL, WcatH, WcatL, bcat, qb, t1, vbuf, MROWS, 1536, DMODEL);
        transpose_k<<<dim3(MROWS/32, DMODEL/32), blk, 0, stream>>>(t1, kTb);

        attn_k<<<dim3(T_SEQ/32, NB*NHEAD), blk, 0, stream>>>(qb, kTb, vbuf, aoH, aoL);

        mgemm_k<0,2,0><<<dim3(4, 32), blk, 0, stream>>>(
            aoH, aoL, WoH, WoL, bo_l, t1, nullptr, nullptr, MROWS, DMODEL, DMODEL);
        ln_k<<<dim3(MROWS), blk, 0, stream>>>(h, t1, ln1g + (size_t)l*DMODEL,
                                              ln1b + (size_t)l*DMODEL, h, hH, hL);

        mgemm_k<0,3,0><<<dim3(16, 32), blk, 0, stream>>>(
            hH, hL, W1H, W1L, f1b_l, (float*)hid, nullptr, nullptr, MROWS, FDIM, DMODEL);
        mgemm_k<1,2,0><<<dim3(4, 32), blk, 0, stream>>>(
            hid, nullptr, W2H, W2L, f2b_l, t1, nullptr, nullptr, MROWS, DMODEL, FDIM);
        ln_k<<<dim3(MROWS), blk, 0, stream>>>(h, t1, ln2g + (size_t)l*DMODEL,
                                              ln2b + (size_t)l*DMODEL, h, hH, hL);
    }

    ln_k<<<dim3(MROWS), blk, 0, stream>>>(h, nullptr, fng, fnb, h, hH, hL);
    pool_k<<<dim3(64), blk, 0, stream>>>(h, part);
    poolsum_k<<<dim3(4), blk, 0, stream>>>(part, pooled);
    cls_k<<<dim3(128), blk, 0, stream>>>(pooled, clsw, clsb, (float*)d_out);
}

// Round 7
// 1298.187 us; speedup vs baseline: 11.4445x; 1.2738x over previous
//
#include <hip/hip_runtime.h>
#include <math.h>
#include <float.h>

#define T_SEQ  2048
#define DMODEL 512
#define NHEAD  8
#define DHEAD  64
#define FDIM   2048
#define NLAYER 4
#define NB     2
#define MROWS  (NB*T_SEQ)   // 4096

typedef _Float16 f16x8 __attribute__((ext_vector_type(8)));
typedef float    f32x4 __attribute__((ext_vector_type(4)));

// ---------------------------------------------------------------------------
// fp32 vector GEMM — kept only for the embedding (K=128, 0.5 GF)
// ---------------------------------------------------------------------------
template<int BN, int EPI, int LAYOUT>
__global__ __launch_bounds__(256) void gemm_k(
    const float* __restrict__ A, const float* __restrict__ W,
    const float* __restrict__ bias, const float* __restrict__ pos,
    float* __restrict__ C, int M, int N, int K)
{
    constexpr int BM = 128;
    constexpr int BK = 32;
    constexpr int MN = BN / 16;
    __shared__ float As[BK][BM + 4];
    __shared__ float Ws[BK][BN + 4];
    const int tid = threadIdx.x;
    const int n0 = blockIdx.x * BN;
    const int m0 = blockIdx.y * BM;
    const int tx = tid & 15;
    const int ty = tid >> 4;

    float acc[8][MN];
    #pragma unroll
    for (int i = 0; i < 8; ++i)
        #pragma unroll
        for (int j = 0; j < MN; ++j) acc[i][j] = 0.f;

    for (int k0 = 0; k0 < K; k0 += BK) {
        #pragma unroll
        for (int it = 0; it < 4; ++it) {
            int qq = tid + 256 * it;
            int m = qq >> 3, kq = qq & 7;
            float4 v4 = *(const float4*)(A + (size_t)(m0 + m) * K + k0 + kq * 4);
            As[kq*4+0][m] = v4.x; As[kq*4+1][m] = v4.y;
            As[kq*4+2][m] = v4.z; As[kq*4+3][m] = v4.w;
        }
        #pragma unroll
        for (int it = 0; it < BN/32; ++it) {
            int qq = tid + 256 * it;
            int n = qq >> 3, kq = qq & 7;
            float4 v4 = *(const float4*)(W + (size_t)(n0 + n) * K + k0 + kq * 4);
            Ws[kq*4+0][n] = v4.x; Ws[kq*4+1][n] = v4.y;
            Ws[kq*4+2][n] = v4.z; Ws[kq*4+3][n] = v4.w;
        }
        __syncthreads();
        for (int kk = 0; kk < BK; ++kk) {
            float a[8], b[MN];
            float4 a0 = *(const float4*)&As[kk][ty*8];
            float4 a1 = *(const float4*)&As[kk][ty*8+4];
            a[0]=a0.x; a[1]=a0.y; a[2]=a0.z; a[3]=a0.w;
            a[4]=a1.x; a[5]=a1.y; a[6]=a1.z; a[7]=a1.w;
            float4 b0 = *(const float4*)&Ws[kk][tx*4];
            b[0]=b0.x; b[1]=b0.y; b[2]=b0.z; b[3]=b0.w;
            if constexpr (MN == 8) {
                float4 b1 = *(const float4*)&Ws[kk][64 + tx*4];
                b[4]=b1.x; b[5]=b1.y; b[6]=b1.z; b[7]=b1.w;
            }
            #pragma unroll
            for (int i = 0; i < 8; ++i)
                #pragma unroll
                for (int j = 0; j < MN; ++j)
                    acc[i][j] = fmaf(a[i], b[j], acc[i][j]);
        }
        __syncthreads();
    }

    #pragma unroll
    for (int i = 0; i < 8; ++i) {
        int m = m0 + ty*8 + i;
        #pragma unroll
        for (int jb = 0; jb < MN/4; ++jb) {
            int nn = n0 + jb*64 + tx*4;
            float4 r;
            r.x = acc[i][jb*4+0] + bias[nn+0];
            r.y = acc[i][jb*4+1] + bias[nn+1];
            r.z = acc[i][jb*4+2] + bias[nn+2];
            r.w = acc[i][jb*4+3] + bias[nn+3];
            if constexpr (EPI == 1) {
                const float* pp = pos + (size_t)(m & (T_SEQ-1)) * DMODEL + nn;
                r.x += pp[0]; r.y += pp[1]; r.z += pp[2]; r.w += pp[3];
            }
            if constexpr (EPI == 2) {
                r.x = r.x > 0.5f ? 1.f : 0.f;
                r.y = r.y > 0.5f ? 1.f : 0.f;
                r.z = r.z > 0.5f ? 1.f : 0.f;
                r.w = r.w > 0.5f ? 1.f : 0.f;
            }
            *(float4*)(C + (size_t)m * N + nn) = r;
        }
    }
}

// ---------------------------------------------------------------------------
// f16-split MFMA GEMM: C = (1/1024)·A'[M,K]·W'[N,K]^T + bias
// A' = 16·A as (hi,lo) f16 planes; W' = 64·W as (hi,lo) planes (pre-split).
// ASRC: 0 = dual-plane A, 1 = single-plane A (exact spikes, lo==0)
// EPI:  0 = fp32 store; 2 = spike -> fp32; 3 = spike -> f16 plane (x16)
// LAYOUT: 0 = [M,N]
//         2 = fused QKV: n<512  -> q as f16 hi/lo planes (O0,O1) head layout
//                        n<1024 -> k as f16 hi/lo planes (O2,O3) head layout
//                        else   -> v fp32 (O4) head layout
// ---------------------------------------------------------------------------
template<int ASRC, int EPI, int LAYOUT>
__global__ __launch_bounds__(256, 2) void mgemm_k(
    const _Float16* __restrict__ AH, const _Float16* __restrict__ AL,
    const _Float16* __restrict__ WH, const _Float16* __restrict__ WL,
    const float* __restrict__ bias,
    float* __restrict__ O0, float* __restrict__ O1, float* __restrict__ O2,
    float* __restrict__ O3, float* __restrict__ O4,
    int M, int N, int K)
{
    __shared__ _Float16 AsH[4][128][8];
    __shared__ _Float16 AsL[4][128][8];
    __shared__ _Float16 WsH[4][128][8];
    __shared__ _Float16 WsL[4][128][8];

    const int tid = threadIdx.x;
    const int n0 = blockIdx.x * 128;
    const int m0 = blockIdx.y * 128;
    const int wv = tid >> 6, lane = tid & 63;
    const int mw = (wv >> 1) * 64, nw = (wv & 1) * 64;
    const int fr = lane & 15;
    const int kb = lane >> 4;

    const int srow = tid >> 1;
    const int skoff = (tid & 1) * 16;
    const int skb = skoff >> 3;

    f32x4 acc[4][4];
    #pragma unroll
    for (int i = 0; i < 4; ++i)
        #pragma unroll
        for (int j = 0; j < 4; ++j) acc[i][j] = (f32x4)(0.f);

    for (int k0 = 0; k0 < K; k0 += 32) {
        {
            const _Float16* ap = AH + (size_t)(m0 + srow) * K + k0 + skoff;
            *(f16x8*)&AsH[skb  ][srow][0] = *(const f16x8*)ap;
            *(f16x8*)&AsH[skb+1][srow][0] = *(const f16x8*)(ap + 8);
            if constexpr (ASRC == 0) {
                const _Float16* alp = AL + (size_t)(m0 + srow) * K + k0 + skoff;
                *(f16x8*)&AsL[skb  ][srow][0] = *(const f16x8*)alp;
                *(f16x8*)&AsL[skb+1][srow][0] = *(const f16x8*)(alp + 8);
            }
        }
        {
            const _Float16* wp = WH + (size_t)(n0 + srow) * K + k0 + skoff;
            *(f16x8*)&WsH[skb  ][srow][0] = *(const f16x8*)wp;
            *(f16x8*)&WsH[skb+1][srow][0] = *(const f16x8*)(wp + 8);
            const _Float16* wlp = WL + (size_t)(n0 + srow) * K + k0 + skoff;
            *(f16x8*)&WsL[skb  ][srow][0] = *(const f16x8*)wlp;
            *(f16x8*)&WsL[skb+1][srow][0] = *(const f16x8*)(wlp + 8);
        }
        __syncthreads();

        f16x8 aH[4], aL[4], bH[4], bL[4];
        #pragma unroll
        for (int i = 0; i < 4; ++i) {
            aH[i] = *(const f16x8*)&AsH[kb][mw + i*16 + fr][0];
            if constexpr (ASRC == 0) aL[i] = *(const f16x8*)&AsL[kb][mw + i*16 + fr][0];
            bH[i] = *(const f16x8*)&WsH[kb][nw + i*16 + fr][0];
            bL[i] = *(const f16x8*)&WsL[kb][nw + i*16 + fr][0];
        }
        #pragma unroll
        for (int i = 0; i < 4; ++i)
            #pragma unroll
            for (int j = 0; j < 4; ++j) {
                acc[i][j] = __builtin_amdgcn_mfma_f32_16x16x32_f16(aH[i], bH[j], acc[i][j], 0, 0, 0);
                acc[i][j] = __builtin_amdgcn_mfma_f32_16x16x32_f16(aH[i], bL[j], acc[i][j], 0, 0, 0);
                if constexpr (ASRC == 0)
                    acc[i][j] = __builtin_amdgcn_mfma_f32_16x16x32_f16(aL[i], bH[j], acc[i][j], 0, 0, 0);
            }
        __syncthreads();
    }

    const int q = lane >> 4;
    #pragma unroll
    for (int j = 0; j < 4; ++j) {
        int n = n0 + nw + j*16 + fr;
        float bv = bias[n];
        #pragma unroll
        for (int i = 0; i < 4; ++i) {
            #pragma unroll
            for (int r = 0; r < 4; ++r) {
                int m = m0 + mw + i*16 + q*4 + r;
                float val = acc[i][j][r] * (1.f/1024.f) + bv;
                if constexpr (EPI == 2) val = val > 0.5f ? 1.f : 0.f;
                if constexpr (EPI == 3) {
                    ((_Float16*)O0)[(size_t)m * N + n] = (val > 0.5f) ? (_Float16)16.f : (_Float16)0.f;
                } else if constexpr (LAYOUT == 0) {
                    O0[(size_t)m * N + n] = val;
                } else {
                    int b_ = m >> 11, t_ = m & (T_SEQ-1);
                    if (n < 512) {
                        size_t hl = (((size_t)(b_*NHEAD + (n>>6))*T_SEQ + t_) << 6) + (n & 63);
                        float s16 = 16.f * val;
                        _Float16 hh = (_Float16)s16;
                        ((_Float16*)O0)[hl] = hh;
                        ((_Float16*)O1)[hl] = (_Float16)(s16 - (float)hh);
                    } else if (n < 1024) {
                        int nn = n - 512;
                        size_t hl = (((size_t)(b_*NHEAD + (nn>>6))*T_SEQ + t_) << 6) + (nn & 63);
                        float s16 = 16.f * val;
                        _Float16 hh = (_Float16)s16;
                        ((_Float16*)O2)[hl] = hh;
                        ((_Float16*)O3)[hl] = (_Float16)(s16 - (float)hh);
                    } else {
                        int nn = n - 1024;
                        O4[(((size_t)(b_*NHEAD + (nn>>6))*T_SEQ + t_) << 6) + (nn & 63)] = val;
                    }
                }
            }
        }
    }
}

// ---------------------------------------------------------------------------
__global__ __launch_bounds__(256) void cvtw_k(
    const float* __restrict__ w, _Float16* __restrict__ H, _Float16* __restrict__ L,
    int n, float scale)
{
    int i = blockIdx.x * 256 + threadIdx.x;
    if (i < n) {
        float s = scale * w[i];
        _Float16 h = (_Float16)s;
        H[i] = h;
        L[i] = (_Float16)(s - (float)h);
    }
}

__global__ __launch_bounds__(256) void cat_k(
    const float* __restrict__ wq, const float* __restrict__ wk, const float* __restrict__ wv,
    const float* __restrict__ bq, const float* __restrict__ bk, const float* __restrict__ bv,
    _Float16* __restrict__ WH, _Float16* __restrict__ WL, float* __restrict__ bcat)
{
    int i = blockIdx.x * 256 + threadIdx.x;
    if (i < 786432) {
        int src = i >> 18, off = i & 262143;
        float w = (src == 0 ? wq : (src == 1 ? wk : wv))[off];
        float s = 64.f * w;
        _Float16 h = (_Float16)s;
        WH[i] = h;
        WL[i] = (_Float16)(s - (float)h);
    } else if (i < 786432 + 1536) {
        int j = i - 786432;
        int src = j >> 9, off = j & 511;
        bcat[j] = (src == 0 ? bq : (src == 1 ? bk : bv))[off];
    }
}

// ---------------------------------------------------------------------------
// Fused sparse attention v4 — MFMA QK^T (f16 hi/lo split, rel err 2^-22),
// u32-key branch-free top-32 select, VALU AV.
// q/k arrive as f16 hi/lo planes (x16) in head layout [B,H,T,64].
// Scores: raw product = 256*q*k -> score = acc/2048 (incl. 1/sqrt(64)).
// ---------------------------------------------------------------------------
__global__ __launch_bounds__(256) void attn_k(
    const _Float16* __restrict__ qH, const _Float16* __restrict__ qL,
    const _Float16* __restrict__ kH, const _Float16* __restrict__ kL,
    const float* __restrict__ v,
    _Float16* __restrict__ outH, _Float16* __restrict__ outL)
{
    // LDS (46080 B): ksH [128][72] @0 (aliased by ss[32][132] and wrow/irow),
    // ksL [128][72] @18432, qsH [32][72] @36864, qsL [32][72] @41472
    __shared__ unsigned char lds[46080];
    _Float16 (*ksH)[72] = (_Float16(*)[72])(lds);
    _Float16 (*ksL)[72] = (_Float16(*)[72])(lds + 18432);
    _Float16 (*qsH)[72] = (_Float16(*)[72])(lds + 36864);
    _Float16 (*qsL)[72] = (_Float16(*)[72])(lds + 41472);
    float    (*ss)[132] = (float(*)[132])(lds);
    float*   wrow       = (float*)(lds);
    int*     irow       = (int*)(lds + 4224);

    const int tid = threadIdx.x;
    const int bh  = blockIdx.y;
    const int t0  = blockIdx.x * 32;
    const _Float16* qHb = qH + ((size_t)bh * T_SEQ + t0) * DHEAD;
    const _Float16* qLb = qL + ((size_t)bh * T_SEQ + t0) * DHEAD;
    const _Float16* kHb = kH + (size_t)bh * T_SEQ * DHEAD;
    const _Float16* kLb = kL + (size_t)bh * T_SEQ * DHEAD;
    const float*    vb  = v  + (size_t)bh * T_SEQ * DHEAD;

    // stage q tile (32 rows x 64 halfs per plane)
    {
        int r = tid >> 3, c = tid & 7;
        *(f16x8*)&qsH[r][c*8] = *(const f16x8*)(qHb + r*DHEAD + c*8);
        *(f16x8*)&qsL[r][c*8] = *(const f16x8*)(qLb + r*DHEAD + c*8);
    }

    unsigned kreg[32];
    #pragma unroll
    for (int i = 0; i < 32; ++i) kreg[i] = 0u;

    const int wv = tid >> 6, lane = tid & 63;
    const int fr = lane & 15, q4 = lane >> 4;
    const int c0w = wv * 32;            // this wave's 32 columns of the tile
    const int srow = tid >> 3;          // select: row 0..31
    const int ssub = tid & 7;           // select: sub 0..7

    for (int jt = 0; jt < 16; ++jt) {
        const int j0 = jt * 128;
        // stage k tile [128 rows][64 halfs] both planes (coalesced 16B/lane)
        {
            int c = tid & 7, r0 = tid >> 3;
            #pragma unroll
            for (int it = 0; it < 4; ++it) {
                int r = r0 + 32*it;
                *(f16x8*)&ksH[r][c*8] = *(const f16x8*)(kHb + (size_t)(j0 + r)*DHEAD + c*8);
                *(f16x8*)&ksL[r][c*8] = *(const f16x8*)(kLb + (size_t)(j0 + r)*DHEAD + c*8);
            }
        }
        __syncthreads();                 // A: q + k tiles ready

        // QK^T: 2 m-frags x 2 n-frags x 2 k-steps x 3 split passes
        f32x4 acc[2][2];
        acc[0][0] = (f32x4)(0.f); acc[0][1] = (f32x4)(0.f);
        acc[1][0] = (f32x4)(0.f); acc[1][1] = (f32x4)(0.f);
        #pragma unroll
        for (int ks = 0; ks < 2; ++ks) {
            const int doff = ks*32 + q4*8;
            f16x8 aH0 = *(const f16x8*)&qsH[fr][doff];
            f16x8 aH1 = *(const f16x8*)&qsH[16 + fr][doff];
            f16x8 aL0 = *(const f16x8*)&qsL[fr][doff];
            f16x8 aL1 = *(const f16x8*)&qsL[16 + fr][doff];
            #pragma unroll
            for (int nj = 0; nj < 2; ++nj) {
                const int cc = c0w + nj*16 + fr;
                f16x8 bHf = *(const f16x8*)&ksH[cc][doff];
                f16x8 bLf = *(const f16x8*)&ksL[cc][doff];
                acc[0][nj] = __builtin_amdgcn_mfma_f32_16x16x32_f16(aH0, bHf, acc[0][nj], 0, 0, 0);
                acc[0][nj] = __builtin_amdgcn_mfma_f32_16x16x32_f16(aH0, bLf, acc[0][nj], 0, 0, 0);
                acc[0][nj] = __builtin_amdgcn_mfma_f32_16x16x32_f16(aL0, bHf, acc[0][nj], 0, 0, 0);
                acc[1][nj] = __builtin_amdgcn_mfma_f32_16x16x32_f16(aH1, bHf, acc[1][nj], 0, 0, 0);
                acc[1][nj] = __builtin_amdgcn_mfma_f32_16x16x32_f16(aH1, bLf, acc[1][nj], 0, 0, 0);
                acc[1][nj] = __builtin_amdgcn_mfma_f32_16x16x32_f16(aL1, bHf, acc[1][nj], 0, 0, 0);
            }
        }
        __syncthreads();                 // B: k reads done; ss may alias ksH

        // scores to LDS: C-layout row = mi*16 + q4*4 + r, col = c0w + nj*16 + fr
        #pragma unroll
        for (int mi = 0; mi < 2; ++mi)
            #pragma unroll
            for (int nj = 0; nj < 2; ++nj)
                #pragma unroll
                for (int r = 0; r < 4; ++r)
                    ss[mi*16 + q4*4 + r][c0w + nj*16 + fr] = acc[mi][nj][r] * (1.f/2048.f);
        __syncthreads();                 // C: scores visible

        // branch-free select: 16 candidates / thread, u32 packed keys
        float4 c4[4];
        {
            const float* ssr = &ss[srow][0] + ssub*4;
            #pragma unroll
            for (int g = 0; g < 4; ++g) c4[g] = *(const float4*)(ssr + g*32);
        }
        unsigned cand[16];
        #pragma unroll
        for (int g = 0; g < 4; ++g) {
            float vg[4] = {c4[g].x, c4[g].y, c4[g].z, c4[g].w};
            #pragma unroll
            for (int r = 0; r < 4; ++r) {
                unsigned u = __float_as_uint(vg[r]);
                u ^= (unsigned)((int)u >> 31) | 0x80000000u;
                int col = ssub*4 + g*32 + r;
                cand[g*4+r] = (u & 0xFFFFF800u) | (unsigned)(2047 - (j0 + col));
            }
        }
        #pragma unroll
        for (int k2 = 2; k2 <= 16; k2 <<= 1) {
            #pragma unroll
            for (int j2 = k2 >> 1; j2 > 0; j2 >>= 1) {
                #pragma unroll
                for (int i2 = 0; i2 < 16; ++i2) {
                    int l2 = i2 ^ j2;
                    if (l2 > i2) {
                        unsigned a = cand[i2], b = cand[l2];
                        bool sw = ((i2 & k2) == 0) ? (a < b) : (a > b);
                        cand[i2] = sw ? b : a;
                        cand[l2] = sw ? a : b;
                    }
                }
            }
        }
        #pragma unroll
        for (int j2 = 0; j2 < 16; ++j2) {
            unsigned b = cand[15 - j2];
            if (kreg[16 + j2] < b) kreg[16 + j2] = b;
        }
        #pragma unroll
        for (int st = 16; st >= 1; st >>= 1) {
            #pragma unroll
            for (int i2 = 0; i2 < 32; ++i2) {
                if ((i2 & st) == 0) {
                    unsigned lo = kreg[i2], hi = kreg[i2 | st];
                    kreg[i2]      = lo < hi ? hi : lo;
                    kreg[i2 | st] = lo < hi ? lo : hi;
                }
            }
        }
        __syncthreads();                 // D: select done before next staging
    }

    // merge 8 per-sub lists (lane^1,2,4)
    #pragma unroll
    for (int s = 1; s <= 4; s <<= 1) {
        #pragma unroll
        for (int i = 0; i < 16; ++i) {
            unsigned pa = (unsigned)__shfl_xor((int)kreg[31-i], s, 64);
            unsigned pb = (unsigned)__shfl_xor((int)kreg[i],    s, 64);
            if (pa > kreg[i])    kreg[i]    = pa;
            if (pb > kreg[31-i]) kreg[31-i] = pb;
        }
        #pragma unroll
        for (int st = 16; st >= 1; st >>= 1) {
            #pragma unroll
            for (int i2 = 0; i2 < 32; ++i2) {
                if ((i2 & st) == 0) {
                    unsigned lo = kreg[i2], hi = kreg[i2 | st];
                    kreg[i2]      = lo < hi ? hi : lo;
                    kreg[i2 | st] = lo < hi ? lo : hi;
                }
            }
        }
    }

    // softmax over kept 32
    if (ssub == 0) {
        float w[32];
        #pragma unroll
        for (int i = 0; i < 32; ++i) {
            unsigned um = kreg[i] & 0xFFFFF800u;
            unsigned ub = (um & 0x80000000u) ? (um ^ 0x80000000u) : ~um;
            w[i] = __uint_as_float(ub);
        }
        float m = w[0];
        float s = 0.f;
        #pragma unroll
        for (int i = 0; i < 32; ++i) { w[i] = expf(w[i] - m); s += w[i]; }
        float inv = 1.f / s;
        #pragma unroll
        for (int i = 0; i < 32; ++i) {
            wrow[srow*33 + i] = w[i] * inv;
            irow[srow*33 + i] = 2047 - (int)(kreg[i] & 0x7FFu);
        }
    }
    __syncthreads();

    // AV: wave per row-group, lane = head dim
    const int wid = tid >> 6, lane2 = tid & 63;
    const int b = bh >> 3, h = bh & 7;
    for (int rr = wid; rr < 32; rr += 4) {
        float accv = 0.f;
        #pragma unroll
        for (int i = 0; i < 32; ++i) {
            float wgt = wrow[rr*33 + i];
            int   idx = irow[rr*33 + i];
            accv = fmaf(wgt, vb[(size_t)idx * DHEAD + lane2], accv);
        }
        size_t oi = ((size_t)(b * T_SEQ + t0 + rr)) * DMODEL + h * DHEAD + lane2;
        float s16 = 16.f * accv;
        _Float16 hh = (_Float16)s16;
        outH[oi] = hh;
        outL[oi] = (_Float16)(s16 - (float)hh);
    }
}

// ---------------------------------------------------------------------------
// LayerNorm (+residual); also emits x16 f16 hi/lo planes of the output
// ---------------------------------------------------------------------------
__global__ __launch_bounds__(256) void ln_k(
    const float* __restrict__ x, const float* __restrict__ res,
    const float* __restrict__ g, const float* __restrict__ bb,
    float* __restrict__ out, _Float16* __restrict__ oH, _Float16* __restrict__ oL)
{
    __shared__ float red[8];
    const int row = blockIdx.x;
    const int tid = threadIdx.x;
    const float* xr = x + (size_t)row * DMODEL;
    float v0 = xr[tid], v1 = xr[tid + 256];
    if (res) {
        const float* rr = res + (size_t)row * DMODEL;
        v0 += rr[tid]; v1 += rr[tid + 256];
    }
    float s = v0 + v1;
    #pragma unroll
    for (int o = 1; o < 64; o <<= 1) s += __shfl_xor(s, o);
    const int wid = tid >> 6, lane = tid & 63;
    if (lane == 0) red[wid] = s;
    __syncthreads();
    float mean = (red[0] + red[1] + red[2] + red[3]) * (1.f / DMODEL);
    float d0 = v0 - mean, d1 = v1 - mean;
    float qs = d0*d0 + d1*d1;
    #pragma unroll
    for (int o = 1; o < 64; o <<= 1) qs += __shfl_xor(qs, o);
    if (lane == 0) red[4 + wid] = qs;
    __syncthreads();
    float var = (red[4] + red[5] + red[6] + red[7]) * (1.f / DMODEL);
    float rs = rsqrtf(var + 1e-5f);
    float o0 = d0 * rs * g[tid]       + bb[tid];
    float o1 = d1 * rs * g[tid + 256] + bb[tid + 256];
    size_t base = (size_t)row * DMODEL;
    out[base + tid]       = o0;
    out[base + tid + 256] = o1;
    float s0 = 16.f * o0, s1 = 16.f * o1;
    _Float16 h0 = (_Float16)s0, h1 = (_Float16)s1;
    oH[base + tid]       = h0;
    oH[base + tid + 256] = h1;
    oL[base + tid]       = (_Float16)(s0 - (float)h0);
    oL[base + tid + 256] = (_Float16)(s1 - (float)h1);
}

// ---------------------------------------------------------------------------
__global__ __launch_bounds__(256) void pool_k(
    const float* __restrict__ h, float* __restrict__ part)
{
    const int chunk = blockIdx.x & 15;
    const int idx = (blockIdx.x >> 4) * 256 + threadIdx.x;
    const int b = idx >> 9, d = idx & 511;
    const float* p = h + ((size_t)b * T_SEQ + chunk * 128) * DMODEL + d;
    float s = 0.f;
    for (int t = 0; t < 128; ++t) s += p[(size_t)t * DMODEL];
    part[chunk * 1024 + idx] = s;
}

__global__ __launch_bounds__(256) void poolsum_k(
    const float* __restrict__ part, float* __restrict__ pooled)
{
    int idx = blockIdx.x * 256 + threadIdx.x;
    float s = 0.f;
    #pragma unroll
    for (int c = 0; c < 16; ++c) s += part[c * 1024 + idx];
    pooled[idx] = s * (1.f / T_SEQ);
}

__global__ __launch_bounds__(256) void cls_k(
    const float* __restrict__ pooled, const float* __restrict__ w,
    const float* __restrict__ bias, float* __restrict__ out)
{
    const int wid = threadIdx.x >> 6, lane = threadIdx.x & 63;
    const int oi = blockIdx.x * 4 + wid;
    const int b = oi >> 8, o = oi & 255;
    const float* pr = pooled + b * DMODEL;
    const float* wr = w + (size_t)o * DMODEL;
    float s = 0.f;
    for (int d = lane; d < DMODEL; d += 64) s = fmaf(pr[d], wr[d], s);
    #pragma unroll
    for (int off = 1; off < 64; off <<= 1) s += __shfl_xor(s, off);
    if (lane == 0) out[oi] = s + bias[o];
}

// ---------------------------------------------------------------------------
extern "C" void kernel_launch(void* const* d_in, const int* in_sizes, int n_in,
                              void* d_out, int out_size, void* d_ws, size_t ws_size,
                              hipStream_t stream)
{
    const float* x     = (const float*)d_in[0];
    const float* emb_w = (const float*)d_in[1];
    const float* emb_b = (const float*)d_in[2];
    const float* pos   = (const float*)d_in[3];
    const float* wq    = (const float*)d_in[4];
    const float* bq    = (const float*)d_in[5];
    const float* wk    = (const float*)d_in[6];
    const float* bk    = (const float*)d_in[7];
    const float* wv    = (const float*)d_in[8];
    const float* bv    = (const float*)d_in[9];
    const float* wo    = (const float*)d_in[10];
    const float* bo    = (const float*)d_in[11];
    const float* ln1g  = (const float*)d_in[12];
    const float* ln1b  = (const float*)d_in[13];
    const float* fc1w  = (const float*)d_in[14];
    const float* fc1b  = (const float*)d_in[15];
    const float* fc2w  = (const float*)d_in[16];
    const float* fc2b  = (const float*)d_in[17];
    const float* ln2g  = (const float*)d_in[18];
    const float* ln2b  = (const float*)d_in[19];
    const float* fng   = (const float*)d_in[20];
    const float* fnb   = (const float*)d_in[21];
    const float* clsw  = (const float*)d_in[22];
    const float* clsb  = (const float*)d_in[23];

    float* ws = (float*)d_ws;
    const size_t SZ  = (size_t)MROWS * DMODEL;   // 2,097,152 floats
    const size_t HP  = SZ / 2;                   // one f16 plane, in floats
    float*     h     = ws;                       // fp32 residual
    float*     t1    = ws + 1*SZ;                // spike fp32 temp
    _Float16*  hH    = (_Float16*)(ws + 2*SZ);
    _Float16*  hL    = (_Float16*)(ws + 2*SZ + HP);
    _Float16*  aoH   = (_Float16*)(ws + 3*SZ);
    _Float16*  aoL   = (_Float16*)(ws + 3*SZ + HP);
    _Float16*  qbH   = (_Float16*)(ws + 4*SZ);   // q f16 planes, head layout
    _Float16*  qbL   = (_Float16*)(ws + 4*SZ + HP);
    _Float16*  kbH   = (_Float16*)(ws + 5*SZ);   // k f16 planes, head layout
    _Float16*  kbL   = (_Float16*)(ws + 5*SZ + HP);
    float*     vbuf  = ws + 6*SZ;                // v fp32 head layout
    _Float16*  WcatH = (_Float16*)(ws + 7*SZ);
    _Float16*  WcatL = (_Float16*)(ws + 7*SZ + 393216);
    _Float16*  WoH   = (_Float16*)(ws + 7*SZ + 786432);
    _Float16*  WoL   = (_Float16*)(ws + 7*SZ + 917504);
    _Float16*  W1H   = (_Float16*)(ws + 7*SZ + 1048576);
    _Float16*  W1L   = (_Float16*)(ws + 7*SZ + 1572864);
    _Float16*  W2H   = (_Float16*)(ws + 7*SZ + 2097152);
    _Float16*  W2L   = (_Float16*)(ws + 7*SZ + 2621440);
    float*     bcat  = ws + 7*SZ + 3145728;
    float*     pooled= ws + 7*SZ + 3145728 + 1536;
    float*     part  = ws + 7*SZ + 3145728 + 1536 + 1024;
    _Float16*  hid   = (_Float16*)(ws + 4*SZ);   // [M,FDIM] halfs, aliases q/k planes (dead)
    const size_t needed = (7*SZ + 3145728 + 1536 + 1024 + 16384) * sizeof(float);
    if (ws_size < needed) return;

    dim3 blk(256);

    gemm_k<64,1,0><<<dim3(DMODEL/64, MROWS/128), blk, 0, stream>>>(
        x, emb_w, emb_b, pos, h, MROWS, DMODEL, 128);
    cvtw_k<<<dim3((int)(SZ/256)), blk, 0, stream>>>(h, hH, hL, (int)SZ, 16.f);

    for (int l = 0; l < NLAYER; ++l) {
        const float* wq_l = wq + (size_t)l*DMODEL*DMODEL;
        const float* bq_l = bq + (size_t)l*DMODEL;
        const float* wk_l = wk + (size_t)l*DMODEL*DMODEL;
        const float* bk_l = bk + (size_t)l*DMODEL;
        const float* wv_l = wv + (size_t)l*DMODEL*DMODEL;
        const float* bv_l = bv + (size_t)l*DMODEL;
        const float* wo_l = wo + (size_t)l*DMODEL*DMODEL;
        const float* bo_l = bo + (size_t)l*DMODEL;
        const float* f1w_l = fc1w + (size_t)l*FDIM*DMODEL;
        const float* f1b_l = fc1b + (size_t)l*FDIM;
        const float* f2w_l = fc2w + (size_t)l*DMODEL*FDIM;
        const float* f2b_l = fc2b + (size_t)l*DMODEL;

        cat_k<<<dim3(3079), blk, 0, stream>>>(wq_l, wk_l, wv_l, bq_l, bk_l, bv_l,
                                              WcatH, WcatL, bcat);
        cvtw_k<<<dim3(1024), blk, 0, stream>>>(wo_l, WoH, WoL, 262144, 64.f);
        cvtw_k<<<dim3(4096), blk, 0, stream>>>(f1w_l, W1H, W1L, 1048576, 64.f);
        cvtw_k<<<dim3(4096), blk, 0, stream>>>(f2w_l, W2H, W2L, 1048576, 64.f);

        // fused QKV: q,k as f16 planes (head layout), v fp32 (head layout)
        mgemm_k<0,0,2><<<dim3(12, 32), blk, 0, stream>>>(
            hH, hL, WcatH, WcatL, bcat,
            (float*)qbH, (float*)qbL, (float*)kbH, (float*)kbL, vbuf,
            MROWS, 1536, DMODEL);

        attn_k<<<dim3(T_SEQ/32, NB*NHEAD), blk, 0, stream>>>(
            qbH, qbL, kbH, kbL, vbuf, aoH, aoL);

        mgemm_k<0,2,0><<<dim3(4, 32), blk, 0, stream>>>(
            aoH, aoL, WoH, WoL, bo_l, t1, nullptr, nullptr, nullptr, nullptr,
            MROWS, DMODEL, DMODEL);
        ln_k<<<dim3(MROWS), blk, 0, stream>>>(h, t1, ln1g + (size_t)l*DMODEL,
                                              ln1b + (size_t)l*DMODEL, h, hH, hL);

        mgemm_k<0,3,0><<<dim3(16, 32), blk, 0, stream>>>(
            hH, hL, W1H, W1L, f1b_l, (float*)hid, nullptr, nullptr, nullptr, nullptr,
            MROWS, FDIM, DMODEL);
        mgemm_k<1,2,0><<<dim3(4, 32), blk, 0, stream>>>(
            hid, nullptr, W2H, W2L, f2b_l, t1, nullptr, nullptr, nullptr, nullptr,
            MROWS, DMODEL, FDIM);
        ln_k<<<dim3(MROWS), blk, 0, stream>>>(h, t1, ln2g + (size_t)l*DMODEL,
                                              ln2b + (size_t)l*DMODEL, h, hH, hL);
    }

    ln_k<<<dim3(MROWS), blk, 0, stream>>>(h, nullptr, fng, fnb, h, hH, hL);
    pool_k<<<dim3(64), blk, 0, stream>>>(h, part);
    poolsum_k<<<dim3(4), blk, 0, stream>>>(part, pooled);
    cls_k<<<dim3(128), blk, 0, stream>>>(pooled, clsw, clsb, (float*)d_out);
}

// Round 8
// 1231.158 us; speedup vs baseline: 12.0676x; 1.0544x over previous
//
#include <hip/hip_runtime.h>
#include <math.h>
#include <float.h>

#define T_SEQ  2048
#define DMODEL 512
#define NHEAD  8
#define DHEAD  64
#define FDIM   2048
#define NLAYER 4
#define NB     2
#define MROWS  (NB*T_SEQ)   // 4096

typedef _Float16 f16x8 __attribute__((ext_vector_type(8)));
typedef float    f32x4 __attribute__((ext_vector_type(4)));

// async 16B global -> LDS (wave-uniform LDS base, lane x 16B dest)
__device__ __forceinline__ void async16(const _Float16* g, _Float16* l) {
    __builtin_amdgcn_global_load_lds(
        (const __attribute__((address_space(1))) unsigned int*)g,
        (__attribute__((address_space(3))) unsigned int*)l, 16, 0, 0);
}

// ---------------------------------------------------------------------------
// fp32 vector GEMM — embedding only (K=128)
// ---------------------------------------------------------------------------
template<int BN, int EPI>
__global__ __launch_bounds__(256) void gemm_k(
    const float* __restrict__ A, const float* __restrict__ W,
    const float* __restrict__ bias, const float* __restrict__ pos,
    float* __restrict__ C, int M, int N, int K)
{
    constexpr int BM = 128;
    constexpr int BK = 32;
    constexpr int MN = BN / 16;
    __shared__ float As[BK][BM + 4];
    __shared__ float Ws[BK][BN + 4];
    const int tid = threadIdx.x;
    const int n0 = blockIdx.x * BN;
    const int m0 = blockIdx.y * BM;
    const int tx = tid & 15;
    const int ty = tid >> 4;

    float acc[8][MN];
    #pragma unroll
    for (int i = 0; i < 8; ++i)
        #pragma unroll
        for (int j = 0; j < MN; ++j) acc[i][j] = 0.f;

    for (int k0 = 0; k0 < K; k0 += BK) {
        #pragma unroll
        for (int it = 0; it < 4; ++it) {
            int qq = tid + 256 * it;
            int m = qq >> 3, kq = qq & 7;
            float4 v4 = *(const float4*)(A + (size_t)(m0 + m) * K + k0 + kq * 4);
            As[kq*4+0][m] = v4.x; As[kq*4+1][m] = v4.y;
            As[kq*4+2][m] = v4.z; As[kq*4+3][m] = v4.w;
        }
        #pragma unroll
        for (int it = 0; it < BN/32; ++it) {
            int qq = tid + 256 * it;
            int n = qq >> 3, kq = qq & 7;
            float4 v4 = *(const float4*)(W + (size_t)(n0 + n) * K + k0 + kq * 4);
            Ws[kq*4+0][n] = v4.x; Ws[kq*4+1][n] = v4.y;
            Ws[kq*4+2][n] = v4.z; Ws[kq*4+3][n] = v4.w;
        }
        __syncthreads();
        for (int kk = 0; kk < BK; ++kk) {
            float a[8], b[MN];
            float4 a0 = *(const float4*)&As[kk][ty*8];
            float4 a1 = *(const float4*)&As[kk][ty*8+4];
            a[0]=a0.x; a[1]=a0.y; a[2]=a0.z; a[3]=a0.w;
            a[4]=a1.x; a[5]=a1.y; a[6]=a1.z; a[7]=a1.w;
            float4 b0 = *(const float4*)&Ws[kk][tx*4];
            b[0]=b0.x; b[1]=b0.y; b[2]=b0.z; b[3]=b0.w;
            if constexpr (MN == 8) {
                float4 b1 = *(const float4*)&Ws[kk][64 + tx*4];
                b[4]=b1.x; b[5]=b1.y; b[6]=b1.z; b[7]=b1.w;
            }
            #pragma unroll
            for (int i = 0; i < 8; ++i)
                #pragma unroll
                for (int j = 0; j < MN; ++j)
                    acc[i][j] = fmaf(a[i], b[j], acc[i][j]);
        }
        __syncthreads();
    }

    #pragma unroll
    for (int i = 0; i < 8; ++i) {
        int m = m0 + ty*8 + i;
        #pragma unroll
        for (int jb = 0; jb < MN/4; ++jb) {
            int nn = n0 + jb*64 + tx*4;
            float4 r;
            r.x = acc[i][jb*4+0] + bias[nn+0];
            r.y = acc[i][jb*4+1] + bias[nn+1];
            r.z = acc[i][jb*4+2] + bias[nn+2];
            r.w = acc[i][jb*4+3] + bias[nn+3];
            if constexpr (EPI == 1) {
                const float* pp = pos + (size_t)(m & (T_SEQ-1)) * DMODEL + nn;
                r.x += pp[0]; r.y += pp[1]; r.z += pp[2]; r.w += pp[3];
            }
            *(float4*)(C + (size_t)m * N + nn) = r;
        }
    }
}

// ---------------------------------------------------------------------------
// f16-split MFMA GEMM: C = (1/1024)·A'[M,K]·W'[N,K]^T + bias
// BM: 128 (4 m-frags/wave) or 64 (2 m-frags/wave; use when grid would be <1/CU)
// ASRC: 0 = dual-plane A; 1 = single-plane A (exact spikes)
// EPI:  0 = fp32; 2 = spike->fp32; 3 = spike->f16 plane (x16)
// LAYOUT: 0 = [M,N]; 2 = fused QKV (q,k f16 planes head layout; v fp32)
// ---------------------------------------------------------------------------
template<int BM, int ASRC, int EPI, int LAYOUT>
__global__ __launch_bounds__(256, 2) void mgemm_k(
    const _Float16* __restrict__ AH, const _Float16* __restrict__ AL,
    const _Float16* __restrict__ WH, const _Float16* __restrict__ WL,
    const float* __restrict__ bias,
    float* __restrict__ O0, float* __restrict__ O1, float* __restrict__ O2,
    float* __restrict__ O3, float* __restrict__ O4,
    int M, int N, int K)
{
    constexpr int MI = BM / 32;
    __shared__ _Float16 AsH[4][BM][8];
    __shared__ _Float16 AsL[4][BM][8];
    __shared__ _Float16 WsH[4][128][8];
    __shared__ _Float16 WsL[4][128][8];

    const int tid = threadIdx.x;
    const int n0 = blockIdx.x * 128;
    const int m0 = blockIdx.y * BM;
    const int wv = tid >> 6, lane = tid & 63;
    const int mw = (wv >> 1) * (BM/2), nw = (wv & 1) * 64;
    const int fr = lane & 15;
    const int kb = lane >> 4;

    const int wsrow = tid >> 1;
    const int wskb  = (tid & 1) * 2;
    const int wkoff = (tid & 1) * 16;

    f32x4 acc[MI][4];
    #pragma unroll
    for (int i = 0; i < MI; ++i)
        #pragma unroll
        for (int j = 0; j < 4; ++j) acc[i][j] = (f32x4)(0.f);

    for (int k0 = 0; k0 < K; k0 += 32) {
        if constexpr (BM == 128) {
            const _Float16* ap = AH + (size_t)(m0 + wsrow) * K + k0 + wkoff;
            *(f16x8*)&AsH[wskb  ][wsrow][0] = *(const f16x8*)ap;
            *(f16x8*)&AsH[wskb+1][wsrow][0] = *(const f16x8*)(ap + 8);
            if constexpr (ASRC == 0) {
                const _Float16* alp = AL + (size_t)(m0 + wsrow) * K + k0 + wkoff;
                *(f16x8*)&AsL[wskb  ][wsrow][0] = *(const f16x8*)alp;
                *(f16x8*)&AsL[wskb+1][wsrow][0] = *(const f16x8*)(alp + 8);
            }
        } else {
            const int arow = tid >> 2, akb = tid & 3;
            *(f16x8*)&AsH[akb][arow][0] =
                *(const f16x8*)(AH + (size_t)(m0 + arow) * K + k0 + akb*8);
            if constexpr (ASRC == 0)
                *(f16x8*)&AsL[akb][arow][0] =
                    *(const f16x8*)(AL + (size_t)(m0 + arow) * K + k0 + akb*8);
        }
        {
            const _Float16* wp = WH + (size_t)(n0 + wsrow) * K + k0 + wkoff;
            *(f16x8*)&WsH[wskb  ][wsrow][0] = *(const f16x8*)wp;
            *(f16x8*)&WsH[wskb+1][wsrow][0] = *(const f16x8*)(wp + 8);
            const _Float16* wlp = WL + (size_t)(n0 + wsrow) * K + k0 + wkoff;
            *(f16x8*)&WsL[wskb  ][wsrow][0] = *(const f16x8*)wlp;
            *(f16x8*)&WsL[wskb+1][wsrow][0] = *(const f16x8*)(wlp + 8);
        }
        __syncthreads();

        f16x8 aH[MI], aL[MI], bH[4], bL[4];
        #pragma unroll
        for (int i = 0; i < MI; ++i) {
            aH[i] = *(const f16x8*)&AsH[kb][mw + i*16 + fr][0];
            if constexpr (ASRC == 0) aL[i] = *(const f16x8*)&AsL[kb][mw + i*16 + fr][0];
        }
        #pragma unroll
        for (int j = 0; j < 4; ++j) {
            bH[j] = *(const f16x8*)&WsH[kb][nw + j*16 + fr][0];
            bL[j] = *(const f16x8*)&WsL[kb][nw + j*16 + fr][0];
        }
        #pragma unroll
        for (int i = 0; i < MI; ++i)
            #pragma unroll
            for (int j = 0; j < 4; ++j) {
                acc[i][j] = __builtin_amdgcn_mfma_f32_16x16x32_f16(aH[i], bH[j], acc[i][j], 0, 0, 0);
                acc[i][j] = __builtin_amdgcn_mfma_f32_16x16x32_f16(aH[i], bL[j], acc[i][j], 0, 0, 0);
                if constexpr (ASRC == 0)
                    acc[i][j] = __builtin_amdgcn_mfma_f32_16x16x32_f16(aL[i], bH[j], acc[i][j], 0, 0, 0);
            }
        __syncthreads();
    }

    const int qq = lane >> 4;
    #pragma unroll
    for (int j = 0; j < 4; ++j) {
        int n = n0 + nw + j*16 + fr;
        float bv = bias[n];
        #pragma unroll
        for (int i = 0; i < MI; ++i) {
            #pragma unroll
            for (int r = 0; r < 4; ++r) {
                int m = m0 + mw + i*16 + qq*4 + r;
                float val = acc[i][j][r] * (1.f/1024.f) + bv;
                if constexpr (EPI == 2) val = val > 0.5f ? 1.f : 0.f;
                if constexpr (EPI == 3) {
                    ((_Float16*)O0)[(size_t)m * N + n] = (val > 0.5f) ? (_Float16)16.f : (_Float16)0.f;
                } else if constexpr (LAYOUT == 0) {
                    O0[(size_t)m * N + n] = val;
                } else {
                    int b_ = m >> 11, t_ = m & (T_SEQ-1);
                    if (n < 512) {
                        size_t hl = (((size_t)(b_*NHEAD + (n>>6))*T_SEQ + t_) << 6) + (n & 63);
                        float s16 = 16.f * val;
                        _Float16 hh = (_Float16)s16;
                        ((_Float16*)O0)[hl] = hh;
                        ((_Float16*)O1)[hl] = (_Float16)(s16 - (float)hh);
                    } else if (n < 1024) {
                        int nn = n - 512;
                        size_t hl = (((size_t)(b_*NHEAD + (nn>>6))*T_SEQ + t_) << 6) + (nn & 63);
                        float s16 = 16.f * val;
                        _Float16 hh = (_Float16)s16;
                        ((_Float16*)O2)[hl] = hh;
                        ((_Float16*)O3)[hl] = (_Float16)(s16 - (float)hh);
                    } else {
                        int nn = n - 1024;
                        O4[(((size_t)(b_*NHEAD + (nn>>6))*T_SEQ + t_) << 6) + (nn & 63)] = val;
                    }
                }
            }
        }
    }
}

// ---------------------------------------------------------------------------
// h-split (embedding output -> x16 planes)
// ---------------------------------------------------------------------------
__global__ __launch_bounds__(256) void cvtw_k(
    const float* __restrict__ w, _Float16* __restrict__ H, _Float16* __restrict__ L,
    int n, float scale)
{
    int i = blockIdx.x * 256 + threadIdx.x;
    if (i < n) {
        float s = scale * w[i];
        _Float16 h = (_Float16)s;
        H[i] = h;
        L[i] = (_Float16)(s - (float)h);
    }
}

// all of one layer's weight conversions fused (x64 split), one launch
__global__ __launch_bounds__(256) void cvtlayer_k(
    const float* __restrict__ wq, const float* __restrict__ wk, const float* __restrict__ wv,
    const float* __restrict__ bq, const float* __restrict__ bk, const float* __restrict__ bv,
    const float* __restrict__ wo, const float* __restrict__ f1w, const float* __restrict__ f2w,
    _Float16* __restrict__ WcatH, _Float16* __restrict__ WcatL, float* __restrict__ bcat,
    _Float16* __restrict__ WoH, _Float16* __restrict__ WoL,
    _Float16* __restrict__ W1H, _Float16* __restrict__ W1L,
    _Float16* __restrict__ W2H, _Float16* __restrict__ W2L)
{
    int i = blockIdx.x * 256 + threadIdx.x;
    float w;
    _Float16 *H, *L;
    int off;
    if (i < 786432) {
        int src = i >> 18, o = i & 262143;
        w = (src == 0 ? wq : (src == 1 ? wk : wv))[o];
        H = WcatH; L = WcatL; off = i;
    } else if (i < 1048576) {
        off = i - 786432;  w = wo[off];  H = WoH; L = WoL;
    } else if (i < 2097152) {
        off = i - 1048576; w = f1w[off]; H = W1H; L = W1L;
    } else if (i < 3145728) {
        off = i - 2097152; w = f2w[off]; H = W2H; L = W2L;
    } else if (i < 3145728 + 1536) {
        int j = i - 3145728;
        int src = j >> 9, o = j & 511;
        bcat[j] = (src == 0 ? bq : (src == 1 ? bk : bv))[o];
        return;
    } else return;
    float s = 64.f * w;
    _Float16 h = (_Float16)s;
    H[off] = h;
    L[off] = (_Float16)(s - (float)h);
}

// ---------------------------------------------------------------------------
// Fused sparse attention v5 — async global_load_lds K staging (swizzled,
// unpadded [128][64] per plane), separate ss region -> 2 barriers/tile,
// MFMA QK^T (f16 hi/lo), u32-key branch-free top-32 select, VALU AV.
// LDS swizzle: row cc's 16B chunk ch lives at slot (ch ^ (cc&7)) -> fragment
// ds_read_b128 2-way conflicts (free); global side provides the permutation.
// ---------------------------------------------------------------------------
__global__ __launch_bounds__(256) void attn_k(
    const _Float16* __restrict__ qH, const _Float16* __restrict__ qL,
    const _Float16* __restrict__ kH, const _Float16* __restrict__ kL,
    const float* __restrict__ v,
    _Float16* __restrict__ outH, _Float16* __restrict__ outL)
{
    // ksH [128*64] @0 (16384) | ksL @16384 | qsH[32][72] @32768 | qsL @37376
    // ss[32][132] f32 @41984 (16896) -> total 58880; wrow/irow alias ss
    __shared__ unsigned char lds[58880];
    _Float16* ksH = (_Float16*)(lds);
    _Float16* ksL = (_Float16*)(lds + 16384);
    _Float16 (*qsH)[72] = (_Float16(*)[72])(lds + 32768);
    _Float16 (*qsL)[72] = (_Float16(*)[72])(lds + 37376);
    float    (*ss)[132] = (float(*)[132])(lds + 41984);
    float*   wrow       = (float*)(lds + 41984);
    int*     irow       = (int*)(lds + 41984 + 4224);

    const int tid = threadIdx.x;
    const int bh  = blockIdx.y;
    const int t0  = blockIdx.x * 32;
    const _Float16* qHb = qH + ((size_t)bh * T_SEQ + t0) * DHEAD;
    const _Float16* qLb = qL + ((size_t)bh * T_SEQ + t0) * DHEAD;
    const _Float16* kHb = kH + (size_t)bh * T_SEQ * DHEAD;
    const _Float16* kLb = kL + (size_t)bh * T_SEQ * DHEAD;
    const float*    vb  = v  + (size_t)bh * T_SEQ * DHEAD;

    // stage q tile (padded [32][72] halfs per plane)
    {
        int r = tid >> 3, c = tid & 7;
        *(f16x8*)&qsH[r][c*8] = *(const f16x8*)(qHb + r*DHEAD + c*8);
        *(f16x8*)&qsL[r][c*8] = *(const f16x8*)(qLb + r*DHEAD + c*8);
    }

    unsigned kreg[32];
    #pragma unroll
    for (int i = 0; i < 32; ++i) kreg[i] = 0u;

    const int wv = tid >> 6, lane = tid & 63;
    const int fr = lane & 15, q4 = lane >> 4;
    const int c0w = wv * 32;
    const int srow = tid >> 3;
    const int ssub = tid & 7;

    // async stage of one K tile: per wave 4 instrs/plane, 8 rows/instr
    auto stage = [&](int jt) {
        const int j0 = jt * 128;
        #pragma unroll
        for (int i = 0; i < 4; ++i) {
            const int r0 = wv*32 + i*8;                 // wave-uniform
            const int cc = r0 + (lane >> 3);
            const int ch = (lane & 7) ^ (cc & 7);       // swizzled source chunk
            const size_t goff = (size_t)(j0 + cc) * DHEAD + ch*8;
            async16(kHb + goff, ksH + r0*64);
            async16(kLb + goff, ksL + r0*64);
        }
    };

    stage(0);
    __syncthreads();                     // q + ks(0) ready (drains vmcnt)

    for (int jt = 0; jt < 16; ++jt) {
        const int j0 = jt * 128;

        // QK^T: 2 m-frags x 2 n-frags x 2 k-steps x 3 split passes
        f32x4 acc[2][2];
        acc[0][0] = (f32x4)(0.f); acc[0][1] = (f32x4)(0.f);
        acc[1][0] = (f32x4)(0.f); acc[1][1] = (f32x4)(0.f);
        #pragma unroll
        for (int ks = 0; ks < 2; ++ks) {
            const int doff = ks*32 + q4*8;
            const int chq  = ks*4 + q4;                 // chunk index of doff
            f16x8 aH0 = *(const f16x8*)&qsH[fr][doff];
            f16x8 aH1 = *(const f16x8*)&qsH[16 + fr][doff];
            f16x8 aL0 = *(const f16x8*)&qsL[fr][doff];
            f16x8 aL1 = *(const f16x8*)&qsL[16 + fr][doff];
            #pragma unroll
            for (int nj = 0; nj < 2; ++nj) {
                const int cc = c0w + nj*16 + fr;
                const int sl = cc*64 + (chq ^ (cc & 7))*8;
                f16x8 bHf = *(const f16x8*)&ksH[sl];
                f16x8 bLf = *(const f16x8*)&ksL[sl];
                acc[0][nj] = __builtin_amdgcn_mfma_f32_16x16x32_f16(aH0, bHf, acc[0][nj], 0, 0, 0);
                acc[0][nj] = __builtin_amdgcn_mfma_f32_16x16x32_f16(aH0, bLf, acc[0][nj], 0, 0, 0);
                acc[0][nj] = __builtin_amdgcn_mfma_f32_16x16x32_f16(aL0, bHf, acc[0][nj], 0, 0, 0);
                acc[1][nj] = __builtin_amdgcn_mfma_f32_16x16x32_f16(aH1, bHf, acc[1][nj], 0, 0, 0);
                acc[1][nj] = __builtin_amdgcn_mfma_f32_16x16x32_f16(aH1, bLf, acc[1][nj], 0, 0, 0);
                acc[1][nj] = __builtin_amdgcn_mfma_f32_16x16x32_f16(aL1, bHf, acc[1][nj], 0, 0, 0);
            }
        }
        // scores to LDS (C-layout: row = mi*16 + q4*4 + r, col = c0w + nj*16 + fr)
        #pragma unroll
        for (int mi = 0; mi < 2; ++mi)
            #pragma unroll
            for (int nj = 0; nj < 2; ++nj)
                #pragma unroll
                for (int r = 0; r < 4; ++r)
                    ss[mi*16 + q4*4 + r][c0w + nj*16 + fr] = acc[mi][nj][r] * (1.f/2048.f);
        __syncthreads();                 // C: ss visible; all ks reads done

        if (jt < 15) stage(jt + 1);      // async; hides under select

        // branch-free select: 16 candidates / thread, u32 packed keys
        float4 c4[4];
        {
            const float* ssr = &ss[srow][0] + ssub*4;
            #pragma unroll
            for (int g = 0; g < 4; ++g) c4[g] = *(const float4*)(ssr + g*32);
        }
        unsigned cand[16];
        #pragma unroll
        for (int g = 0; g < 4; ++g) {
            float vg[4] = {c4[g].x, c4[g].y, c4[g].z, c4[g].w};
            #pragma unroll
            for (int r = 0; r < 4; ++r) {
                unsigned u = __float_as_uint(vg[r]);
                u ^= (unsigned)((int)u >> 31) | 0x80000000u;
                int col = ssub*4 + g*32 + r;
                cand[g*4+r] = (u & 0xFFFFF800u) | (unsigned)(2047 - (j0 + col));
            }
        }
        #pragma unroll
        for (int k2 = 2; k2 <= 16; k2 <<= 1) {
            #pragma unroll
            for (int j2 = k2 >> 1; j2 > 0; j2 >>= 1) {
                #pragma unroll
                for (int i2 = 0; i2 < 16; ++i2) {
                    int l2 = i2 ^ j2;
                    if (l2 > i2) {
                        unsigned a = cand[i2], b = cand[l2];
                        bool sw = ((i2 & k2) == 0) ? (a < b) : (a > b);
                        cand[i2] = sw ? b : a;
                        cand[l2] = sw ? a : b;
                    }
                }
            }
        }
        #pragma unroll
        for (int j2 = 0; j2 < 16; ++j2) {
            unsigned b = cand[15 - j2];
            if (kreg[16 + j2] < b) kreg[16 + j2] = b;
        }
        #pragma unroll
        for (int st = 16; st >= 1; st >>= 1) {
            #pragma unroll
            for (int i2 = 0; i2 < 32; ++i2) {
                if ((i2 & st) == 0) {
                    unsigned lo = kreg[i2], hi = kreg[i2 | st];
                    kreg[i2]      = lo < hi ? hi : lo;
                    kreg[i2 | st] = lo < hi ? lo : hi;
                }
            }
        }
        __syncthreads();                 // A: ks(t+1) ready; ss reads done
    }

    // merge 8 per-sub lists (lane^1,2,4)
    #pragma unroll
    for (int s = 1; s <= 4; s <<= 1) {
        #pragma unroll
        for (int i = 0; i < 16; ++i) {
            unsigned pa = (unsigned)__shfl_xor((int)kreg[31-i], s, 64);
            unsigned pb = (unsigned)__shfl_xor((int)kreg[i],    s, 64);
            if (pa > kreg[i])    kreg[i]    = pa;
            if (pb > kreg[31-i]) kreg[31-i] = pb;
        }
        #pragma unroll
        for (int st = 16; st >= 1; st >>= 1) {
            #pragma unroll
            for (int i2 = 0; i2 < 32; ++i2) {
                if ((i2 & st) == 0) {
                    unsigned lo = kreg[i2], hi = kreg[i2 | st];
                    kreg[i2]      = lo < hi ? hi : lo;
                    kreg[i2 | st] = lo < hi ? lo : hi;
                }
            }
        }
    }

    // softmax over kept 32
    if (ssub == 0) {
        float w[32];
        #pragma unroll
        for (int i = 0; i < 32; ++i) {
            unsigned um = kreg[i] & 0xFFFFF800u;
            unsigned ub = (um & 0x80000000u) ? (um ^ 0x80000000u) : ~um;
            w[i] = __uint_as_float(ub);
        }
        float m = w[0];
        float s = 0.f;
        #pragma unroll
        for (int i = 0; i < 32; ++i) { w[i] = expf(w[i] - m); s += w[i]; }
        float inv = 1.f / s;
        #pragma unroll
        for (int i = 0; i < 32; ++i) {
            wrow[srow*33 + i] = w[i] * inv;
            irow[srow*33 + i] = 2047 - (int)(kreg[i] & 0x7FFu);
        }
    }
    __syncthreads();

    // AV: wave per row-group, lane = head dim
    const int wid = tid >> 6, lane2 = tid & 63;
    const int b = bh >> 3, h = bh & 7;
    for (int rr = wid; rr < 32; rr += 4) {
        float accv = 0.f;
        #pragma unroll
        for (int i = 0; i < 32; ++i) {
            float wgt = wrow[rr*33 + i];
            int   idx = irow[rr*33 + i];
            accv = fmaf(wgt, vb[(size_t)idx * DHEAD + lane2], accv);
        }
        size_t oi = ((size_t)(b * T_SEQ + t0 + rr)) * DMODEL + h * DHEAD + lane2;
        float s16 = 16.f * accv;
        _Float16 hh = (_Float16)s16;
        outH[oi] = hh;
        outL[oi] = (_Float16)(s16 - (float)hh);
    }
}

// ---------------------------------------------------------------------------
// LayerNorm (+residual); also emits x16 f16 hi/lo planes of the output
// ---------------------------------------------------------------------------
__global__ __launch_bounds__(256) void ln_k(
    const float* __restrict__ x, const float* __restrict__ res,
    const float* __restrict__ g, const float* __restrict__ bb,
    float* __restrict__ out, _Float16* __restrict__ oH, _Float16* __restrict__ oL)
{
    __shared__ float red[8];
    const int row = blockIdx.x;
    const int tid = threadIdx.x;
    const float* xr = x + (size_t)row * DMODEL;
    float v0 = xr[tid], v1 = xr[tid + 256];
    if (res) {
        const float* rr = res + (size_t)row * DMODEL;
        v0 += rr[tid]; v1 += rr[tid + 256];
    }
    float s = v0 + v1;
    #pragma unroll
    for (int o = 1; o < 64; o <<= 1) s += __shfl_xor(s, o);
    const int wid = tid >> 6, lane = tid & 63;
    if (lane == 0) red[wid] = s;
    __syncthreads();
    float mean = (red[0] + red[1] + red[2] + red[3]) * (1.f / DMODEL);
    float d0 = v0 - mean, d1 = v1 - mean;
    float qs = d0*d0 + d1*d1;
    #pragma unroll
    for (int o = 1; o < 64; o <<= 1) qs += __shfl_xor(qs, o);
    if (lane == 0) red[4 + wid] = qs;
    __syncthreads();
    float var = (red[4] + red[5] + red[6] + red[7]) * (1.f / DMODEL);
    float rs = rsqrtf(var + 1e-5f);
    float o0 = d0 * rs * g[tid]       + bb[tid];
    float o1 = d1 * rs * g[tid + 256] + bb[tid + 256];
    size_t base = (size_t)row * DMODEL;
    out[base + tid]       = o0;
    out[base + tid + 256] = o1;
    float s0 = 16.f * o0, s1 = 16.f * o1;
    _Float16 h0 = (_Float16)s0, h1 = (_Float16)s1;
    oH[base + tid]       = h0;
    oH[base + tid + 256] = h1;
    oL[base + tid]       = (_Float16)(s0 - (float)h0);
    oL[base + tid + 256] = (_Float16)(s1 - (float)h1);
}

// ---------------------------------------------------------------------------
__global__ __launch_bounds__(256) void pool_k(
    const float* __restrict__ h, float* __restrict__ part)
{
    const int chunk = blockIdx.x & 15;
    const int idx = (blockIdx.x >> 4) * 256 + threadIdx.x;
    const int b = idx >> 9, d = idx & 511;
    const float* p = h + ((size_t)b * T_SEQ + chunk * 128) * DMODEL + d;
    float s = 0.f;
    for (int t = 0; t < 128; ++t) s += p[(size_t)t * DMODEL];
    part[chunk * 1024 + idx] = s;
}

__global__ __launch_bounds__(256) void poolsum_k(
    const float* __restrict__ part, float* __restrict__ pooled)
{
    int idx = blockIdx.x * 256 + threadIdx.x;
    float s = 0.f;
    #pragma unroll
    for (int c = 0; c < 16; ++c) s += part[c * 1024 + idx];
    pooled[idx] = s * (1.f / T_SEQ);
}

__global__ __launch_bounds__(256) void cls_k(
    const float* __restrict__ pooled, const float* __restrict__ w,
    const float* __restrict__ bias, float* __restrict__ out)
{
    const int wid = threadIdx.x >> 6, lane = threadIdx.x & 63;
    const int oi = blockIdx.x * 4 + wid;
    const int b = oi >> 8, o = oi & 255;
    const float* pr = pooled + b * DMODEL;
    const float* wr = w + (size_t)o * DMODEL;
    float s = 0.f;
    for (int d = lane; d < DMODEL; d += 64) s = fmaf(pr[d], wr[d], s);
    #pragma unroll
    for (int off = 1; off < 64; off <<= 1) s += __shfl_xor(s, off);
    if (lane == 0) out[oi] = s + bias[o];
}

// ---------------------------------------------------------------------------
extern "C" void kernel_launch(void* const* d_in, const int* in_sizes, int n_in,
                              void* d_out, int out_size, void* d_ws, size_t ws_size,
                              hipStream_t stream)
{
    const float* x     = (const float*)d_in[0];
    const float* emb_w = (const float*)d_in[1];
    const float* emb_b = (const float*)d_in[2];
    const float* pos   = (const float*)d_in[3];
    const float* wq    = (const float*)d_in[4];
    const float* bq    = (const float*)d_in[5];
    const float* wk    = (const float*)d_in[6];
    const float* bk    = (const float*)d_in[7];
    const float* wv    = (const float*)d_in[8];
    const float* bv    = (const float*)d_in[9];
    const float* wo    = (const float*)d_in[10];
    const float* bo    = (const float*)d_in[11];
    const float* ln1g  = (const float*)d_in[12];
    const float* ln1b  = (const float*)d_in[13];
    const float* fc1w  = (const float*)d_in[14];
    const float* fc1b  = (const float*)d_in[15];
    const float* fc2w  = (const float*)d_in[16];
    const float* fc2b  = (const float*)d_in[17];
    const float* ln2g  = (const float*)d_in[18];
    const float* ln2b  = (const float*)d_in[19];
    const float* fng   = (const float*)d_in[20];
    const float* fnb   = (const float*)d_in[21];
    const float* clsw  = (const float*)d_in[22];
    const float* clsb  = (const float*)d_in[23];

    float* ws = (float*)d_ws;
    const size_t SZ  = (size_t)MROWS * DMODEL;   // 2,097,152 floats
    const size_t HP  = SZ / 2;
    float*     h     = ws;
    float*     t1    = ws + 1*SZ;
    _Float16*  hH    = (_Float16*)(ws + 2*SZ);
    _Float16*  hL    = (_Float16*)(ws + 2*SZ + HP);
    _Float16*  aoH   = (_Float16*)(ws + 3*SZ);
    _Float16*  aoL   = (_Float16*)(ws + 3*SZ + HP);
    _Float16*  qbH   = (_Float16*)(ws + 4*SZ);
    _Float16*  qbL   = (_Float16*)(ws + 4*SZ + HP);
    _Float16*  kbH   = (_Float16*)(ws + 5*SZ);
    _Float16*  kbL   = (_Float16*)(ws + 5*SZ + HP);
    float*     vbuf  = ws + 6*SZ;
    _Float16*  WcatH = (_Float16*)(ws + 7*SZ);
    _Float16*  WcatL = (_Float16*)(ws + 7*SZ + 393216);
    _Float16*  WoH   = (_Float16*)(ws + 7*SZ + 786432);
    _Float16*  WoL   = (_Float16*)(ws + 7*SZ + 917504);
    _Float16*  W1H   = (_Float16*)(ws + 7*SZ + 1048576);
    _Float16*  W1L   = (_Float16*)(ws + 7*SZ + 1572864);
    _Float16*  W2H   = (_Float16*)(ws + 7*SZ + 2097152);
    _Float16*  W2L   = (_Float16*)(ws + 7*SZ + 2621440);
    float*     bcat  = ws + 7*SZ + 3145728;
    float*     pooled= ws + 7*SZ + 3145728 + 1536;
    float*     part  = ws + 7*SZ + 3145728 + 1536 + 1024;
    _Float16*  hid   = (_Float16*)(ws + 4*SZ);   // aliases q/k planes (dead then)
    const size_t needed = (7*SZ + 3145728 + 1536 + 1024 + 16384) * sizeof(float);
    if (ws_size < needed) return;

    dim3 blk(256);

    gemm_k<64,1><<<dim3(DMODEL/64, MROWS/128), blk, 0, stream>>>(
        x, emb_w, emb_b, pos, h, MROWS, DMODEL, 128);
    cvtw_k<<<dim3((int)(SZ/256)), blk, 0, stream>>>(h, hH, hL, (int)SZ, 16.f);

    for (int l = 0; l < NLAYER; ++l) {
        const float* wq_l = wq + (size_t)l*DMODEL*DMODEL;
        const float* bq_l = bq + (size_t)l*DMODEL;
        const float* wk_l = wk + (size_t)l*DMODEL*DMODEL;
        const float* bk_l = bk + (size_t)l*DMODEL;
        const float* wv_l = wv + (size_t)l*DMODEL*DMODEL;
        const float* bv_l = bv + (size_t)l*DMODEL;
        const float* wo_l = wo + (size_t)l*DMODEL*DMODEL;
        const float* bo_l = bo + (size_t)l*DMODEL;
        const float* f1w_l = fc1w + (size_t)l*FDIM*DMODEL;
        const float* f1b_l = fc1b + (size_t)l*FDIM;
        const float* f2w_l = fc2w + (size_t)l*DMODEL*FDIM;
        const float* f2b_l = fc2b + (size_t)l*DMODEL;

        // all weight conversions for this layer in one launch
        cvtlayer_k<<<dim3(12294), blk, 0, stream>>>(
            wq_l, wk_l, wv_l, bq_l, bk_l, bv_l, wo_l, f1w_l, f2w_l,
            WcatH, WcatL, bcat, WoH, WoL, W1H, W1L, W2H, W2L);

        // fused QKV (BM=64 -> 768 blocks): q,k f16 planes head layout, v fp32
        mgemm_k<64,0,0,2><<<dim3(12, 64), blk, 0, stream>>>(
            hH, hL, WcatH, WcatL, bcat,
            (float*)qbH, (float*)qbL, (float*)kbH, (float*)kbL, vbuf,
            MROWS, 1536, DMODEL);

        attn_k<<<dim3(T_SEQ/32, NB*NHEAD), blk, 0, stream>>>(
            qbH, qbL, kbH, kbL, vbuf, aoH, aoL);

        // o-proj + spike (BM=64 -> 256 blocks)
        mgemm_k<64,0,2,0><<<dim3(4, 64), blk, 0, stream>>>(
            aoH, aoL, WoH, WoL, bo_l, t1, nullptr, nullptr, nullptr, nullptr,
            MROWS, DMODEL, DMODEL);
        ln_k<<<dim3(MROWS), blk, 0, stream>>>(h, t1, ln1g + (size_t)l*DMODEL,
                                              ln1b + (size_t)l*DMODEL, h, hH, hL);

        // FFN: fc1 (BM=128, 512 blocks) spike->f16; fc2 (BM=64, 256 blocks)
        mgemm_k<128,0,3,0><<<dim3(16, 32), blk, 0, stream>>>(
            hH, hL, W1H, W1L, f1b_l, (float*)hid, nullptr, nullptr, nullptr, nullptr,
            MROWS, FDIM, DMODEL);
        mgemm_k<64,1,2,0><<<dim3(4, 64), blk, 0, stream>>>(
            hid, nullptr, W2H, W2L, f2b_l, t1, nullptr, nullptr, nullptr, nullptr,
            MROWS, DMODEL, FDIM);
        ln_k<<<dim3(MROWS), blk, 0, stream>>>(h, t1, ln2g + (size_t)l*DMODEL,
                                              ln2b + (size_t)l*DMODEL, h, hH, hL);
    }

    ln_k<<<dim3(MROWS), blk, 0, stream>>>(h, nullptr, fng, fnb, h, hH, hL);
    pool_k<<<dim3(64), blk, 0, stream>>>(h, part);
    poolsum_k<<<dim3(4), blk, 0, stream>>>(part, pooled);
    cls_k<<<dim3(128), blk, 0, stream>>>(pooled, clsw, clsb, (float*)d_out);
}